// Round 4
// baseline (3329.543 us; speedup 1.0000x reference)
//
#include <hip/hip_runtime.h>
#include <cstdint>
#include <cstddef>

typedef unsigned short u16;
typedef __attribute__((ext_vector_type(8))) short bf16x8;
typedef __attribute__((ext_vector_type(4))) float f32x4;
typedef unsigned int u32;
typedef __attribute__((address_space(1))) const u32 gu32;
typedef __attribute__((address_space(3))) u32 lu32;

__device__ __forceinline__ void gload_lds16(const void* g, void* l) {
    __builtin_amdgcn_global_load_lds((gu32*)g, (lu32*)l, 16, 0, 0);
}

__device__ __forceinline__ u16 f2bf(float v) {
    u32 u = __float_as_uint(v);
    return (u16)((u + 0x7fffu + ((u >> 16) & 1u)) >> 16);
}
__device__ __forceinline__ float bf2f(u16 h) { return __uint_as_float(((u32)h) << 16); }

// 6-term emulated f32 product: a1b1 + (a1b2 + a2b1) + (a1b3 + a3b1 + a2b2)
__device__ __forceinline__ void mfma6(f32x4& c, bf16x8 a1, bf16x8 a2, bf16x8 a3,
                                      bf16x8 b1, bf16x8 b2, bf16x8 b3) {
    c = __builtin_amdgcn_mfma_f32_16x16x32_bf16(a1, b1, c, 0, 0, 0);
    c = __builtin_amdgcn_mfma_f32_16x16x32_bf16(a1, b2, c, 0, 0, 0);
    c = __builtin_amdgcn_mfma_f32_16x16x32_bf16(a2, b1, c, 0, 0, 0);
    c = __builtin_amdgcn_mfma_f32_16x16x32_bf16(a1, b3, c, 0, 0, 0);
    c = __builtin_amdgcn_mfma_f32_16x16x32_bf16(a3, b1, c, 0, 0, 0);
    c = __builtin_amdgcn_mfma_f32_16x16x32_bf16(a2, b2, c, 0, 0, 0);
}

// ---------------------------------------------------------------------------
// Weight prep: w (O, I, 4) f32 -> 3 bf16 planes, each (O, 4*I), k = kcv*I + i
// ---------------------------------------------------------------------------
__global__ void split_weightT(const float* __restrict__ w, u16* __restrict__ p1,
                              u16* __restrict__ p2, u16* __restrict__ p3, int I) {
    int o = blockIdx.x;
    const int KD = 4 * I;
    const float* wr = w + (size_t)o * KD;
    for (int i = threadIdx.x; i < I; i += 256) {
        float4 v = *reinterpret_cast<const float4*>(&wr[i * 4]);
        float vals[4] = {v.x, v.y, v.z, v.w};
#pragma unroll
        for (int kcv = 0; kcv < 4; kcv++) {
            float f = vals[kcv];
            u16 h1 = f2bf(f); float r = f - bf2f(h1);
            u16 h2 = f2bf(r); r -= bf2f(h2);
            u16 h3 = f2bf(r);
            size_t idx = (size_t)o * KD + kcv * I + i;
            p1[idx] = h1; p2[idx] = h2; p3[idx] = h3;
        }
    }
}

// ---------------------------------------------------------------------------
// Activation prep: x (8, 2048, I) f32 -> 3 bf16 planes (8, 2050, I), one zero
// row before/after each batch (absorbs conv edge taps).
// ---------------------------------------------------------------------------
__global__ void split_x(const float* __restrict__ x, u16* __restrict__ p0,
                        size_t pstride, int I) {
    int pr = blockIdx.x;
    int b = pr / 2050, r = pr - b * 2050;
    u16* d0 = p0 + (size_t)pr * I;
    u16* d1 = d0 + pstride;
    u16* d2 = d1 + pstride;
    if (r == 0 || r == 2049) {
        ushort4 z = {0, 0, 0, 0};
        for (int i = threadIdx.x * 4; i < I; i += 1024) {
            *reinterpret_cast<ushort4*>(d0 + i) = z;
            *reinterpret_cast<ushort4*>(d1 + i) = z;
            *reinterpret_cast<ushort4*>(d2 + i) = z;
        }
        return;
    }
    const float* src = x + ((size_t)b * 2048 + (r - 1)) * I;
    for (int i = threadIdx.x * 4; i < I; i += 1024) {
        float4 v = *reinterpret_cast<const float4*>(src + i);
        ushort4 h1, h2, h3;
        float f, rr;
        f = v.x; h1.x = f2bf(f); rr = f - bf2f(h1.x); h2.x = f2bf(rr); rr -= bf2f(h2.x); h3.x = f2bf(rr);
        f = v.y; h1.y = f2bf(f); rr = f - bf2f(h1.y); h2.y = f2bf(rr); rr -= bf2f(h2.y); h3.y = f2bf(rr);
        f = v.z; h1.z = f2bf(f); rr = f - bf2f(h1.z); h2.z = f2bf(rr); rr -= bf2f(h2.z); h3.z = f2bf(rr);
        f = v.w; h1.w = f2bf(f); rr = f - bf2f(h1.w); h2.w = f2bf(rr); rr -= bf2f(h2.w); h3.w = f2bf(rr);
        *reinterpret_cast<ushort4*>(d0 + i) = h1;
        *reinterpret_cast<ushort4*>(d1 + i) = h2;
        *reinterpret_cast<ushort4*>(d2 + i) = h3;
    }
}

// ---------------------------------------------------------------------------
// Generic row split: in (R, C) f32 -> 3 planes (R*C) u16.  Grid: R blocks.
// ---------------------------------------------------------------------------
__global__ void split_rows(const float* __restrict__ in, u16* __restrict__ p0,
                           size_t pstride, int C) {
    size_t base = (size_t)blockIdx.x * C;
    u16* d0 = p0 + base;
    u16* d1 = d0 + pstride;
    u16* d2 = d1 + pstride;
    for (int i = threadIdx.x * 4; i < C; i += 1024) {
        float4 v = *reinterpret_cast<const float4*>(in + base + i);
        ushort4 h1, h2, h3;
        float f, rr;
        f = v.x; h1.x = f2bf(f); rr = f - bf2f(h1.x); h2.x = f2bf(rr); rr -= bf2f(h2.x); h3.x = f2bf(rr);
        f = v.y; h1.y = f2bf(f); rr = f - bf2f(h1.y); h2.y = f2bf(rr); rr -= bf2f(h2.y); h3.y = f2bf(rr);
        f = v.z; h1.z = f2bf(f); rr = f - bf2f(h1.z); h2.z = f2bf(rr); rr -= bf2f(h2.z); h3.z = f2bf(rr);
        f = v.w; h1.w = f2bf(f); rr = f - bf2f(h1.w); h2.w = f2bf(rr); rr -= bf2f(h2.w); h3.w = f2bf(rr);
        *reinterpret_cast<ushort4*>(d0 + i) = h1;
        *reinterpret_cast<ushort4*>(d1 + i) = h2;
        *reinterpret_cast<ushort4*>(d2 + i) = h3;
    }
}

__global__ void cnorm_kernel(const float* __restrict__ cb, float* __restrict__ cn) {
    int w = threadIdx.x >> 6, lane = threadIdx.x & 63;
    int row = blockIdx.x * 4 + w;
    float4 v = *reinterpret_cast<const float4*>(&cb[(size_t)row * 256 + lane * 4]);
    float s = v.x * v.x + v.y * v.y + v.z * v.z + v.w * v.w;
#pragma unroll
    for (int off = 32; off; off >>= 1) s += __shfl_xor(s, off);
    if (lane == 0) cn[row] = s;
}

// ---------------------------------------------------------------------------
// Conv1d(k=4,s=2,p=1) as 6-term MFMA GEMM, all-gload_lds staging.
// A planes: padded x (8,2050,I); row for (b,t,k): (b*2050+2t)*I + k (k linear).
// B planes: split weights (O, KD).  LDS kg-major [tile][kg][row][8elem], 48KB.
// Epilogue: bias add then split-write 3 bf16 output planes (O columns).
// ---------------------------------------------------------------------------
__global__ __launch_bounds__(256, 3)
void conv_mfma3(const u16* __restrict__ xs, unsigned pstr_x,
                const u16* __restrict__ wt, unsigned pstr_w,
                const float* __restrict__ bias,
                u16* __restrict__ outp, unsigned pstr_o,
                int I, int O, int nchunk) {
    __shared__ u16 lds[24576];
    const int bid = blockIdx.x;
    const int wid = (bid & 7) * nchunk + (bid >> 3);
    const int m0 = (wid & 63) << 7;
    const int n0 = (wid >> 6) << 7;
    const int tid = threadIdx.x, lane = tid & 63, wv = tid >> 6;
    const int wr = ((wv >> 1) & 1) << 6, wc = (wv & 1) << 6;
    const int fr = lane & 15, fkg = lane >> 4;
    const int b = m0 >> 10, t0 = m0 & 1023;
    const int KD = I << 2;

    const u16* srcp[12];
    int dsto[12];
#pragma unroll
    for (int j = 0; j < 12; j++) {
        int ii = wv * 12 + j;
        int tile = ii >> 3, sub = ii & 7;
        int kg = sub >> 1, half = sub & 1;
        int r = half * 64 + lane;
        if (tile < 3)
            srcp[j] = xs + (size_t)tile * pstr_x +
                      (size_t)(b * 2050 + 2 * (t0 + r)) * I + kg * 8;
        else
            srcp[j] = wt + (size_t)(tile - 3) * pstr_w + (size_t)(n0 + r) * KD + kg * 8;
        dsto[j] = tile * 4096 + sub * 512;
    }

    f32x4 acc[4][4];
#pragma unroll
    for (int i = 0; i < 4; i++)
#pragma unroll
        for (int j = 0; j < 4; j++) acc[i][j] = (f32x4){0.f, 0.f, 0.f, 0.f};

    for (int kt = 0; kt < KD; kt += 32) {
#pragma unroll
        for (int j = 0; j < 12; j++) {
            gload_lds16(srcp[j], &lds[dsto[j]]);
            srcp[j] += 32;
        }
        __syncthreads();
        bf16x8 bfr[3][4];
#pragma unroll
        for (int p = 0; p < 3; p++)
#pragma unroll
            for (int fn = 0; fn < 4; fn++)
                bfr[p][fn] = *reinterpret_cast<const bf16x8*>(
                    &lds[(3 + p) * 4096 + fkg * 1024 + (wc + fn * 16 + fr) * 8]);
#pragma unroll
        for (int fm = 0; fm < 4; fm++) {
            int aidx = fkg * 1024 + (wr + fm * 16 + fr) * 8;
            bf16x8 a1 = *reinterpret_cast<const bf16x8*>(&lds[aidx]);
            bf16x8 a2 = *reinterpret_cast<const bf16x8*>(&lds[4096 + aidx]);
            bf16x8 a3 = *reinterpret_cast<const bf16x8*>(&lds[8192 + aidx]);
#pragma unroll
            for (int fn = 0; fn < 4; fn++)
                mfma6(acc[fm][fn], a1, a2, a3, bfr[0][fn], bfr[1][fn], bfr[2][fn]);
        }
        __syncthreads();
    }
#pragma unroll
    for (int fm = 0; fm < 4; fm++) {
        int row0 = m0 + wr + fm * 16 + fkg * 4;
#pragma unroll
        for (int fn = 0; fn < 4; fn++) {
            int col = n0 + wc + fn * 16 + fr;
            float bv = bias[col];
#pragma unroll
            for (int j = 0; j < 4; j++) {
                float f = acc[fm][fn][j] + bv;
                u16 h1 = f2bf(f); float r1 = f - bf2f(h1);
                u16 h2 = f2bf(r1); r1 -= bf2f(h2);
                u16 h3 = f2bf(r1);
                size_t o = (size_t)(row0 + j) * O + col;
                outp[o] = h1;
                outp[(size_t)pstr_o + o] = h2;
                outp[2 * (size_t)pstr_o + o] = h3;
            }
        }
    }
}

// ---------------------------------------------------------------------------
// Projection: z_e[m,d] = sum_c concat[m,c] * proj_w[d,c] + b[d], 6-term MFMA.
// A = 3 concat segments (each 3 planes); B = proj_w planes (256, 3328).
// Epilogue: write z_e f32 and 3 split planes for VQ.
// ---------------------------------------------------------------------------
__global__ __launch_bounds__(256, 3)
void proj_mfma(const u16* __restrict__ sA, const u16* __restrict__ sB,
               const u16* __restrict__ sM, const u16* __restrict__ wp,
               const float* __restrict__ bias, float* __restrict__ z_e,
               u16* __restrict__ zpl) {
    __shared__ u16 lds[24576];
    const int bid = blockIdx.x;
    const int wid = (bid & 7) * 16 + (bid >> 3);
    const int m0 = (wid & 63) << 7;
    const int n0 = (wid >> 6) << 7;
    const int tid = threadIdx.x, lane = tid & 63, wv = tid >> 6;
    const int wr = ((wv >> 1) & 1) << 6, wc = (wv & 1) << 6;
    const int fr = lane & 15, fkg = lane >> 4;

    const u16* srcp[12];
    int dsto[12];
#pragma unroll
    for (int j = 0; j < 12; j++) {
        int ii = wv * 12 + j;
        int tile = ii >> 3, sub = ii & 7;
        int kg = sub >> 1, half = sub & 1;
        int r = half * 64 + lane;
        if (tile >= 3)
            srcp[j] = wp + (size_t)(tile - 3) * 851968 + (size_t)(n0 + r) * 3328 + kg * 8;
        else
            srcp[j] = nullptr;
        dsto[j] = tile * 4096 + sub * 512;
    }

    f32x4 acc[4][4];
#pragma unroll
    for (int i = 0; i < 4; i++)
#pragma unroll
        for (int j = 0; j < 4; j++) acc[i][j] = (f32x4){0.f, 0.f, 0.f, 0.f};

    const u16* segp[3] = {sA, sB, sM};
    const int segC[3] = {1280, 1024, 1024};
    const unsigned segP[3] = {10485760u, 8388608u, 8388608u};

    for (int seg = 0; seg < 3; seg++) {
        const u16* sp = segp[seg];
        const int sc = segC[seg];
        const unsigned sps = segP[seg];
#pragma unroll
        for (int j = 0; j < 12; j++) {
            int ii = wv * 12 + j;
            int tile = ii >> 3, sub = ii & 7;
            int kg = sub >> 1, half = sub & 1;
            int r = half * 64 + lane;
            if (tile < 3)
                srcp[j] = sp + (size_t)tile * sps + (size_t)(m0 + r) * sc + kg * 8;
        }
        const int niter = sc >> 5;
        for (int it = 0; it < niter; it++) {
#pragma unroll
            for (int j = 0; j < 12; j++) {
                gload_lds16(srcp[j], &lds[dsto[j]]);
                srcp[j] += 32;
            }
            __syncthreads();
            bf16x8 bfr[3][4];
#pragma unroll
            for (int p = 0; p < 3; p++)
#pragma unroll
                for (int fn = 0; fn < 4; fn++)
                    bfr[p][fn] = *reinterpret_cast<const bf16x8*>(
                        &lds[(3 + p) * 4096 + fkg * 1024 + (wc + fn * 16 + fr) * 8]);
#pragma unroll
            for (int fm = 0; fm < 4; fm++) {
                int aidx = fkg * 1024 + (wr + fm * 16 + fr) * 8;
                bf16x8 a1 = *reinterpret_cast<const bf16x8*>(&lds[aidx]);
                bf16x8 a2 = *reinterpret_cast<const bf16x8*>(&lds[4096 + aidx]);
                bf16x8 a3 = *reinterpret_cast<const bf16x8*>(&lds[8192 + aidx]);
#pragma unroll
                for (int fn = 0; fn < 4; fn++)
                    mfma6(acc[fm][fn], a1, a2, a3, bfr[0][fn], bfr[1][fn], bfr[2][fn]);
            }
            __syncthreads();
        }
    }
#pragma unroll
    for (int fm = 0; fm < 4; fm++) {
        int row0 = m0 + wr + fm * 16 + fkg * 4;
#pragma unroll
        for (int fn = 0; fn < 4; fn++) {
            int col = n0 + wc + fn * 16 + fr;
            float bv = bias[col];
#pragma unroll
            for (int j = 0; j < 4; j++) {
                float f = acc[fm][fn][j] + bv;
                size_t o = (size_t)(row0 + j) * 256 + col;
                z_e[o] = f;
                u16 h1 = f2bf(f); float r1 = f - bf2f(h1);
                u16 h2 = f2bf(r1); r1 -= bf2f(h2);
                u16 h3 = f2bf(r1);
                zpl[o] = h1;
                zpl[2097152 + o] = h2;
                zpl[4194304 + o] = h3;
            }
        }
    }
}

// ---------------------------------------------------------------------------
// VQ: 6-term MFMA (K=256) + f64 compare + LDS argmin epilogue.
// ---------------------------------------------------------------------------
__global__ __launch_bounds__(256, 3)
void vq_mfma3(const u16* __restrict__ zpl, const u16* __restrict__ cbpl,
              const float* __restrict__ cn, double* __restrict__ pmin,
              int* __restrict__ pidx) {
    __shared__ __align__(16) char smem[49152];
    u16* lds = (u16*)smem;
    const int bid = blockIdx.x;
    const int wid = (bid & 7) * 512 + (bid >> 3);
    const int m0 = (wid & 63) << 7;
    const int n0 = (wid >> 6) << 7;
    const int tid = threadIdx.x, lane = tid & 63, wv = tid >> 6;
    const int wr = ((wv >> 1) & 1) << 6, wc = (wv & 1) << 6;
    const int fr = lane & 15, fkg = lane >> 4;

    const u16* srcp[12];
    int dsto[12];
#pragma unroll
    for (int j = 0; j < 12; j++) {
        int ii = wv * 12 + j;
        int tile = ii >> 3, sub = ii & 7;
        int kg = sub >> 1, half = sub & 1;
        int r = half * 64 + lane;
        if (tile < 3)
            srcp[j] = zpl + (size_t)tile * 2097152 + (size_t)(m0 + r) * 256 + kg * 8;
        else
            srcp[j] = cbpl + (size_t)(tile - 3) * 2097152 + (size_t)(n0 + r) * 256 + kg * 8;
        dsto[j] = tile * 4096 + sub * 512;
    }

    f32x4 acc[4][4];
#pragma unroll
    for (int i = 0; i < 4; i++)
#pragma unroll
        for (int j = 0; j < 4; j++) acc[i][j] = (f32x4){0.f, 0.f, 0.f, 0.f};

    for (int kt = 0; kt < 256; kt += 32) {
#pragma unroll
        for (int j = 0; j < 12; j++) {
            gload_lds16(srcp[j], &lds[dsto[j]]);
            srcp[j] += 32;
        }
        __syncthreads();
        bf16x8 bfr[3][4];
#pragma unroll
        for (int p = 0; p < 3; p++)
#pragma unroll
            for (int fn = 0; fn < 4; fn++)
                bfr[p][fn] = *reinterpret_cast<const bf16x8*>(
                    &lds[(3 + p) * 4096 + fkg * 1024 + (wc + fn * 16 + fr) * 8]);
#pragma unroll
        for (int fm = 0; fm < 4; fm++) {
            int aidx = fkg * 1024 + (wr + fm * 16 + fr) * 8;
            bf16x8 a1 = *reinterpret_cast<const bf16x8*>(&lds[aidx]);
            bf16x8 a2 = *reinterpret_cast<const bf16x8*>(&lds[4096 + aidx]);
            bf16x8 a3 = *reinterpret_cast<const bf16x8*>(&lds[8192 + aidx]);
#pragma unroll
            for (int fn = 0; fn < 4; fn++)
                mfma6(acc[fm][fn], a1, a2, a3, bfr[0][fn], bfr[1][fn], bfr[2][fn]);
        }
        __syncthreads();
    }
    // ---- epilogue: per-row argmin, d = |c|^2 - 2 dot in f64 (LDS reused)
    double (*red_d)[32] = (double (*)[32])smem;
    int (*red_n)[32] = (int (*)[32])(smem + 32768);
#pragma unroll
    for (int fm = 0; fm < 4; fm++)
#pragma unroll
        for (int j = 0; j < 4; j++) {
            double best = 1e300; int bestn = 0x7fffffff;
#pragma unroll
            for (int fn = 0; fn < 4; fn++) {
                int gn = n0 + wc + fn * 16 + fr;
                double d = (double)cn[gn] - 2.0 * (double)acc[fm][fn][j];
                if (d < best || (d == best && gn < bestn)) { best = d; bestn = gn; }
            }
            int row = wr + fm * 16 + fkg * 4 + j;
            int cand = ((wv & 1) << 4) + fr;
            red_d[row][cand] = best; red_n[row][cand] = bestn;
        }
    __syncthreads();
    if (tid < 128) {
        double best = red_d[tid][0]; int bestn = red_n[tid][0];
#pragma unroll 4
        for (int k = 1; k < 32; k++) {
            double d = red_d[tid][k]; int n2 = red_n[tid][k];
            if (d < best || (d == best && n2 < bestn)) { best = d; bestn = n2; }
        }
        size_t idx = (size_t)(m0 + tid) * 64 + (n0 >> 7);
        pmin[idx] = best; pidx[idx] = bestn;
    }
}

// ---------------------------------------------------------------------------
__global__ void vq_finalize(const double* __restrict__ pmin, const int* __restrict__ pidx,
                            const float* __restrict__ z, const float* __restrict__ cb,
                            float* __restrict__ out, double* __restrict__ cpart) {
    int w = threadIdx.x >> 6, lane = threadIdx.x & 63;
    int m = blockIdx.x * 4 + w;
    double d = pmin[(size_t)m * 64 + lane];
    int n = pidx[(size_t)m * 64 + lane];
#pragma unroll
    for (int off = 32; off; off >>= 1) {
        double d2 = __shfl_xor(d, off);
        int n2 = __shfl_xor(n, off);
        if (d2 < d || (d2 == d && n2 < n)) { d = d2; n = n2; }
    }
    float4 cv = *reinterpret_cast<const float4*>(&cb[(size_t)n * 256 + lane * 4]);
    float4 zv = *reinterpret_cast<const float4*>(&z[(size_t)m * 256 + lane * 4]);
    *reinterpret_cast<float4*>(&out[(size_t)m * 256 + lane * 4]) = cv;
    float dx = zv.x - cv.x, dy = zv.y - cv.y, dz = zv.z - cv.z, dw = zv.w - cv.w;
    double s = (double)(dx * dx) + (double)(dy * dy) + (double)(dz * dz) + (double)(dw * dw);
#pragma unroll
    for (int off = 32; off; off >>= 1) s += __shfl_xor(s, off);
    if (lane == 0) {
        out[2097152 + m] = (float)n;
        cpart[m] = s;
    }
}

__global__ void vq_reduce(const double* __restrict__ cpart, float* __restrict__ out) {
    __shared__ double sm[256];
    double s = 0.0;
    for (int i = threadIdx.x; i < 8192; i += 256) s += cpart[i];
    sm[threadIdx.x] = s;
    __syncthreads();
    for (int off = 128; off; off >>= 1) {
        if ((int)threadIdx.x < off) sm[threadIdx.x] += sm[threadIdx.x + off];
        __syncthreads();
    }
    if (threadIdx.x == 0) out[2105344] = (float)(sm[0] / 2097152.0);
}

// ---------------------------------------------------------------------------
extern "C" void kernel_launch(void* const* d_in, const int* in_sizes, int n_in,
                              void* d_out, int out_size, void* d_ws, size_t ws_size,
                              hipStream_t stream) {
    (void)in_sizes; (void)n_in; (void)out_size; (void)ws_size;
    const float* whisper   = (const float*)d_in[0];
    const float* wavlm     = (const float*)d_in[1];
    const float* muq       = (const float*)d_in[2];
    const float* w_conv_w  = (const float*)d_in[3];
    const float* w_conv_b  = (const float*)d_in[4];
    const float* wl_conv_w = (const float*)d_in[5];
    const float* wl_conv_b = (const float*)d_in[6];
    const float* proj_w    = (const float*)d_in[7];
    const float* proj_b    = (const float*)d_in[8];
    const float* codebook  = (const float*)d_in[9];
    float* out = (float*)d_out;
    char* wsb = (char*)d_ws;

    // ---- workspace layout (bytes), peak 239,173,632 < 252,567,552 proven ----
    // phase 1 (whisper):
    u16*   xsA   = (u16*)(wsb + 0);            // 3 planes, pstr 20,992,000 elems
    u16*   wtbA  = (u16*)(wsb + 125952000);    // 3 planes, pstr 6,553,600
    u16*   cApl  = (u16*)(wsb + 176259072);    // 3 planes, pstr 10,485,760
    // phase 2 (wavlm):
    u16*   xsB   = (u16*)(wsb + 0);            // pstr 16,793,600
    u16*   wtbB  = (u16*)(wsb + 100761600);    // pstr 4,194,304
    u16*   cBpl  = (u16*)(wsb + 125927424);    // pstr 8,388,608
    // phase 3 (proj):
    u16*   muqpl = (u16*)(wsb + 0);            // pstr 8,388,608
    u16*   wtpPl = (u16*)(wsb + 50331648);     // pstr 851,968
    float* z_e   = (float*)(wsb + 55443456);   // 8192*256 f32
    u16*   zpl   = (u16*)(wsb + 63832064);     // pstr 2,097,152
    // phase 4 (vq):
    u16*   cbpl  = (u16*)(wsb + 76414976);     // pstr 2,097,152
    float* cnorm = (float*)(wsb + 88997888);
    double* pmin = (double*)(wsb + 89030656);
    int*    pidx = (int*)(wsb + 93224960);
    double* cpart= (double*)(wsb + 95322112);

    // phase 1: whisper conv
    split_x<<<16400, 256, 0, stream>>>(whisper, xsA, 20992000, 1280);
    split_weightT<<<1280, 256, 0, stream>>>(w_conv_w, wtbA, wtbA + 6553600,
                                            wtbA + 2u * 6553600, 1280);
    conv_mfma3<<<640, 256, 0, stream>>>(xsA, 20992000, wtbA, 6553600, w_conv_b,
                                        cApl, 10485760, 1280, 1280, 80);
    // phase 2: wavlm conv (reuses xsA/wtbA region)
    split_x<<<16400, 256, 0, stream>>>(wavlm, xsB, 16793600, 1024);
    split_weightT<<<1024, 256, 0, stream>>>(wl_conv_w, wtbB, wtbB + 4194304,
                                            wtbB + 2u * 4194304, 1024);
    conv_mfma3<<<512, 256, 0, stream>>>(xsB, 16793600, wtbB, 4194304, wl_conv_b,
                                        cBpl, 8388608, 1024, 1024, 64);
    // phase 3: projection
    split_rows<<<8192, 256, 0, stream>>>(muq, muqpl, 8388608, 1024);
    split_rows<<<256, 256, 0, stream>>>(proj_w, wtpPl, 851968, 3328);
    proj_mfma<<<128, 256, 0, stream>>>(cApl, cBpl, muqpl, wtpPl, proj_b, z_e, zpl);
    // phase 4: VQ
    split_rows<<<8192, 256, 0, stream>>>(codebook, cbpl, 2097152, 256);
    cnorm_kernel<<<2048, 256, 0, stream>>>(codebook, cnorm);
    vq_mfma3<<<4096, 256, 0, stream>>>(zpl, cbpl, cnorm, pmin, pidx);
    vq_finalize<<<2048, 256, 0, stream>>>(pmin, pidx, z_e, codebook, out, cpart);
    vq_reduce<<<1, 256, 0, stream>>>(cpart, out);
}

// Round 5
// 3150.466 us; speedup vs baseline: 1.0568x; 1.0568x over previous
//
#include <hip/hip_runtime.h>
#include <cstdint>
#include <cstddef>

typedef unsigned short u16;
typedef __attribute__((ext_vector_type(8))) short bf16x8;
typedef __attribute__((ext_vector_type(4))) float f32x4;
typedef unsigned int u32;
typedef __attribute__((address_space(1))) const u32 gu32;
typedef __attribute__((address_space(3))) u32 lu32;

__device__ __forceinline__ void gload_lds16(const void* g, void* l) {
    __builtin_amdgcn_global_load_lds((gu32*)g, (lu32*)l, 16, 0, 0);
}

__device__ __forceinline__ u16 f2bf(float v) {
    u32 u = __float_as_uint(v);
    return (u16)((u + 0x7fffu + ((u >> 16) & 1u)) >> 16);
}
__device__ __forceinline__ float bf2f(u16 h) { return __uint_as_float(((u32)h) << 16); }

// 6-term emulated f32 product: a1b1 + (a1b2 + a2b1) + (a1b3 + a3b1 + a2b2)
__device__ __forceinline__ void mfma6(f32x4& c, bf16x8 a1, bf16x8 a2, bf16x8 a3,
                                      bf16x8 b1, bf16x8 b2, bf16x8 b3) {
    c = __builtin_amdgcn_mfma_f32_16x16x32_bf16(a1, b1, c, 0, 0, 0);
    c = __builtin_amdgcn_mfma_f32_16x16x32_bf16(a1, b2, c, 0, 0, 0);
    c = __builtin_amdgcn_mfma_f32_16x16x32_bf16(a2, b1, c, 0, 0, 0);
    c = __builtin_amdgcn_mfma_f32_16x16x32_bf16(a1, b3, c, 0, 0, 0);
    c = __builtin_amdgcn_mfma_f32_16x16x32_bf16(a3, b1, c, 0, 0, 0);
    c = __builtin_amdgcn_mfma_f32_16x16x32_bf16(a2, b2, c, 0, 0, 0);
}

// ---------------------------------------------------------------------------
// Weight prep: w (O, I, 4) f32 -> 3 bf16 planes, each (O, 4*I), k = kcv*I + i
// ---------------------------------------------------------------------------
__global__ void split_weightT(const float* __restrict__ w, u16* __restrict__ p1,
                              u16* __restrict__ p2, u16* __restrict__ p3, int I) {
    int o = blockIdx.x;
    const int KD = 4 * I;
    const float* wr = w + (size_t)o * KD;
    for (int i = threadIdx.x; i < I; i += 256) {
        float4 v = *reinterpret_cast<const float4*>(&wr[i * 4]);
        float vals[4] = {v.x, v.y, v.z, v.w};
#pragma unroll
        for (int kcv = 0; kcv < 4; kcv++) {
            float f = vals[kcv];
            u16 h1 = f2bf(f); float r = f - bf2f(h1);
            u16 h2 = f2bf(r); r -= bf2f(h2);
            u16 h3 = f2bf(r);
            size_t idx = (size_t)o * KD + kcv * I + i;
            p1[idx] = h1; p2[idx] = h2; p3[idx] = h3;
        }
    }
}

// ---------------------------------------------------------------------------
// Activation prep: x (8, 2048, I) f32 -> 3 bf16 planes (8, 2050, I), one zero
// row before/after each batch (absorbs conv edge taps).
// ---------------------------------------------------------------------------
__global__ void split_x(const float* __restrict__ x, u16* __restrict__ p0,
                        size_t pstride, int I) {
    int pr = blockIdx.x;
    int b = pr / 2050, r = pr - b * 2050;
    u16* d0 = p0 + (size_t)pr * I;
    u16* d1 = d0 + pstride;
    u16* d2 = d1 + pstride;
    if (r == 0 || r == 2049) {
        ushort4 z = {0, 0, 0, 0};
        for (int i = threadIdx.x * 4; i < I; i += 1024) {
            *reinterpret_cast<ushort4*>(d0 + i) = z;
            *reinterpret_cast<ushort4*>(d1 + i) = z;
            *reinterpret_cast<ushort4*>(d2 + i) = z;
        }
        return;
    }
    const float* src = x + ((size_t)b * 2048 + (r - 1)) * I;
    for (int i = threadIdx.x * 4; i < I; i += 1024) {
        float4 v = *reinterpret_cast<const float4*>(src + i);
        ushort4 h1, h2, h3;
        float f, rr;
        f = v.x; h1.x = f2bf(f); rr = f - bf2f(h1.x); h2.x = f2bf(rr); rr -= bf2f(h2.x); h3.x = f2bf(rr);
        f = v.y; h1.y = f2bf(f); rr = f - bf2f(h1.y); h2.y = f2bf(rr); rr -= bf2f(h2.y); h3.y = f2bf(rr);
        f = v.z; h1.z = f2bf(f); rr = f - bf2f(h1.z); h2.z = f2bf(rr); rr -= bf2f(h2.z); h3.z = f2bf(rr);
        f = v.w; h1.w = f2bf(f); rr = f - bf2f(h1.w); h2.w = f2bf(rr); rr -= bf2f(h2.w); h3.w = f2bf(rr);
        *reinterpret_cast<ushort4*>(d0 + i) = h1;
        *reinterpret_cast<ushort4*>(d1 + i) = h2;
        *reinterpret_cast<ushort4*>(d2 + i) = h3;
    }
}

// ---------------------------------------------------------------------------
// Generic row split: in (R, C) f32 -> 3 planes (R*C) u16.  Grid: R blocks.
// ---------------------------------------------------------------------------
__global__ void split_rows(const float* __restrict__ in, u16* __restrict__ p0,
                           size_t pstride, int C) {
    size_t base = (size_t)blockIdx.x * C;
    u16* d0 = p0 + base;
    u16* d1 = d0 + pstride;
    u16* d2 = d1 + pstride;
    for (int i = threadIdx.x * 4; i < C; i += 1024) {
        float4 v = *reinterpret_cast<const float4*>(in + base + i);
        ushort4 h1, h2, h3;
        float f, rr;
        f = v.x; h1.x = f2bf(f); rr = f - bf2f(h1.x); h2.x = f2bf(rr); rr -= bf2f(h2.x); h3.x = f2bf(rr);
        f = v.y; h1.y = f2bf(f); rr = f - bf2f(h1.y); h2.y = f2bf(rr); rr -= bf2f(h2.y); h3.y = f2bf(rr);
        f = v.z; h1.z = f2bf(f); rr = f - bf2f(h1.z); h2.z = f2bf(rr); rr -= bf2f(h2.z); h3.z = f2bf(rr);
        f = v.w; h1.w = f2bf(f); rr = f - bf2f(h1.w); h2.w = f2bf(rr); rr -= bf2f(h2.w); h3.w = f2bf(rr);
        *reinterpret_cast<ushort4*>(d0 + i) = h1;
        *reinterpret_cast<ushort4*>(d1 + i) = h2;
        *reinterpret_cast<ushort4*>(d2 + i) = h3;
    }
}

__global__ void cnorm_kernel(const float* __restrict__ cb, float* __restrict__ cn) {
    int w = threadIdx.x >> 6, lane = threadIdx.x & 63;
    int row = blockIdx.x * 4 + w;
    float4 v = *reinterpret_cast<const float4*>(&cb[(size_t)row * 256 + lane * 4]);
    float s = v.x * v.x + v.y * v.y + v.z * v.z + v.w * v.w;
#pragma unroll
    for (int off = 32; off; off >>= 1) s += __shfl_xor(s, off);
    if (lane == 0) cn[row] = s;
}

// ---------------------------------------------------------------------------
// Conv1d(k=4,s=2,p=1) as 6-term MFMA GEMM, all-gload_lds staging.
// Grid: dim3(64, O/128) — m fastest (round-robin across XCDs keeps A-panel
// sharing in L2; the chunked swizzle destroyed it in round 4).
// ---------------------------------------------------------------------------
__global__ __launch_bounds__(256, 3)
void conv_mfma3(const u16* __restrict__ xs, unsigned pstr_x,
                const u16* __restrict__ wt, unsigned pstr_w,
                const float* __restrict__ bias,
                u16* __restrict__ outp, unsigned pstr_o,
                int I, int O) {
    __shared__ u16 lds[24576];
    const int m0 = blockIdx.x << 7;
    const int n0 = blockIdx.y << 7;
    const int tid = threadIdx.x, lane = tid & 63, wv = tid >> 6;
    const int wr = ((wv >> 1) & 1) << 6, wc = (wv & 1) << 6;
    const int fr = lane & 15, fkg = lane >> 4;
    const int b = m0 >> 10, t0 = m0 & 1023;
    const int KD = I << 2;

    const u16* srcp[12];
    int dsto[12];
#pragma unroll
    for (int j = 0; j < 12; j++) {
        int ii = wv * 12 + j;
        int tile = ii >> 3, sub = ii & 7;
        int kg = sub >> 1, half = sub & 1;
        int r = half * 64 + lane;
        if (tile < 3)
            srcp[j] = xs + (size_t)tile * pstr_x +
                      (size_t)(b * 2050 + 2 * (t0 + r)) * I + kg * 8;
        else
            srcp[j] = wt + (size_t)(tile - 3) * pstr_w + (size_t)(n0 + r) * KD + kg * 8;
        dsto[j] = tile * 4096 + sub * 512;
    }

    f32x4 acc[4][4];
#pragma unroll
    for (int i = 0; i < 4; i++)
#pragma unroll
        for (int j = 0; j < 4; j++) acc[i][j] = (f32x4){0.f, 0.f, 0.f, 0.f};

    for (int kt = 0; kt < KD; kt += 32) {
#pragma unroll
        for (int j = 0; j < 12; j++) {
            gload_lds16(srcp[j], &lds[dsto[j]]);
            srcp[j] += 32;
        }
        __syncthreads();
        bf16x8 bfr[3][4];
#pragma unroll
        for (int p = 0; p < 3; p++)
#pragma unroll
            for (int fn = 0; fn < 4; fn++)
                bfr[p][fn] = *reinterpret_cast<const bf16x8*>(
                    &lds[(3 + p) * 4096 + fkg * 1024 + (wc + fn * 16 + fr) * 8]);
#pragma unroll
        for (int fm = 0; fm < 4; fm++) {
            int aidx = fkg * 1024 + (wr + fm * 16 + fr) * 8;
            bf16x8 a1 = *reinterpret_cast<const bf16x8*>(&lds[aidx]);
            bf16x8 a2 = *reinterpret_cast<const bf16x8*>(&lds[4096 + aidx]);
            bf16x8 a3 = *reinterpret_cast<const bf16x8*>(&lds[8192 + aidx]);
#pragma unroll
            for (int fn = 0; fn < 4; fn++)
                mfma6(acc[fm][fn], a1, a2, a3, bfr[0][fn], bfr[1][fn], bfr[2][fn]);
        }
        __syncthreads();
    }
#pragma unroll
    for (int fm = 0; fm < 4; fm++) {
        int row0 = m0 + wr + fm * 16 + fkg * 4;
#pragma unroll
        for (int fn = 0; fn < 4; fn++) {
            int col = n0 + wc + fn * 16 + fr;
            float bv = bias[col];
#pragma unroll
            for (int j = 0; j < 4; j++) {
                float f = acc[fm][fn][j] + bv;
                u16 h1 = f2bf(f); float r1 = f - bf2f(h1);
                u16 h2 = f2bf(r1); r1 -= bf2f(h2);
                u16 h3 = f2bf(r1);
                size_t o = (size_t)(row0 + j) * O + col;
                outp[o] = h1;
                outp[(size_t)pstr_o + o] = h2;
                outp[2 * (size_t)pstr_o + o] = h3;
            }
        }
    }
}

// ---------------------------------------------------------------------------
// Projection: z_e[m,d] = sum_c concat[m,c] * proj_w[d,c] + b[d], 6-term MFMA.
// Grid: dim3(64, 2).
// ---------------------------------------------------------------------------
__global__ __launch_bounds__(256, 3)
void proj_mfma(const u16* __restrict__ sA, const u16* __restrict__ sB,
               const u16* __restrict__ sM, const u16* __restrict__ wp,
               const float* __restrict__ bias, float* __restrict__ z_e,
               u16* __restrict__ zpl) {
    __shared__ u16 lds[24576];
    const int m0 = blockIdx.x << 7;
    const int n0 = blockIdx.y << 7;
    const int tid = threadIdx.x, lane = tid & 63, wv = tid >> 6;
    const int wr = ((wv >> 1) & 1) << 6, wc = (wv & 1) << 6;
    const int fr = lane & 15, fkg = lane >> 4;

    const u16* srcp[12];
    int dsto[12];
#pragma unroll
    for (int j = 0; j < 12; j++) {
        int ii = wv * 12 + j;
        int tile = ii >> 3, sub = ii & 7;
        int kg = sub >> 1, half = sub & 1;
        int r = half * 64 + lane;
        if (tile >= 3)
            srcp[j] = wp + (size_t)(tile - 3) * 851968 + (size_t)(n0 + r) * 3328 + kg * 8;
        else
            srcp[j] = nullptr;
        dsto[j] = tile * 4096 + sub * 512;
    }

    f32x4 acc[4][4];
#pragma unroll
    for (int i = 0; i < 4; i++)
#pragma unroll
        for (int j = 0; j < 4; j++) acc[i][j] = (f32x4){0.f, 0.f, 0.f, 0.f};

    const u16* segp[3] = {sA, sB, sM};
    const int segC[3] = {1280, 1024, 1024};
    const unsigned segP[3] = {10485760u, 8388608u, 8388608u};

    for (int seg = 0; seg < 3; seg++) {
        const u16* sp = segp[seg];
        const int sc = segC[seg];
        const unsigned sps = segP[seg];
#pragma unroll
        for (int j = 0; j < 12; j++) {
            int ii = wv * 12 + j;
            int tile = ii >> 3, sub = ii & 7;
            int kg = sub >> 1, half = sub & 1;
            int r = half * 64 + lane;
            if (tile < 3)
                srcp[j] = sp + (size_t)tile * sps + (size_t)(m0 + r) * sc + kg * 8;
        }
        const int niter = sc >> 5;
        for (int it = 0; it < niter; it++) {
#pragma unroll
            for (int j = 0; j < 12; j++) {
                gload_lds16(srcp[j], &lds[dsto[j]]);
                srcp[j] += 32;
            }
            __syncthreads();
            bf16x8 bfr[3][4];
#pragma unroll
            for (int p = 0; p < 3; p++)
#pragma unroll
                for (int fn = 0; fn < 4; fn++)
                    bfr[p][fn] = *reinterpret_cast<const bf16x8*>(
                        &lds[(3 + p) * 4096 + fkg * 1024 + (wc + fn * 16 + fr) * 8]);
#pragma unroll
            for (int fm = 0; fm < 4; fm++) {
                int aidx = fkg * 1024 + (wr + fm * 16 + fr) * 8;
                bf16x8 a1 = *reinterpret_cast<const bf16x8*>(&lds[aidx]);
                bf16x8 a2 = *reinterpret_cast<const bf16x8*>(&lds[4096 + aidx]);
                bf16x8 a3 = *reinterpret_cast<const bf16x8*>(&lds[8192 + aidx]);
#pragma unroll
                for (int fn = 0; fn < 4; fn++)
                    mfma6(acc[fm][fn], a1, a2, a3, bfr[0][fn], bfr[1][fn], bfr[2][fn]);
            }
            __syncthreads();
        }
    }
#pragma unroll
    for (int fm = 0; fm < 4; fm++) {
        int row0 = m0 + wr + fm * 16 + fkg * 4;
#pragma unroll
        for (int fn = 0; fn < 4; fn++) {
            int col = n0 + wc + fn * 16 + fr;
            float bv = bias[col];
#pragma unroll
            for (int j = 0; j < 4; j++) {
                float f = acc[fm][fn][j] + bv;
                size_t o = (size_t)(row0 + j) * 256 + col;
                z_e[o] = f;
                u16 h1 = f2bf(f); float r1 = f - bf2f(h1);
                u16 h2 = f2bf(r1); r1 -= bf2f(h2);
                u16 h3 = f2bf(r1);
                zpl[o] = h1;
                zpl[2097152 + o] = h2;
                zpl[4194304 + o] = h3;
            }
        }
    }
}

// ---------------------------------------------------------------------------
// VQ: 6-term MFMA (K=256) + f64 compare + LDS argmin epilogue.  Grid (64,64).
// ---------------------------------------------------------------------------
__global__ __launch_bounds__(256, 3)
void vq_mfma3(const u16* __restrict__ zpl, const u16* __restrict__ cbpl,
              const float* __restrict__ cn, double* __restrict__ pmin,
              int* __restrict__ pidx) {
    __shared__ __align__(16) char smem[49152];
    u16* lds = (u16*)smem;
    const int m0 = blockIdx.x << 7;
    const int n0 = blockIdx.y << 7;
    const int tid = threadIdx.x, lane = tid & 63, wv = tid >> 6;
    const int wr = ((wv >> 1) & 1) << 6, wc = (wv & 1) << 6;
    const int fr = lane & 15, fkg = lane >> 4;

    const u16* srcp[12];
    int dsto[12];
#pragma unroll
    for (int j = 0; j < 12; j++) {
        int ii = wv * 12 + j;
        int tile = ii >> 3, sub = ii & 7;
        int kg = sub >> 1, half = sub & 1;
        int r = half * 64 + lane;
        if (tile < 3)
            srcp[j] = zpl + (size_t)tile * 2097152 + (size_t)(m0 + r) * 256 + kg * 8;
        else
            srcp[j] = cbpl + (size_t)(tile - 3) * 2097152 + (size_t)(n0 + r) * 256 + kg * 8;
        dsto[j] = tile * 4096 + sub * 512;
    }

    f32x4 acc[4][4];
#pragma unroll
    for (int i = 0; i < 4; i++)
#pragma unroll
        for (int j = 0; j < 4; j++) acc[i][j] = (f32x4){0.f, 0.f, 0.f, 0.f};

    for (int kt = 0; kt < 256; kt += 32) {
#pragma unroll
        for (int j = 0; j < 12; j++) {
            gload_lds16(srcp[j], &lds[dsto[j]]);
            srcp[j] += 32;
        }
        __syncthreads();
        bf16x8 bfr[3][4];
#pragma unroll
        for (int p = 0; p < 3; p++)
#pragma unroll
            for (int fn = 0; fn < 4; fn++)
                bfr[p][fn] = *reinterpret_cast<const bf16x8*>(
                    &lds[(3 + p) * 4096 + fkg * 1024 + (wc + fn * 16 + fr) * 8]);
#pragma unroll
        for (int fm = 0; fm < 4; fm++) {
            int aidx = fkg * 1024 + (wr + fm * 16 + fr) * 8;
            bf16x8 a1 = *reinterpret_cast<const bf16x8*>(&lds[aidx]);
            bf16x8 a2 = *reinterpret_cast<const bf16x8*>(&lds[4096 + aidx]);
            bf16x8 a3 = *reinterpret_cast<const bf16x8*>(&lds[8192 + aidx]);
#pragma unroll
            for (int fn = 0; fn < 4; fn++)
                mfma6(acc[fm][fn], a1, a2, a3, bfr[0][fn], bfr[1][fn], bfr[2][fn]);
        }
        __syncthreads();
    }
    // ---- epilogue: per-row argmin, d = |c|^2 - 2 dot in f64 (LDS reused)
    double (*red_d)[32] = (double (*)[32])smem;
    int (*red_n)[32] = (int (*)[32])(smem + 32768);
#pragma unroll
    for (int fm = 0; fm < 4; fm++)
#pragma unroll
        for (int j = 0; j < 4; j++) {
            double best = 1e300; int bestn = 0x7fffffff;
#pragma unroll
            for (int fn = 0; fn < 4; fn++) {
                int gn = n0 + wc + fn * 16 + fr;
                double d = (double)cn[gn] - 2.0 * (double)acc[fm][fn][j];
                if (d < best || (d == best && gn < bestn)) { best = d; bestn = gn; }
            }
            int row = wr + fm * 16 + fkg * 4 + j;
            int cand = ((wv & 1) << 4) + fr;
            red_d[row][cand] = best; red_n[row][cand] = bestn;
        }
    __syncthreads();
    if (tid < 128) {
        double best = red_d[tid][0]; int bestn = red_n[tid][0];
#pragma unroll 4
        for (int k = 1; k < 32; k++) {
            double d = red_d[tid][k]; int n2 = red_n[tid][k];
            if (d < best || (d == best && n2 < bestn)) { best = d; bestn = n2; }
        }
        size_t idx = (size_t)(m0 + tid) * 64 + (n0 >> 7);
        pmin[idx] = best; pidx[idx] = bestn;
    }
}

// ---------------------------------------------------------------------------
__global__ void vq_finalize(const double* __restrict__ pmin, const int* __restrict__ pidx,
                            const float* __restrict__ z, const float* __restrict__ cb,
                            float* __restrict__ out, double* __restrict__ cpart) {
    int w = threadIdx.x >> 6, lane = threadIdx.x & 63;
    int m = blockIdx.x * 4 + w;
    double d = pmin[(size_t)m * 64 + lane];
    int n = pidx[(size_t)m * 64 + lane];
#pragma unroll
    for (int off = 32; off; off >>= 1) {
        double d2 = __shfl_xor(d, off);
        int n2 = __shfl_xor(n, off);
        if (d2 < d || (d2 == d && n2 < n)) { d = d2; n = n2; }
    }
    float4 cv = *reinterpret_cast<const float4*>(&cb[(size_t)n * 256 + lane * 4]);
    float4 zv = *reinterpret_cast<const float4*>(&z[(size_t)m * 256 + lane * 4]);
    *reinterpret_cast<float4*>(&out[(size_t)m * 256 + lane * 4]) = cv;
    float dx = zv.x - cv.x, dy = zv.y - cv.y, dz = zv.z - cv.z, dw = zv.w - cv.w;
    double s = (double)(dx * dx) + (double)(dy * dy) + (double)(dz * dz) + (double)(dw * dw);
#pragma unroll
    for (int off = 32; off; off >>= 1) s += __shfl_xor(s, off);
    if (lane == 0) {
        out[2097152 + m] = (float)n;
        cpart[m] = s;
    }
}

__global__ void vq_reduce(const double* __restrict__ cpart, float* __restrict__ out) {
    __shared__ double sm[256];
    double s = 0.0;
    for (int i = threadIdx.x; i < 8192; i += 256) s += cpart[i];
    sm[threadIdx.x] = s;
    __syncthreads();
    for (int off = 128; off; off >>= 1) {
        if ((int)threadIdx.x < off) sm[threadIdx.x] += sm[threadIdx.x + off];
        __syncthreads();
    }
    if (threadIdx.x == 0) out[2105344] = (float)(sm[0] / 2097152.0);
}

// ---------------------------------------------------------------------------
extern "C" void kernel_launch(void* const* d_in, const int* in_sizes, int n_in,
                              void* d_out, int out_size, void* d_ws, size_t ws_size,
                              hipStream_t stream) {
    (void)in_sizes; (void)n_in; (void)out_size; (void)ws_size;
    const float* whisper   = (const float*)d_in[0];
    const float* wavlm     = (const float*)d_in[1];
    const float* muq       = (const float*)d_in[2];
    const float* w_conv_w  = (const float*)d_in[3];
    const float* w_conv_b  = (const float*)d_in[4];
    const float* wl_conv_w = (const float*)d_in[5];
    const float* wl_conv_b = (const float*)d_in[6];
    const float* proj_w    = (const float*)d_in[7];
    const float* proj_b    = (const float*)d_in[8];
    const float* codebook  = (const float*)d_in[9];
    float* out = (float*)d_out;
    char* wsb = (char*)d_ws;

    // ---- workspace layout (bytes), peak 239,173,632 ----
    // phase 1 (whisper):
    u16*   xsA   = (u16*)(wsb + 0);            // 3 planes, pstr 20,992,000 elems
    u16*   wtbA  = (u16*)(wsb + 125952000);    // 3 planes, pstr 6,553,600
    u16*   cApl  = (u16*)(wsb + 176259072);    // 3 planes, pstr 10,485,760
    // phase 2 (wavlm):
    u16*   xsB   = (u16*)(wsb + 0);            // pstr 16,793,600
    u16*   wtbB  = (u16*)(wsb + 100761600);    // pstr 4,194,304
    u16*   cBpl  = (u16*)(wsb + 125927424);    // pstr 8,388,608
    // phase 3 (proj):
    u16*   muqpl = (u16*)(wsb + 0);            // pstr 8,388,608
    u16*   wtpPl = (u16*)(wsb + 50331648);     // pstr 851,968
    float* z_e   = (float*)(wsb + 55443456);   // 8192*256 f32
    u16*   zpl   = (u16*)(wsb + 63832064);     // pstr 2,097,152
    // phase 4 (vq):
    u16*   cbpl  = (u16*)(wsb + 76414976);     // pstr 2,097,152
    float* cnorm = (float*)(wsb + 88997888);
    double* pmin = (double*)(wsb + 89030656);
    int*    pidx = (int*)(wsb + 93224960);
    double* cpart= (double*)(wsb + 95322112);

    // phase 1: whisper conv
    split_x<<<16400, 256, 0, stream>>>(whisper, xsA, 20992000, 1280);
    split_weightT<<<1280, 256, 0, stream>>>(w_conv_w, wtbA, wtbA + 6553600,
                                            wtbA + 2u * 6553600, 1280);
    conv_mfma3<<<dim3(64, 10), 256, 0, stream>>>(xsA, 20992000, wtbA, 6553600,
                                                 w_conv_b, cApl, 10485760, 1280, 1280);
    // phase 2: wavlm conv (reuses xsA/wtbA region)
    split_x<<<16400, 256, 0, stream>>>(wavlm, xsB, 16793600, 1024);
    split_weightT<<<1024, 256, 0, stream>>>(wl_conv_w, wtbB, wtbB + 4194304,
                                            wtbB + 2u * 4194304, 1024);
    conv_mfma3<<<dim3(64, 8), 256, 0, stream>>>(xsB, 16793600, wtbB, 4194304,
                                                wl_conv_b, cBpl, 8388608, 1024, 1024);
    // phase 3: projection
    split_rows<<<8192, 256, 0, stream>>>(muq, muqpl, 8388608, 1024);
    split_rows<<<256, 256, 0, stream>>>(proj_w, wtpPl, 851968, 3328);
    proj_mfma<<<dim3(64, 2), 256, 0, stream>>>(cApl, cBpl, muqpl, wtpPl, proj_b, z_e, zpl);
    // phase 4: VQ
    split_rows<<<8192, 256, 0, stream>>>(codebook, cbpl, 2097152, 256);
    cnorm_kernel<<<2048, 256, 0, stream>>>(codebook, cnorm);
    vq_mfma3<<<dim3(64, 64), 256, 0, stream>>>(zpl, cbpl, cnorm, pmin, pidx);
    vq_finalize<<<2048, 256, 0, stream>>>(pmin, pidx, z_e, codebook, out, cpart);
    vq_reduce<<<1, 256, 0, stream>>>(cpart, out);
}

// Round 6
// 2041.021 us; speedup vs baseline: 1.6313x; 1.5436x over previous
//
#include <hip/hip_runtime.h>
#include <cstdint>
#include <cstddef>

typedef unsigned short u16;
typedef __attribute__((ext_vector_type(8))) short bf16x8;
typedef __attribute__((ext_vector_type(4))) float f32x4;
typedef unsigned int u32;
typedef __attribute__((address_space(1))) const u32 gu32;
typedef __attribute__((address_space(3))) u32 lu32;

__device__ __forceinline__ void gload_lds16(const void* g, void* l) {
    __builtin_amdgcn_global_load_lds((gu32*)g, (lu32*)l, 16, 0, 0);
}

__device__ __forceinline__ u16 f2bf(float v) {
    u32 u = __float_as_uint(v);
    return (u16)((u + 0x7fffu + ((u >> 16) & 1u)) >> 16);
}
__device__ __forceinline__ float bf2f(u16 h) { return __uint_as_float(((u32)h) << 16); }

__device__ __forceinline__ void split3(float f, u16& h1, u16& h2, u16& h3) {
    h1 = f2bf(f); float r = f - bf2f(h1);
    h2 = f2bf(r); r -= bf2f(h2);
    h3 = f2bf(r);
}

// 6-term emulated f32 product
__device__ __forceinline__ void mfma6(f32x4& c, bf16x8 a1, bf16x8 a2, bf16x8 a3,
                                      bf16x8 b1, bf16x8 b2, bf16x8 b3) {
    c = __builtin_amdgcn_mfma_f32_16x16x32_bf16(a1, b1, c, 0, 0, 0);
    c = __builtin_amdgcn_mfma_f32_16x16x32_bf16(a1, b2, c, 0, 0, 0);
    c = __builtin_amdgcn_mfma_f32_16x16x32_bf16(a2, b1, c, 0, 0, 0);
    c = __builtin_amdgcn_mfma_f32_16x16x32_bf16(a1, b3, c, 0, 0, 0);
    c = __builtin_amdgcn_mfma_f32_16x16x32_bf16(a3, b1, c, 0, 0, 0);
    c = __builtin_amdgcn_mfma_f32_16x16x32_bf16(a2, b2, c, 0, 0, 0);
}

// ---------------------------------------------------------------------------
// Weight prep -> k8 layout: plane[kg][o][8], kg = (kcv*I + i) >> 3.
// w (O, I, 4) f32.  Grid: O blocks; thread t < I/8 handles 8 i's, all kcv.
// ---------------------------------------------------------------------------
__global__ void split_weightT8(const float* __restrict__ w, u16* __restrict__ p0,
                               size_t pstr, int I, int O) {
    int o = blockIdx.x;
    int G = I >> 3;
    int t = threadIdx.x;
    if (t >= G) return;
    const float* wr = w + ((size_t)o * I + t * 8) * 4;
    float vals[32];
#pragma unroll
    for (int q = 0; q < 8; q++)
        *reinterpret_cast<float4*>(&vals[q * 4]) =
            *reinterpret_cast<const float4*>(&wr[q * 4]);
#pragma unroll
    for (int kcv = 0; kcv < 4; kcv++) {
        u16 h1[8], h2[8], h3[8];
#pragma unroll
        for (int q = 0; q < 8; q++)
            split3(vals[q * 4 + kcv], h1[q], h2[q], h3[q]);
        size_t dst = ((size_t)(kcv * G + t) * O + o) * 8;
        *reinterpret_cast<ushort4*>(&p0[dst])     = *reinterpret_cast<ushort4*>(&h1[0]);
        *reinterpret_cast<ushort4*>(&p0[dst + 4]) = *reinterpret_cast<ushort4*>(&h1[4]);
        *reinterpret_cast<ushort4*>(&p0[pstr + dst])     = *reinterpret_cast<ushort4*>(&h2[0]);
        *reinterpret_cast<ushort4*>(&p0[pstr + dst + 4]) = *reinterpret_cast<ushort4*>(&h2[4]);
        *reinterpret_cast<ushort4*>(&p0[2 * pstr + dst])     = *reinterpret_cast<ushort4*>(&h3[0]);
        *reinterpret_cast<ushort4*>(&p0[2 * pstr + dst + 4]) = *reinterpret_cast<ushort4*>(&h3[4]);
    }
}

// ---------------------------------------------------------------------------
// Activation prep -> k8 layout: plane[g][prow][8], g = i>>3, prow in (8,2050)
// padded rows (zero row before/after each batch).
// ---------------------------------------------------------------------------
__global__ void split_x8(const float* __restrict__ x, u16* __restrict__ p0,
                         size_t pstr, int I) {
    int pr = blockIdx.x;
    int b = pr / 2050, r = pr - b * 2050;
    int G = I >> 3;
    int t = threadIdx.x;
    if (t >= G) return;
    size_t dst = ((size_t)t * 16400 + pr) * 8;
    if (r == 0 || r == 2049) {
        ushort4 z = {0, 0, 0, 0};
        *reinterpret_cast<ushort4*>(&p0[dst]) = z;
        *reinterpret_cast<ushort4*>(&p0[dst + 4]) = z;
        *reinterpret_cast<ushort4*>(&p0[pstr + dst]) = z;
        *reinterpret_cast<ushort4*>(&p0[pstr + dst + 4]) = z;
        *reinterpret_cast<ushort4*>(&p0[2 * pstr + dst]) = z;
        *reinterpret_cast<ushort4*>(&p0[2 * pstr + dst + 4]) = z;
        return;
    }
    const float* src = x + (size_t)(b * 2048 + r - 1) * I + t * 8;
    float4 v0 = *reinterpret_cast<const float4*>(src);
    float4 v1 = *reinterpret_cast<const float4*>(src + 4);
    float vals[8] = {v0.x, v0.y, v0.z, v0.w, v1.x, v1.y, v1.z, v1.w};
    u16 h1[8], h2[8], h3[8];
#pragma unroll
    for (int q = 0; q < 8; q++) split3(vals[q], h1[q], h2[q], h3[q]);
    *reinterpret_cast<ushort4*>(&p0[dst])     = *reinterpret_cast<ushort4*>(&h1[0]);
    *reinterpret_cast<ushort4*>(&p0[dst + 4]) = *reinterpret_cast<ushort4*>(&h1[4]);
    *reinterpret_cast<ushort4*>(&p0[pstr + dst])     = *reinterpret_cast<ushort4*>(&h2[0]);
    *reinterpret_cast<ushort4*>(&p0[pstr + dst + 4]) = *reinterpret_cast<ushort4*>(&h2[4]);
    *reinterpret_cast<ushort4*>(&p0[2 * pstr + dst])     = *reinterpret_cast<ushort4*>(&h3[0]);
    *reinterpret_cast<ushort4*>(&p0[2 * pstr + dst + 4]) = *reinterpret_cast<ushort4*>(&h3[4]);
}

// ---------------------------------------------------------------------------
// Generic row split -> k8: in (R, C) f32 -> plane[g][r][8], g = c>>3.
// ---------------------------------------------------------------------------
__global__ void split_rows8(const float* __restrict__ in, u16* __restrict__ p0,
                            size_t pstr, int R, int C) {
    int r = blockIdx.x;
    int G = C >> 3;
    for (int t = threadIdx.x; t < G; t += 256) {
        const float* src = in + (size_t)r * C + t * 8;
        float4 v0 = *reinterpret_cast<const float4*>(src);
        float4 v1 = *reinterpret_cast<const float4*>(src + 4);
        float vals[8] = {v0.x, v0.y, v0.z, v0.w, v1.x, v1.y, v1.z, v1.w};
        u16 h1[8], h2[8], h3[8];
#pragma unroll
        for (int q = 0; q < 8; q++) split3(vals[q], h1[q], h2[q], h3[q]);
        size_t dst = ((size_t)t * R + r) * 8;
        *reinterpret_cast<ushort4*>(&p0[dst])     = *reinterpret_cast<ushort4*>(&h1[0]);
        *reinterpret_cast<ushort4*>(&p0[dst + 4]) = *reinterpret_cast<ushort4*>(&h1[4]);
        *reinterpret_cast<ushort4*>(&p0[pstr + dst])     = *reinterpret_cast<ushort4*>(&h2[0]);
        *reinterpret_cast<ushort4*>(&p0[pstr + dst + 4]) = *reinterpret_cast<ushort4*>(&h2[4]);
        *reinterpret_cast<ushort4*>(&p0[2 * pstr + dst])     = *reinterpret_cast<ushort4*>(&h3[0]);
        *reinterpret_cast<ushort4*>(&p0[2 * pstr + dst + 4]) = *reinterpret_cast<ushort4*>(&h3[4]);
    }
}

__global__ void cnorm_kernel(const float* __restrict__ cb, float* __restrict__ cn) {
    int w = threadIdx.x >> 6, lane = threadIdx.x & 63;
    int row = blockIdx.x * 4 + w;
    float4 v = *reinterpret_cast<const float4*>(&cb[(size_t)row * 256 + lane * 4]);
    float s = v.x * v.x + v.y * v.y + v.z * v.z + v.w * v.w;
#pragma unroll
    for (int off = 32; off; off >>= 1) s += __shfl_xor(s, off);
    if (lane == 0) cn[row] = s;
}

// ---------------------------------------------------------------------------
// Conv1d(k=4,s=2,p=1): 6-term MFMA, k8-coalesced gload_lds staging.
// A: x8[g][prow][8]; B: wt8[kg][o][8].  Output: k8 planes for proj.
// ---------------------------------------------------------------------------
__global__ __launch_bounds__(256, 3)
void conv_mfma4(const u16* __restrict__ xs, unsigned pstr_x,
                const u16* __restrict__ wt, unsigned pstr_w,
                const float* __restrict__ bias,
                u16* __restrict__ outp, unsigned pstr_o,
                int I, int O) {
    __shared__ u16 lds[24576];
    const int m0 = blockIdx.x << 7;
    const int n0 = blockIdx.y << 7;
    const int tid = threadIdx.x, lane = tid & 63, wv = tid >> 6;
    const int wr = ((wv >> 1) & 1) << 6, wc = (wv & 1) << 6;
    const int fr = lane & 15, fkg = lane >> 4;
    const int b = m0 >> 10, t0 = m0 & 1023;
    const int G = I >> 3;
    const int SL = 131200;                 // 16400*8, row-slice stride per g

    const u16* srcp[12];
    int dsto[12], inc[12], adj[12];
#pragma unroll
    for (int j = 0; j < 12; j++) {
        int ii = wv * 12 + j;
        int tile = ii >> 3, sub = ii & 7;
        int kg = sub >> 1, half = sub & 1;
        int r = half * 64 + lane;
        if (tile < 3) {
            srcp[j] = xs + (size_t)tile * pstr_x + (size_t)kg * SL +
                      (size_t)(b * 2050 + 2 * (t0 + r)) * 8;
            inc[j] = 4 * SL;
            adj[j] = 8 - (int)pstr_x;      // next tap: -G*SL + one prow
        } else {
            srcp[j] = wt + (size_t)(tile - 3) * pstr_w + (size_t)kg * O * 8 +
                      (size_t)(n0 + r) * 8;
            inc[j] = O * 32;
            adj[j] = 0;
        }
        dsto[j] = tile * 4096 + sub * 512;
    }

    f32x4 acc[4][4];
#pragma unroll
    for (int i = 0; i < 4; i++)
#pragma unroll
        for (int j = 0; j < 4; j++) acc[i][j] = (f32x4){0.f, 0.f, 0.f, 0.f};

    for (int kcv = 0; kcv < 4; kcv++) {
        for (int gi = 0; gi < G; gi += 4) {
#pragma unroll
            for (int j = 0; j < 12; j++) {
                gload_lds16(srcp[j], &lds[dsto[j]]);
                srcp[j] += inc[j];
            }
            __syncthreads();
            bf16x8 bfr[3][4];
#pragma unroll
            for (int p = 0; p < 3; p++)
#pragma unroll
                for (int fn = 0; fn < 4; fn++)
                    bfr[p][fn] = *reinterpret_cast<const bf16x8*>(
                        &lds[(3 + p) * 4096 + fkg * 1024 + (wc + fn * 16 + fr) * 8]);
#pragma unroll
            for (int fm = 0; fm < 4; fm++) {
                int aidx = fkg * 1024 + (wr + fm * 16 + fr) * 8;
                bf16x8 a1 = *reinterpret_cast<const bf16x8*>(&lds[aidx]);
                bf16x8 a2 = *reinterpret_cast<const bf16x8*>(&lds[4096 + aidx]);
                bf16x8 a3 = *reinterpret_cast<const bf16x8*>(&lds[8192 + aidx]);
#pragma unroll
                for (int fn = 0; fn < 4; fn++)
                    mfma6(acc[fm][fn], a1, a2, a3, bfr[0][fn], bfr[1][fn], bfr[2][fn]);
            }
            __syncthreads();
        }
#pragma unroll
        for (int j = 0; j < 12; j++) srcp[j] += adj[j];
    }
    // epilogue: bias add, split, write k8 planes [o>>3][m][8]
#pragma unroll
    for (int fm = 0; fm < 4; fm++) {
        int row0 = m0 + wr + fm * 16 + fkg * 4;
#pragma unroll
        for (int fn = 0; fn < 4; fn++) {
            int col = n0 + wc + fn * 16 + fr;
            float bv = bias[col];
            size_t cbase = ((size_t)(col >> 3) * 8192) * 8 + (col & 7);
#pragma unroll
            for (int j = 0; j < 4; j++) {
                float f = acc[fm][fn][j] + bv;
                u16 h1, h2, h3; split3(f, h1, h2, h3);
                size_t o = cbase + (size_t)(row0 + j) * 8;
                outp[o] = h1;
                outp[(size_t)pstr_o + o] = h2;
                outp[2 * (size_t)pstr_o + o] = h3;
            }
        }
    }
}

// ---------------------------------------------------------------------------
// Projection: 6-term MFMA over 3 k8 segments; writes z_e f32 + z8 planes.
// ---------------------------------------------------------------------------
__global__ __launch_bounds__(256, 3)
void proj_mfma4(const u16* __restrict__ sA, const u16* __restrict__ sB,
                const u16* __restrict__ sM, const u16* __restrict__ wp,
                const float* __restrict__ bias, float* __restrict__ z_e,
                u16* __restrict__ zpl) {
    __shared__ u16 lds[24576];
    const int m0 = blockIdx.x << 7;
    const int n0 = blockIdx.y << 7;
    const int tid = threadIdx.x, lane = tid & 63, wv = tid >> 6;
    const int wr = ((wv >> 1) & 1) << 6, wc = (wv & 1) << 6;
    const int fr = lane & 15, fkg = lane >> 4;

    const u16* srcp[12];
    int dsto[12];
#pragma unroll
    for (int j = 0; j < 12; j++) {
        int ii = wv * 12 + j;
        int tile = ii >> 3, sub = ii & 7;
        int kg = sub >> 1, half = sub & 1;
        int r = half * 64 + lane;
        if (tile >= 3)
            srcp[j] = wp + (size_t)(tile - 3) * 851968 + (size_t)kg * 2048 +
                      (size_t)(n0 + r) * 8;
        else
            srcp[j] = nullptr;
        dsto[j] = tile * 4096 + sub * 512;
    }

    f32x4 acc[4][4];
#pragma unroll
    for (int i = 0; i < 4; i++)
#pragma unroll
        for (int j = 0; j < 4; j++) acc[i][j] = (f32x4){0.f, 0.f, 0.f, 0.f};

    const u16* segp[3] = {sA, sB, sM};
    const int segG[3] = {160, 128, 128};
    const unsigned segP[3] = {10485760u, 8388608u, 8388608u};

    for (int seg = 0; seg < 3; seg++) {
        const u16* sp = segp[seg];
        const unsigned sps = segP[seg];
#pragma unroll
        for (int j = 0; j < 12; j++) {
            int ii = wv * 12 + j;
            int tile = ii >> 3, sub = ii & 7;
            int kg = sub >> 1, half = sub & 1;
            int r = half * 64 + lane;
            if (tile < 3)
                srcp[j] = sp + (size_t)tile * sps + (size_t)kg * 65536 +
                          (size_t)(m0 + r) * 8;
        }
        const int niter = segG[seg] >> 2;
        for (int it = 0; it < niter; it++) {
#pragma unroll
            for (int j = 0; j < 12; j++) {
                gload_lds16(srcp[j], &lds[dsto[j]]);
                int ii = wv * 12 + j;
                srcp[j] += (ii >> 3) < 3 ? 262144 : 8192;
            }
            __syncthreads();
            bf16x8 bfr[3][4];
#pragma unroll
            for (int p = 0; p < 3; p++)
#pragma unroll
                for (int fn = 0; fn < 4; fn++)
                    bfr[p][fn] = *reinterpret_cast<const bf16x8*>(
                        &lds[(3 + p) * 4096 + fkg * 1024 + (wc + fn * 16 + fr) * 8]);
#pragma unroll
            for (int fm = 0; fm < 4; fm++) {
                int aidx = fkg * 1024 + (wr + fm * 16 + fr) * 8;
                bf16x8 a1 = *reinterpret_cast<const bf16x8*>(&lds[aidx]);
                bf16x8 a2 = *reinterpret_cast<const bf16x8*>(&lds[4096 + aidx]);
                bf16x8 a3 = *reinterpret_cast<const bf16x8*>(&lds[8192 + aidx]);
#pragma unroll
                for (int fn = 0; fn < 4; fn++)
                    mfma6(acc[fm][fn], a1, a2, a3, bfr[0][fn], bfr[1][fn], bfr[2][fn]);
            }
            __syncthreads();
        }
    }
#pragma unroll
    for (int fm = 0; fm < 4; fm++) {
        int row0 = m0 + wr + fm * 16 + fkg * 4;
#pragma unroll
        for (int fn = 0; fn < 4; fn++) {
            int col = n0 + wc + fn * 16 + fr;
            float bv = bias[col];
            size_t cbase = ((size_t)(col >> 3) * 8192) * 8 + (col & 7);
#pragma unroll
            for (int j = 0; j < 4; j++) {
                float f = acc[fm][fn][j] + bv;
                z_e[(size_t)(row0 + j) * 256 + col] = f;
                u16 h1, h2, h3; split3(f, h1, h2, h3);
                size_t o = cbase + (size_t)(row0 + j) * 8;
                zpl[o] = h1;
                zpl[2097152 + o] = h2;
                zpl[4194304 + o] = h3;
            }
        }
    }
}

// ---------------------------------------------------------------------------
// VQ: 6-term MFMA (K=256, k8 planes) + f64 compare + LDS argmin epilogue.
// ---------------------------------------------------------------------------
__global__ __launch_bounds__(256, 3)
void vq_mfma4(const u16* __restrict__ zpl, const u16* __restrict__ cbpl,
              const float* __restrict__ cn, double* __restrict__ pmin,
              int* __restrict__ pidx) {
    __shared__ __align__(16) char smem[49152];
    u16* lds = (u16*)smem;
    const int m0 = blockIdx.x << 7;
    const int n0 = blockIdx.y << 7;
    const int tid = threadIdx.x, lane = tid & 63, wv = tid >> 6;
    const int wr = ((wv >> 1) & 1) << 6, wc = (wv & 1) << 6;
    const int fr = lane & 15, fkg = lane >> 4;

    const u16* srcp[12];
    int dsto[12];
#pragma unroll
    for (int j = 0; j < 12; j++) {
        int ii = wv * 12 + j;
        int tile = ii >> 3, sub = ii & 7;
        int kg = sub >> 1, half = sub & 1;
        int r = half * 64 + lane;
        if (tile < 3)
            srcp[j] = zpl + (size_t)tile * 2097152 + (size_t)kg * 65536 +
                      (size_t)(m0 + r) * 8;
        else
            srcp[j] = cbpl + (size_t)(tile - 3) * 2097152 + (size_t)kg * 65536 +
                      (size_t)(n0 + r) * 8;
        dsto[j] = tile * 4096 + sub * 512;
    }

    f32x4 acc[4][4];
#pragma unroll
    for (int i = 0; i < 4; i++)
#pragma unroll
        for (int j = 0; j < 4; j++) acc[i][j] = (f32x4){0.f, 0.f, 0.f, 0.f};

    for (int kt = 0; kt < 256; kt += 32) {
#pragma unroll
        for (int j = 0; j < 12; j++) {
            gload_lds16(srcp[j], &lds[dsto[j]]);
            srcp[j] += 262144;
        }
        __syncthreads();
        bf16x8 bfr[3][4];
#pragma unroll
        for (int p = 0; p < 3; p++)
#pragma unroll
            for (int fn = 0; fn < 4; fn++)
                bfr[p][fn] = *reinterpret_cast<const bf16x8*>(
                    &lds[(3 + p) * 4096 + fkg * 1024 + (wc + fn * 16 + fr) * 8]);
#pragma unroll
        for (int fm = 0; fm < 4; fm++) {
            int aidx = fkg * 1024 + (wr + fm * 16 + fr) * 8;
            bf16x8 a1 = *reinterpret_cast<const bf16x8*>(&lds[aidx]);
            bf16x8 a2 = *reinterpret_cast<const bf16x8*>(&lds[4096 + aidx]);
            bf16x8 a3 = *reinterpret_cast<const bf16x8*>(&lds[8192 + aidx]);
#pragma unroll
            for (int fn = 0; fn < 4; fn++)
                mfma6(acc[fm][fn], a1, a2, a3, bfr[0][fn], bfr[1][fn], bfr[2][fn]);
        }
        __syncthreads();
    }
    double (*red_d)[32] = (double (*)[32])smem;
    int (*red_n)[32] = (int (*)[32])(smem + 32768);
#pragma unroll
    for (int fm = 0; fm < 4; fm++)
#pragma unroll
        for (int j = 0; j < 4; j++) {
            double best = 1e300; int bestn = 0x7fffffff;
#pragma unroll
            for (int fn = 0; fn < 4; fn++) {
                int gn = n0 + wc + fn * 16 + fr;
                double d = (double)cn[gn] - 2.0 * (double)acc[fm][fn][j];
                if (d < best || (d == best && gn < bestn)) { best = d; bestn = gn; }
            }
            int row = wr + fm * 16 + fkg * 4 + j;
            int cand = ((wv & 1) << 4) + fr;
            red_d[row][cand] = best; red_n[row][cand] = bestn;
        }
    __syncthreads();
    if (tid < 128) {
        double best = red_d[tid][0]; int bestn = red_n[tid][0];
#pragma unroll 4
        for (int k = 1; k < 32; k++) {
            double d = red_d[tid][k]; int n2 = red_n[tid][k];
            if (d < best || (d == best && n2 < bestn)) { best = d; bestn = n2; }
        }
        size_t idx = (size_t)(m0 + tid) * 64 + (n0 >> 7);
        pmin[idx] = best; pidx[idx] = bestn;
    }
}

// ---------------------------------------------------------------------------
__global__ void vq_finalize(const double* __restrict__ pmin, const int* __restrict__ pidx,
                            const float* __restrict__ z, const float* __restrict__ cb,
                            float* __restrict__ out, double* __restrict__ cpart) {
    int w = threadIdx.x >> 6, lane = threadIdx.x & 63;
    int m = blockIdx.x * 4 + w;
    double d = pmin[(size_t)m * 64 + lane];
    int n = pidx[(size_t)m * 64 + lane];
#pragma unroll
    for (int off = 32; off; off >>= 1) {
        double d2 = __shfl_xor(d, off);
        int n2 = __shfl_xor(n, off);
        if (d2 < d || (d2 == d && n2 < n)) { d = d2; n = n2; }
    }
    float4 cv = *reinterpret_cast<const float4*>(&cb[(size_t)n * 256 + lane * 4]);
    float4 zv = *reinterpret_cast<const float4*>(&z[(size_t)m * 256 + lane * 4]);
    *reinterpret_cast<float4*>(&out[(size_t)m * 256 + lane * 4]) = cv;
    float dx = zv.x - cv.x, dy = zv.y - cv.y, dz = zv.z - cv.z, dw = zv.w - cv.w;
    double s = (double)(dx * dx) + (double)(dy * dy) + (double)(dz * dz) + (double)(dw * dw);
#pragma unroll
    for (int off = 32; off; off >>= 1) s += __shfl_xor(s, off);
    if (lane == 0) {
        out[2097152 + m] = (float)n;
        cpart[m] = s;
    }
}

__global__ void vq_reduce(const double* __restrict__ cpart, float* __restrict__ out) {
    __shared__ double sm[256];
    double s = 0.0;
    for (int i = threadIdx.x; i < 8192; i += 256) s += cpart[i];
    sm[threadIdx.x] = s;
    __syncthreads();
    for (int off = 128; off; off >>= 1) {
        if ((int)threadIdx.x < off) sm[threadIdx.x] += sm[threadIdx.x + off];
        __syncthreads();
    }
    if (threadIdx.x == 0) out[2105344] = (float)(sm[0] / 2097152.0);
}

// ---------------------------------------------------------------------------
extern "C" void kernel_launch(void* const* d_in, const int* in_sizes, int n_in,
                              void* d_out, int out_size, void* d_ws, size_t ws_size,
                              hipStream_t stream) {
    (void)in_sizes; (void)n_in; (void)out_size; (void)ws_size;
    const float* whisper   = (const float*)d_in[0];
    const float* wavlm     = (const float*)d_in[1];
    const float* muq       = (const float*)d_in[2];
    const float* w_conv_w  = (const float*)d_in[3];
    const float* w_conv_b  = (const float*)d_in[4];
    const float* wl_conv_w = (const float*)d_in[5];
    const float* wl_conv_b = (const float*)d_in[6];
    const float* proj_w    = (const float*)d_in[7];
    const float* proj_b    = (const float*)d_in[8];
    const float* codebook  = (const float*)d_in[9];
    float* out = (float*)d_out;
    char* wsb = (char*)d_ws;

    // ---- workspace layout (bytes), same footprint as round 5 ----
    u16*   xsA   = (u16*)(wsb + 0);            // 3 planes, pstr 20,992,000 elems
    u16*   wtbA  = (u16*)(wsb + 125952000);    // 3 planes, pstr 6,553,600
    u16*   cApl  = (u16*)(wsb + 176259072);    // 3 planes, pstr 10,485,760
    u16*   xsB   = (u16*)(wsb + 0);            // pstr 16,793,600
    u16*   wtbB  = (u16*)(wsb + 100761600);    // pstr 4,194,304
    u16*   cBpl  = (u16*)(wsb + 125927424);    // pstr 8,388,608
    u16*   muqpl = (u16*)(wsb + 0);            // pstr 8,388,608
    u16*   wtpPl = (u16*)(wsb + 50331648);     // pstr 851,968
    float* z_e   = (float*)(wsb + 55443456);   // 8192*256 f32
    u16*   zpl   = (u16*)(wsb + 63832064);     // pstr 2,097,152
    u16*   cbpl  = (u16*)(wsb + 76414976);     // pstr 2,097,152
    float* cnorm = (float*)(wsb + 88997888);
    double* pmin = (double*)(wsb + 89030656);
    int*    pidx = (int*)(wsb + 93224960);
    double* cpart= (double*)(wsb + 95322112);

    // phase 1: whisper conv
    split_x8<<<16400, 256, 0, stream>>>(whisper, xsA, 20992000, 1280);
    split_weightT8<<<1280, 256, 0, stream>>>(w_conv_w, wtbA, 6553600, 1280, 1280);
    conv_mfma4<<<dim3(64, 10), 256, 0, stream>>>(xsA, 20992000, wtbA, 6553600,
                                                 w_conv_b, cApl, 10485760, 1280, 1280);
    // phase 2: wavlm conv (reuses xsA/wtbA region)
    split_x8<<<16400, 256, 0, stream>>>(wavlm, xsB, 16793600, 1024);
    split_weightT8<<<1024, 256, 0, stream>>>(wl_conv_w, wtbB, 4194304, 1024, 1024);
    conv_mfma4<<<dim3(64, 8), 256, 0, stream>>>(xsB, 16793600, wtbB, 4194304,
                                                wl_conv_b, cBpl, 8388608, 1024, 1024);
    // phase 3: projection
    split_rows8<<<8192, 256, 0, stream>>>(muq, muqpl, 8388608, 8192, 1024);
    split_rows8<<<256, 256, 0, stream>>>(proj_w, wtpPl, 851968, 256, 3328);
    proj_mfma4<<<dim3(64, 2), 256, 0, stream>>>(cApl, cBpl, muqpl, wtpPl, proj_b, z_e, zpl);
    // phase 4: VQ
    split_rows8<<<8192, 256, 0, stream>>>(codebook, cbpl, 2097152, 8192, 256);
    cnorm_kernel<<<2048, 256, 0, stream>>>(codebook, cnorm);
    vq_mfma4<<<dim3(64, 64), 256, 0, stream>>>(zpl, cbpl, cnorm, pmin, pidx);
    vq_finalize<<<2048, 256, 0, stream>>>(pmin, pidx, z_e, codebook, out, cpart);
    vq_reduce<<<1, 256, 0, stream>>>(cpart, out);
}

// Round 7
// 1737.347 us; speedup vs baseline: 1.9165x; 1.1748x over previous
//
#include <hip/hip_runtime.h>
#include <cstdint>
#include <cstddef>

typedef unsigned short u16;
typedef __attribute__((ext_vector_type(8))) short bf16x8;
typedef __attribute__((ext_vector_type(4))) float f32x4;
typedef unsigned int u32;
typedef __attribute__((address_space(1))) const u32 gu32;
typedef __attribute__((address_space(3))) u32 lu32;

__device__ __forceinline__ void gload_lds16(const void* g, void* l) {
    __builtin_amdgcn_global_load_lds((gu32*)g, (lu32*)l, 16, 0, 0);
}

__device__ __forceinline__ u16 f2bf(float v) {
    u32 u = __float_as_uint(v);
    return (u16)((u + 0x7fffu + ((u >> 16) & 1u)) >> 16);
}
__device__ __forceinline__ float bf2f(u16 h) { return __uint_as_float(((u32)h) << 16); }

__device__ __forceinline__ void split3(float f, u16& h1, u16& h2, u16& h3) {
    h1 = f2bf(f); float r = f - bf2f(h1);
    h2 = f2bf(r); r -= bf2f(h2);
    h3 = f2bf(r);
}

// 6-term emulated f32 product
__device__ __forceinline__ void mfma6(f32x4& c, bf16x8 a1, bf16x8 a2, bf16x8 a3,
                                      bf16x8 b1, bf16x8 b2, bf16x8 b3) {
    c = __builtin_amdgcn_mfma_f32_16x16x32_bf16(a1, b1, c, 0, 0, 0);
    c = __builtin_amdgcn_mfma_f32_16x16x32_bf16(a1, b2, c, 0, 0, 0);
    c = __builtin_amdgcn_mfma_f32_16x16x32_bf16(a2, b1, c, 0, 0, 0);
    c = __builtin_amdgcn_mfma_f32_16x16x32_bf16(a1, b3, c, 0, 0, 0);
    c = __builtin_amdgcn_mfma_f32_16x16x32_bf16(a3, b1, c, 0, 0, 0);
    c = __builtin_amdgcn_mfma_f32_16x16x32_bf16(a2, b2, c, 0, 0, 0);
}

// ---------------------------------------------------------------------------
// Weight prep -> k8 layout: plane[kg][o][8], kg = (kcv*I + i) >> 3.
// ---------------------------------------------------------------------------
__global__ void split_weightT8(const float* __restrict__ w, u16* __restrict__ p0,
                               size_t pstr, int I, int O) {
    int o = blockIdx.x;
    int G = I >> 3;
    int t = threadIdx.x;
    if (t >= G) return;
    const float* wr = w + ((size_t)o * I + t * 8) * 4;
    float vals[32];
#pragma unroll
    for (int q = 0; q < 8; q++)
        *reinterpret_cast<float4*>(&vals[q * 4]) =
            *reinterpret_cast<const float4*>(&wr[q * 4]);
#pragma unroll
    for (int kcv = 0; kcv < 4; kcv++) {
        u16 h1[8], h2[8], h3[8];
#pragma unroll
        for (int q = 0; q < 8; q++)
            split3(vals[q * 4 + kcv], h1[q], h2[q], h3[q]);
        size_t dst = ((size_t)(kcv * G + t) * O + o) * 8;
        *reinterpret_cast<ushort4*>(&p0[dst])     = *reinterpret_cast<ushort4*>(&h1[0]);
        *reinterpret_cast<ushort4*>(&p0[dst + 4]) = *reinterpret_cast<ushort4*>(&h1[4]);
        *reinterpret_cast<ushort4*>(&p0[pstr + dst])     = *reinterpret_cast<ushort4*>(&h2[0]);
        *reinterpret_cast<ushort4*>(&p0[pstr + dst + 4]) = *reinterpret_cast<ushort4*>(&h2[4]);
        *reinterpret_cast<ushort4*>(&p0[2 * pstr + dst])     = *reinterpret_cast<ushort4*>(&h3[0]);
        *reinterpret_cast<ushort4*>(&p0[2 * pstr + dst + 4]) = *reinterpret_cast<ushort4*>(&h3[4]);
    }
}

// ---------------------------------------------------------------------------
// Activation prep -> parity k8 layout: plane[g][b][parity][1025][8].
// prow = s+1 (s = input row; prow 0 and 2049 are zero pads).
// parity = prow&1, idx = prow>>1.  Tap kcv reads parity kcv&1 at t+(kcv>>1):
// contiguous in t -> fully coalesced conv A staging.
// ---------------------------------------------------------------------------
__global__ void split_x8p(const float* __restrict__ x, u16* __restrict__ p0,
                          size_t pstr, int I) {
    int pr = blockIdx.x;
    int b = pr / 2050, prow = pr - b * 2050;
    int G = I >> 3;
    int t = threadIdx.x;
    if (t >= G) return;
    int parity = prow & 1, idx = prow >> 1;
    size_t dst = ((size_t)t * 16400 + b * 2050 + parity * 1025 + idx) * 8;
    if (prow == 0 || prow == 2049) {
        ushort4 z = {0, 0, 0, 0};
        *reinterpret_cast<ushort4*>(&p0[dst]) = z;
        *reinterpret_cast<ushort4*>(&p0[dst + 4]) = z;
        *reinterpret_cast<ushort4*>(&p0[pstr + dst]) = z;
        *reinterpret_cast<ushort4*>(&p0[pstr + dst + 4]) = z;
        *reinterpret_cast<ushort4*>(&p0[2 * pstr + dst]) = z;
        *reinterpret_cast<ushort4*>(&p0[2 * pstr + dst + 4]) = z;
        return;
    }
    const float* src = x + (size_t)(b * 2048 + prow - 1) * I + t * 8;
    float4 v0 = *reinterpret_cast<const float4*>(src);
    float4 v1 = *reinterpret_cast<const float4*>(src + 4);
    float vals[8] = {v0.x, v0.y, v0.z, v0.w, v1.x, v1.y, v1.z, v1.w};
    u16 h1[8], h2[8], h3[8];
#pragma unroll
    for (int q = 0; q < 8; q++) split3(vals[q], h1[q], h2[q], h3[q]);
    *reinterpret_cast<ushort4*>(&p0[dst])     = *reinterpret_cast<ushort4*>(&h1[0]);
    *reinterpret_cast<ushort4*>(&p0[dst + 4]) = *reinterpret_cast<ushort4*>(&h1[4]);
    *reinterpret_cast<ushort4*>(&p0[pstr + dst])     = *reinterpret_cast<ushort4*>(&h2[0]);
    *reinterpret_cast<ushort4*>(&p0[pstr + dst + 4]) = *reinterpret_cast<ushort4*>(&h2[4]);
    *reinterpret_cast<ushort4*>(&p0[2 * pstr + dst])     = *reinterpret_cast<ushort4*>(&h3[0]);
    *reinterpret_cast<ushort4*>(&p0[2 * pstr + dst + 4]) = *reinterpret_cast<ushort4*>(&h3[4]);
}

// ---------------------------------------------------------------------------
// Generic row split -> k8: in (R, C) f32 -> plane[g][r][8], g = c>>3.
// ---------------------------------------------------------------------------
__global__ void split_rows8(const float* __restrict__ in, u16* __restrict__ p0,
                            size_t pstr, int R, int C) {
    int r = blockIdx.x;
    int G = C >> 3;
    for (int t = threadIdx.x; t < G; t += 256) {
        const float* src = in + (size_t)r * C + t * 8;
        float4 v0 = *reinterpret_cast<const float4*>(src);
        float4 v1 = *reinterpret_cast<const float4*>(src + 4);
        float vals[8] = {v0.x, v0.y, v0.z, v0.w, v1.x, v1.y, v1.z, v1.w};
        u16 h1[8], h2[8], h3[8];
#pragma unroll
        for (int q = 0; q < 8; q++) split3(vals[q], h1[q], h2[q], h3[q]);
        size_t dst = ((size_t)t * R + r) * 8;
        *reinterpret_cast<ushort4*>(&p0[dst])     = *reinterpret_cast<ushort4*>(&h1[0]);
        *reinterpret_cast<ushort4*>(&p0[dst + 4]) = *reinterpret_cast<ushort4*>(&h1[4]);
        *reinterpret_cast<ushort4*>(&p0[pstr + dst])     = *reinterpret_cast<ushort4*>(&h2[0]);
        *reinterpret_cast<ushort4*>(&p0[pstr + dst + 4]) = *reinterpret_cast<ushort4*>(&h2[4]);
        *reinterpret_cast<ushort4*>(&p0[2 * pstr + dst])     = *reinterpret_cast<ushort4*>(&h3[0]);
        *reinterpret_cast<ushort4*>(&p0[2 * pstr + dst + 4]) = *reinterpret_cast<ushort4*>(&h3[4]);
    }
}

__global__ void cnorm_kernel(const float* __restrict__ cb, float* __restrict__ cn) {
    int w = threadIdx.x >> 6, lane = threadIdx.x & 63;
    int row = blockIdx.x * 4 + w;
    float4 v = *reinterpret_cast<const float4*>(&cb[(size_t)row * 256 + lane * 4]);
    float s = v.x * v.x + v.y * v.y + v.z * v.z + v.w * v.w;
#pragma unroll
    for (int off = 32; off; off >>= 1) s += __shfl_xor(s, off);
    if (lane == 0) cn[row] = s;
}

// ---------------------------------------------------------------------------
// Conv1d(k=4,s=2,p=1): 6-term MFMA, fully-coalesced gload_lds staging.
// A: parity k8 planes; B: wt8[kg][o][8].  Coalesced LDS epilogue.
// ---------------------------------------------------------------------------
__global__ __launch_bounds__(256, 3)
void conv_mfma5(const u16* __restrict__ xs, unsigned pstr_x,
                const u16* __restrict__ wt, unsigned pstr_w,
                const float* __restrict__ bias,
                u16* __restrict__ outp, unsigned pstr_o,
                int I, int O) {
    __shared__ u16 lds[24576];
    const int m0 = blockIdx.x << 7;
    const int n0 = blockIdx.y << 7;
    const int tid = threadIdx.x, lane = tid & 63, wv = tid >> 6;
    const int wr = ((wv >> 1) & 1) << 6, wc = (wv & 1) << 6;
    const int fr = lane & 15, fkg = lane >> 4;
    const int b = m0 >> 10, t0 = m0 & 1023;
    const int G = I >> 3;
    const int SL = 131200;                 // 16400*8, slice stride per g

    const u16* srcp[12];
    int dsto[12], inc[12];
#pragma unroll
    for (int j = 0; j < 12; j++) {
        int ii = wv * 12 + j;
        int tile = ii >> 3, sub = ii & 7;
        int kg = sub >> 1, half = sub & 1;
        int r = half * 64 + lane;
        if (tile < 3) {
            // kcv=0: parity 0, ofs 0 -> entry b*2050 + (t0+r)
            srcp[j] = xs + (size_t)tile * pstr_x + (size_t)kg * SL +
                      (size_t)(b * 2050 + t0 + r) * 8;
            inc[j] = 4 * SL;
        } else {
            srcp[j] = wt + (size_t)(tile - 3) * pstr_w + (size_t)kg * O * 8 +
                      (size_t)(n0 + r) * 8;
            inc[j] = O * 32;
        }
        dsto[j] = tile * 4096 + sub * 512;
    }

    f32x4 acc[4][4];
#pragma unroll
    for (int i = 0; i < 4; i++)
#pragma unroll
        for (int j = 0; j < 4; j++) acc[i][j] = (f32x4){0.f, 0.f, 0.f, 0.f};

    for (int kcv = 0; kcv < 4; kcv++) {
        for (int gi = 0; gi < G; gi += 4) {
#pragma unroll
            for (int j = 0; j < 12; j++) {
                gload_lds16(srcp[j], &lds[dsto[j]]);
                srcp[j] += inc[j];
            }
            __syncthreads();
            bf16x8 bfr[3][4];
#pragma unroll
            for (int p = 0; p < 3; p++)
#pragma unroll
                for (int fn = 0; fn < 4; fn++)
                    bfr[p][fn] = *reinterpret_cast<const bf16x8*>(
                        &lds[(3 + p) * 4096 + fkg * 1024 + (wc + fn * 16 + fr) * 8]);
#pragma unroll
            for (int fm = 0; fm < 4; fm++) {
                int aidx = fkg * 1024 + (wr + fm * 16 + fr) * 8;
                bf16x8 a1 = *reinterpret_cast<const bf16x8*>(&lds[aidx]);
                bf16x8 a2 = *reinterpret_cast<const bf16x8*>(&lds[4096 + aidx]);
                bf16x8 a3 = *reinterpret_cast<const bf16x8*>(&lds[8192 + aidx]);
#pragma unroll
                for (int fn = 0; fn < 4; fn++)
                    mfma6(acc[fm][fn], a1, a2, a3, bfr[0][fn], bfr[1][fn], bfr[2][fn]);
            }
            __syncthreads();
        }
        if (kcv < 3) {
            // A planes: back G slices, switch parity/offset
            int d = ((kcv == 1) ? -8192 : 8200) - (int)pstr_x;
#pragma unroll
            for (int j = 0; j < 12; j++)
                if (((wv * 12 + j) >> 3) < 3) srcp[j] += d;
        }
    }
    // ---- coalesced epilogue: per fm-slab, stage 3 planes in LDS, 16B stores
    u16 (*eld)[32][132] = (u16 (*)[32][132])lds;   // 25,344 B
    float bv[4];
#pragma unroll
    for (int fn = 0; fn < 4; fn++) bv[fn] = bias[n0 + wc + fn * 16 + fr];
    const int srb = (wr >> 6) * 16 + fkg * 4;      // slab row base
#pragma unroll
    for (int fm = 0; fm < 4; fm++) {
#pragma unroll
        for (int fn = 0; fn < 4; fn++) {
            int cl = wc + fn * 16 + fr;
#pragma unroll
            for (int j = 0; j < 4; j++) {
                float f = acc[fm][fn][j] + bv[fn];
                u16 h1, h2, h3; split3(f, h1, h2, h3);
                eld[0][srb + j][cl] = h1;
                eld[1][srb + j][cl] = h2;
                eld[2][srb + j][cl] = h3;
            }
        }
        __syncthreads();
#pragma unroll
        for (int q = 0; q < 6; q++) {
            int e = q * 256 + tid;
            int g = e / 96, rem = e - g * 96;
            int p = rem >> 5, sr = rem & 31;
            bf16x8 vv = *reinterpret_cast<const bf16x8*>(&eld[p][sr][g * 8]);
            int rowg = m0 + ((sr >> 4) << 6) + fm * 16 + (sr & 15);
            size_t addr = (size_t)p * pstr_o +
                          (size_t)((n0 >> 3) + g) * 65536 + (size_t)rowg * 8;
            *reinterpret_cast<bf16x8*>(&outp[addr]) = vv;
        }
        __syncthreads();
    }
}

// ---------------------------------------------------------------------------
// Projection: 6-term MFMA over 3 k8 segments; z_e f32 + coalesced zpl planes.
// ---------------------------------------------------------------------------
__global__ __launch_bounds__(256, 3)
void proj_mfma5(const u16* __restrict__ sA, const u16* __restrict__ sB,
                const u16* __restrict__ sM, const u16* __restrict__ wp,
                const float* __restrict__ bias, float* __restrict__ z_e,
                u16* __restrict__ zpl) {
    __shared__ u16 lds[24576];
    const int m0 = blockIdx.x << 7;
    const int n0 = blockIdx.y << 7;
    const int tid = threadIdx.x, lane = tid & 63, wv = tid >> 6;
    const int wr = ((wv >> 1) & 1) << 6, wc = (wv & 1) << 6;
    const int fr = lane & 15, fkg = lane >> 4;

    const u16* srcp[12];
    int dsto[12];
#pragma unroll
    for (int j = 0; j < 12; j++) {
        int ii = wv * 12 + j;
        int tile = ii >> 3, sub = ii & 7;
        int kg = sub >> 1, half = sub & 1;
        int r = half * 64 + lane;
        if (tile >= 3)
            srcp[j] = wp + (size_t)(tile - 3) * 851968 + (size_t)kg * 2048 +
                      (size_t)(n0 + r) * 8;
        else
            srcp[j] = nullptr;
        dsto[j] = tile * 4096 + sub * 512;
    }

    f32x4 acc[4][4];
#pragma unroll
    for (int i = 0; i < 4; i++)
#pragma unroll
        for (int j = 0; j < 4; j++) acc[i][j] = (f32x4){0.f, 0.f, 0.f, 0.f};

    const u16* segp[3] = {sA, sB, sM};
    const int segG[3] = {160, 128, 128};
    const unsigned segP[3] = {10485760u, 8388608u, 8388608u};

    for (int seg = 0; seg < 3; seg++) {
        const u16* sp = segp[seg];
        const unsigned sps = segP[seg];
#pragma unroll
        for (int j = 0; j < 12; j++) {
            int ii = wv * 12 + j;
            int tile = ii >> 3, sub = ii & 7;
            int kg = sub >> 1, half = sub & 1;
            int r = half * 64 + lane;
            if (tile < 3)
                srcp[j] = sp + (size_t)tile * sps + (size_t)kg * 65536 +
                          (size_t)(m0 + r) * 8;
        }
        const int niter = segG[seg] >> 2;
        for (int it = 0; it < niter; it++) {
#pragma unroll
            for (int j = 0; j < 12; j++) {
                gload_lds16(srcp[j], &lds[dsto[j]]);
                int ii = wv * 12 + j;
                srcp[j] += (ii >> 3) < 3 ? 262144 : 8192;
            }
            __syncthreads();
            bf16x8 bfr[3][4];
#pragma unroll
            for (int p = 0; p < 3; p++)
#pragma unroll
                for (int fn = 0; fn < 4; fn++)
                    bfr[p][fn] = *reinterpret_cast<const bf16x8*>(
                        &lds[(3 + p) * 4096 + fkg * 1024 + (wc + fn * 16 + fr) * 8]);
#pragma unroll
            for (int fm = 0; fm < 4; fm++) {
                int aidx = fkg * 1024 + (wr + fm * 16 + fr) * 8;
                bf16x8 a1 = *reinterpret_cast<const bf16x8*>(&lds[aidx]);
                bf16x8 a2 = *reinterpret_cast<const bf16x8*>(&lds[4096 + aidx]);
                bf16x8 a3 = *reinterpret_cast<const bf16x8*>(&lds[8192 + aidx]);
#pragma unroll
                for (int fn = 0; fn < 4; fn++)
                    mfma6(acc[fm][fn], a1, a2, a3, bfr[0][fn], bfr[1][fn], bfr[2][fn]);
            }
            __syncthreads();
        }
    }
    // ---- epilogue: z_e f32 direct + coalesced zpl planes via LDS
    u16 (*eld)[32][132] = (u16 (*)[32][132])lds;
    float bv[4];
#pragma unroll
    for (int fn = 0; fn < 4; fn++) bv[fn] = bias[n0 + wc + fn * 16 + fr];
    const int srb = (wr >> 6) * 16 + fkg * 4;
#pragma unroll
    for (int fm = 0; fm < 4; fm++) {
#pragma unroll
        for (int fn = 0; fn < 4; fn++) {
            int cl = wc + fn * 16 + fr;
            int col = n0 + cl;
#pragma unroll
            for (int j = 0; j < 4; j++) {
                float f = acc[fm][fn][j] + bv[fn];
                int rowg = m0 + wr + fm * 16 + fkg * 4 + j;
                z_e[(size_t)rowg * 256 + col] = f;
                u16 h1, h2, h3; split3(f, h1, h2, h3);
                eld[0][srb + j][cl] = h1;
                eld[1][srb + j][cl] = h2;
                eld[2][srb + j][cl] = h3;
            }
        }
        __syncthreads();
#pragma unroll
        for (int q = 0; q < 6; q++) {
            int e = q * 256 + tid;
            int g = e / 96, rem = e - g * 96;
            int p = rem >> 5, sr = rem & 31;
            bf16x8 vv = *reinterpret_cast<const bf16x8*>(&eld[p][sr][g * 8]);
            int rowg = m0 + ((sr >> 4) << 6) + fm * 16 + (sr & 15);
            size_t addr = (size_t)p * 2097152 +
                          (size_t)((n0 >> 3) + g) * 65536 + (size_t)rowg * 8;
            *reinterpret_cast<bf16x8*>(&zpl[addr]) = vv;
        }
        __syncthreads();
    }
}

// ---------------------------------------------------------------------------
// VQ: 6-term MFMA (K=256, k8 planes) + f64 compare + LDS argmin epilogue.
// ---------------------------------------------------------------------------
__global__ __launch_bounds__(256, 3)
void vq_mfma4(const u16* __restrict__ zpl, const u16* __restrict__ cbpl,
              const float* __restrict__ cn, double* __restrict__ pmin,
              int* __restrict__ pidx) {
    __shared__ __align__(16) char smem[49152];
    u16* lds = (u16*)smem;
    const int m0 = blockIdx.x << 7;
    const int n0 = blockIdx.y << 7;
    const int tid = threadIdx.x, lane = tid & 63, wv = tid >> 6;
    const int wr = ((wv >> 1) & 1) << 6, wc = (wv & 1) << 6;
    const int fr = lane & 15, fkg = lane >> 4;

    const u16* srcp[12];
    int dsto[12];
#pragma unroll
    for (int j = 0; j < 12; j++) {
        int ii = wv * 12 + j;
        int tile = ii >> 3, sub = ii & 7;
        int kg = sub >> 1, half = sub & 1;
        int r = half * 64 + lane;
        if (tile < 3)
            srcp[j] = zpl + (size_t)tile * 2097152 + (size_t)kg * 65536 +
                      (size_t)(m0 + r) * 8;
        else
            srcp[j] = cbpl + (size_t)(tile - 3) * 2097152 + (size_t)kg * 65536 +
                      (size_t)(n0 + r) * 8;
        dsto[j] = tile * 4096 + sub * 512;
    }

    f32x4 acc[4][4];
#pragma unroll
    for (int i = 0; i < 4; i++)
#pragma unroll
        for (int j = 0; j < 4; j++) acc[i][j] = (f32x4){0.f, 0.f, 0.f, 0.f};

    for (int kt = 0; kt < 256; kt += 32) {
#pragma unroll
        for (int j = 0; j < 12; j++) {
            gload_lds16(srcp[j], &lds[dsto[j]]);
            srcp[j] += 262144;
        }
        __syncthreads();
        bf16x8 bfr[3][4];
#pragma unroll
        for (int p = 0; p < 3; p++)
#pragma unroll
            for (int fn = 0; fn < 4; fn++)
                bfr[p][fn] = *reinterpret_cast<const bf16x8*>(
                    &lds[(3 + p) * 4096 + fkg * 1024 + (wc + fn * 16 + fr) * 8]);
#pragma unroll
        for (int fm = 0; fm < 4; fm++) {
            int aidx = fkg * 1024 + (wr + fm * 16 + fr) * 8;
            bf16x8 a1 = *reinterpret_cast<const bf16x8*>(&lds[aidx]);
            bf16x8 a2 = *reinterpret_cast<const bf16x8*>(&lds[4096 + aidx]);
            bf16x8 a3 = *reinterpret_cast<const bf16x8*>(&lds[8192 + aidx]);
#pragma unroll
            for (int fn = 0; fn < 4; fn++)
                mfma6(acc[fm][fn], a1, a2, a3, bfr[0][fn], bfr[1][fn], bfr[2][fn]);
        }
        __syncthreads();
    }
    double (*red_d)[32] = (double (*)[32])smem;
    int (*red_n)[32] = (int (*)[32])(smem + 32768);
#pragma unroll
    for (int fm = 0; fm < 4; fm++)
#pragma unroll
        for (int j = 0; j < 4; j++) {
            double best = 1e300; int bestn = 0x7fffffff;
#pragma unroll
            for (int fn = 0; fn < 4; fn++) {
                int gn = n0 + wc + fn * 16 + fr;
                double d = (double)cn[gn] - 2.0 * (double)acc[fm][fn][j];
                if (d < best || (d == best && gn < bestn)) { best = d; bestn = gn; }
            }
            int row = wr + fm * 16 + fkg * 4 + j;
            int cand = ((wv & 1) << 4) + fr;
            red_d[row][cand] = best; red_n[row][cand] = bestn;
        }
    __syncthreads();
    if (tid < 128) {
        double best = red_d[tid][0]; int bestn = red_n[tid][0];
#pragma unroll 4
        for (int k = 1; k < 32; k++) {
            double d = red_d[tid][k]; int n2 = red_n[tid][k];
            if (d < best || (d == best && n2 < bestn)) { best = d; bestn = n2; }
        }
        size_t idx = (size_t)(m0 + tid) * 64 + (n0 >> 7);
        pmin[idx] = best; pidx[idx] = bestn;
    }
}

// ---------------------------------------------------------------------------
__global__ void vq_finalize(const double* __restrict__ pmin, const int* __restrict__ pidx,
                            const float* __restrict__ z, const float* __restrict__ cb,
                            float* __restrict__ out, double* __restrict__ cpart) {
    int w = threadIdx.x >> 6, lane = threadIdx.x & 63;
    int m = blockIdx.x * 4 + w;
    double d = pmin[(size_t)m * 64 + lane];
    int n = pidx[(size_t)m * 64 + lane];
#pragma unroll
    for (int off = 32; off; off >>= 1) {
        double d2 = __shfl_xor(d, off);
        int n2 = __shfl_xor(n, off);
        if (d2 < d || (d2 == d && n2 < n)) { d = d2; n = n2; }
    }
    float4 cv = *reinterpret_cast<const float4*>(&cb[(size_t)n * 256 + lane * 4]);
    float4 zv = *reinterpret_cast<const float4*>(&z[(size_t)m * 256 + lane * 4]);
    *reinterpret_cast<float4*>(&out[(size_t)m * 256 + lane * 4]) = cv;
    float dx = zv.x - cv.x, dy = zv.y - cv.y, dz = zv.z - cv.z, dw = zv.w - cv.w;
    double s = (double)(dx * dx) + (double)(dy * dy) + (double)(dz * dz) + (double)(dw * dw);
#pragma unroll
    for (int off = 32; off; off >>= 1) s += __shfl_xor(s, off);
    if (lane == 0) {
        out[2097152 + m] = (float)n;
        cpart[m] = s;
    }
}

__global__ void vq_reduce(const double* __restrict__ cpart, float* __restrict__ out) {
    __shared__ double sm[256];
    double s = 0.0;
    for (int i = threadIdx.x; i < 8192; i += 256) s += cpart[i];
    sm[threadIdx.x] = s;
    __syncthreads();
    for (int off = 128; off; off >>= 1) {
        if ((int)threadIdx.x < off) sm[threadIdx.x] += sm[threadIdx.x + off];
        __syncthreads();
    }
    if (threadIdx.x == 0) out[2105344] = (float)(sm[0] / 2097152.0);
}

// ---------------------------------------------------------------------------
extern "C" void kernel_launch(void* const* d_in, const int* in_sizes, int n_in,
                              void* d_out, int out_size, void* d_ws, size_t ws_size,
                              hipStream_t stream) {
    (void)in_sizes; (void)n_in; (void)out_size; (void)ws_size;
    const float* whisper   = (const float*)d_in[0];
    const float* wavlm     = (const float*)d_in[1];
    const float* muq       = (const float*)d_in[2];
    const float* w_conv_w  = (const float*)d_in[3];
    const float* w_conv_b  = (const float*)d_in[4];
    const float* wl_conv_w = (const float*)d_in[5];
    const float* wl_conv_b = (const float*)d_in[6];
    const float* proj_w    = (const float*)d_in[7];
    const float* proj_b    = (const float*)d_in[8];
    const float* codebook  = (const float*)d_in[9];
    float* out = (float*)d_out;
    char* wsb = (char*)d_ws;

    // ---- workspace layout (bytes), same footprint as round 6 ----
    u16*   xsA   = (u16*)(wsb + 0);            // 3 planes, pstr 20,992,000 elems
    u16*   wtbA  = (u16*)(wsb + 125952000);    // 3 planes, pstr 6,553,600
    u16*   cApl  = (u16*)(wsb + 176259072);    // 3 planes, pstr 10,485,760
    u16*   xsB   = (u16*)(wsb + 0);            // pstr 16,793,600
    u16*   wtbB  = (u16*)(wsb + 100761600);    // pstr 4,194,304
    u16*   cBpl  = (u16*)(wsb + 125927424);    // pstr 8,388,608
    u16*   muqpl = (u16*)(wsb + 0);            // pstr 8,388,608
    u16*   wtpPl = (u16*)(wsb + 50331648);     // pstr 851,968
    float* z_e   = (float*)(wsb + 55443456);   // 8192*256 f32
    u16*   zpl   = (u16*)(wsb + 63832064);     // pstr 2,097,152
    u16*   cbpl  = (u16*)(wsb + 76414976);     // pstr 2,097,152
    float* cnorm = (float*)(wsb + 88997888);
    double* pmin = (double*)(wsb + 89030656);
    int*    pidx = (int*)(wsb + 93224960);
    double* cpart= (double*)(wsb + 95322112);

    // phase 1: whisper conv
    split_x8p<<<16400, 256, 0, stream>>>(whisper, xsA, 20992000, 1280);
    split_weightT8<<<1280, 256, 0, stream>>>(w_conv_w, wtbA, 6553600, 1280, 1280);
    conv_mfma5<<<dim3(64, 10), 256, 0, stream>>>(xsA, 20992000, wtbA, 6553600,
                                                 w_conv_b, cApl, 10485760, 1280, 1280);
    // phase 2: wavlm conv (reuses xsA/wtbA region)
    split_x8p<<<16400, 256, 0, stream>>>(wavlm, xsB, 16793600, 1024);
    split_weightT8<<<1024, 256, 0, stream>>>(wl_conv_w, wtbB, 4194304, 1024, 1024);
    conv_mfma5<<<dim3(64, 8), 256, 0, stream>>>(xsB, 16793600, wtbB, 4194304,
                                                wl_conv_b, cBpl, 8388608, 1024, 1024);
    // phase 3: projection
    split_rows8<<<8192, 256, 0, stream>>>(muq, muqpl, 8388608, 8192, 1024);
    split_rows8<<<256, 256, 0, stream>>>(proj_w, wtpPl, 851968, 256, 3328);
    proj_mfma5<<<dim3(64, 2), 256, 0, stream>>>(cApl, cBpl, muqpl, wtpPl, proj_b, z_e, zpl);
    // phase 4: VQ
    split_rows8<<<8192, 256, 0, stream>>>(codebook, cbpl, 2097152, 8192, 256);
    cnorm_kernel<<<2048, 256, 0, stream>>>(codebook, cnorm);
    vq_mfma4<<<dim3(64, 64), 256, 0, stream>>>(zpl, cbpl, cnorm, pmin, pidx);
    vq_finalize<<<2048, 256, 0, stream>>>(pmin, pidx, z_e, codebook, out, cpart);
    vq_reduce<<<1, 256, 0, stream>>>(cpart, out);
}

// Round 8
// 1620.807 us; speedup vs baseline: 2.0543x; 1.0719x over previous
//
#include <hip/hip_runtime.h>
#include <cstdint>
#include <cstddef>

typedef unsigned short u16;
typedef __attribute__((ext_vector_type(8))) short bf16x8;
typedef __attribute__((ext_vector_type(4))) float f32x4;
typedef unsigned int u32;
typedef __attribute__((address_space(1))) const u32 gu32;
typedef __attribute__((address_space(3))) u32 lu32;

__device__ __forceinline__ void gload_lds16(const void* g, void* l) {
    __builtin_amdgcn_global_load_lds((gu32*)g, (lu32*)l, 16, 0, 0);
}

__device__ __forceinline__ u16 f2bf(float v) {
    u32 u = __float_as_uint(v);
    return (u16)((u + 0x7fffu + ((u >> 16) & 1u)) >> 16);
}
__device__ __forceinline__ float bf2f(u16 h) { return __uint_as_float(((u32)h) << 16); }

__device__ __forceinline__ void split3(float f, u16& h1, u16& h2, u16& h3) {
    h1 = f2bf(f); float r = f - bf2f(h1);
    h2 = f2bf(r); r -= bf2f(h2);
    h3 = f2bf(r);
}

// 6-term emulated f32 product
__device__ __forceinline__ void mfma6(f32x4& c, bf16x8 a1, bf16x8 a2, bf16x8 a3,
                                      bf16x8 b1, bf16x8 b2, bf16x8 b3) {
    c = __builtin_amdgcn_mfma_f32_16x16x32_bf16(a1, b1, c, 0, 0, 0);
    c = __builtin_amdgcn_mfma_f32_16x16x32_bf16(a1, b2, c, 0, 0, 0);
    c = __builtin_amdgcn_mfma_f32_16x16x32_bf16(a2, b1, c, 0, 0, 0);
    c = __builtin_amdgcn_mfma_f32_16x16x32_bf16(a1, b3, c, 0, 0, 0);
    c = __builtin_amdgcn_mfma_f32_16x16x32_bf16(a3, b1, c, 0, 0, 0);
    c = __builtin_amdgcn_mfma_f32_16x16x32_bf16(a2, b2, c, 0, 0, 0);
}

// ---------------------------------------------------------------------------
// Weight prep -> k8 layout: plane[kg][o][8], kg = (kcv*I + i) >> 3.
// ---------------------------------------------------------------------------
__global__ void split_weightT8(const float* __restrict__ w, u16* __restrict__ p0,
                               size_t pstr, int I, int O) {
    int o = blockIdx.x;
    int G = I >> 3;
    int t = threadIdx.x;
    if (t >= G) return;
    const float* wr = w + ((size_t)o * I + t * 8) * 4;
    float vals[32];
#pragma unroll
    for (int q = 0; q < 8; q++)
        *reinterpret_cast<float4*>(&vals[q * 4]) =
            *reinterpret_cast<const float4*>(&wr[q * 4]);
#pragma unroll
    for (int kcv = 0; kcv < 4; kcv++) {
        u16 h1[8], h2[8], h3[8];
#pragma unroll
        for (int q = 0; q < 8; q++)
            split3(vals[q * 4 + kcv], h1[q], h2[q], h3[q]);
        size_t dst = ((size_t)(kcv * G + t) * O + o) * 8;
        *reinterpret_cast<ushort4*>(&p0[dst])     = *reinterpret_cast<ushort4*>(&h1[0]);
        *reinterpret_cast<ushort4*>(&p0[dst + 4]) = *reinterpret_cast<ushort4*>(&h1[4]);
        *reinterpret_cast<ushort4*>(&p0[pstr + dst])     = *reinterpret_cast<ushort4*>(&h2[0]);
        *reinterpret_cast<ushort4*>(&p0[pstr + dst + 4]) = *reinterpret_cast<ushort4*>(&h2[4]);
        *reinterpret_cast<ushort4*>(&p0[2 * pstr + dst])     = *reinterpret_cast<ushort4*>(&h3[0]);
        *reinterpret_cast<ushort4*>(&p0[2 * pstr + dst + 4]) = *reinterpret_cast<ushort4*>(&h3[4]);
    }
}

// ---------------------------------------------------------------------------
// Activation prep -> parity k8 layout: plane[g][b][parity][1025][8].
// ---------------------------------------------------------------------------
__global__ void split_x8p(const float* __restrict__ x, u16* __restrict__ p0,
                          size_t pstr, int I) {
    int pr = blockIdx.x;
    int b = pr / 2050, prow = pr - b * 2050;
    int G = I >> 3;
    int t = threadIdx.x;
    if (t >= G) return;
    int parity = prow & 1, idx = prow >> 1;
    size_t dst = ((size_t)t * 16400 + b * 2050 + parity * 1025 + idx) * 8;
    if (prow == 0 || prow == 2049) {
        ushort4 z = {0, 0, 0, 0};
        *reinterpret_cast<ushort4*>(&p0[dst]) = z;
        *reinterpret_cast<ushort4*>(&p0[dst + 4]) = z;
        *reinterpret_cast<ushort4*>(&p0[pstr + dst]) = z;
        *reinterpret_cast<ushort4*>(&p0[pstr + dst + 4]) = z;
        *reinterpret_cast<ushort4*>(&p0[2 * pstr + dst]) = z;
        *reinterpret_cast<ushort4*>(&p0[2 * pstr + dst + 4]) = z;
        return;
    }
    const float* src = x + (size_t)(b * 2048 + prow - 1) * I + t * 8;
    float4 v0 = *reinterpret_cast<const float4*>(src);
    float4 v1 = *reinterpret_cast<const float4*>(src + 4);
    float vals[8] = {v0.x, v0.y, v0.z, v0.w, v1.x, v1.y, v1.z, v1.w};
    u16 h1[8], h2[8], h3[8];
#pragma unroll
    for (int q = 0; q < 8; q++) split3(vals[q], h1[q], h2[q], h3[q]);
    *reinterpret_cast<ushort4*>(&p0[dst])     = *reinterpret_cast<ushort4*>(&h1[0]);
    *reinterpret_cast<ushort4*>(&p0[dst + 4]) = *reinterpret_cast<ushort4*>(&h1[4]);
    *reinterpret_cast<ushort4*>(&p0[pstr + dst])     = *reinterpret_cast<ushort4*>(&h2[0]);
    *reinterpret_cast<ushort4*>(&p0[pstr + dst + 4]) = *reinterpret_cast<ushort4*>(&h2[4]);
    *reinterpret_cast<ushort4*>(&p0[2 * pstr + dst])     = *reinterpret_cast<ushort4*>(&h3[0]);
    *reinterpret_cast<ushort4*>(&p0[2 * pstr + dst + 4]) = *reinterpret_cast<ushort4*>(&h3[4]);
}

// ---------------------------------------------------------------------------
// Generic row split -> k8: in (R, C) f32 -> plane[g][r][8], g = c>>3.
// ---------------------------------------------------------------------------
__global__ void split_rows8(const float* __restrict__ in, u16* __restrict__ p0,
                            size_t pstr, int R, int C) {
    int r = blockIdx.x;
    int G = C >> 3;
    for (int t = threadIdx.x; t < G; t += 256) {
        const float* src = in + (size_t)r * C + t * 8;
        float4 v0 = *reinterpret_cast<const float4*>(src);
        float4 v1 = *reinterpret_cast<const float4*>(src + 4);
        float vals[8] = {v0.x, v0.y, v0.z, v0.w, v1.x, v1.y, v1.z, v1.w};
        u16 h1[8], h2[8], h3[8];
#pragma unroll
        for (int q = 0; q < 8; q++) split3(vals[q], h1[q], h2[q], h3[q]);
        size_t dst = ((size_t)t * R + r) * 8;
        *reinterpret_cast<ushort4*>(&p0[dst])     = *reinterpret_cast<ushort4*>(&h1[0]);
        *reinterpret_cast<ushort4*>(&p0[dst + 4]) = *reinterpret_cast<ushort4*>(&h1[4]);
        *reinterpret_cast<ushort4*>(&p0[pstr + dst])     = *reinterpret_cast<ushort4*>(&h2[0]);
        *reinterpret_cast<ushort4*>(&p0[pstr + dst + 4]) = *reinterpret_cast<ushort4*>(&h2[4]);
        *reinterpret_cast<ushort4*>(&p0[2 * pstr + dst])     = *reinterpret_cast<ushort4*>(&h3[0]);
        *reinterpret_cast<ushort4*>(&p0[2 * pstr + dst + 4]) = *reinterpret_cast<ushort4*>(&h3[4]);
    }
}

__global__ void cnorm_kernel(const float* __restrict__ cb, float* __restrict__ cn) {
    int w = threadIdx.x >> 6, lane = threadIdx.x & 63;
    int row = blockIdx.x * 4 + w;
    float4 v = *reinterpret_cast<const float4*>(&cb[(size_t)row * 256 + lane * 4]);
    float s = v.x * v.x + v.y * v.y + v.z * v.z + v.w * v.w;
#pragma unroll
    for (int off = 32; off; off >>= 1) s += __shfl_xor(s, off);
    if (lane == 0) cn[row] = s;
}

// ---------------------------------------------------------------------------
// Conv1d(k=4,s=2,p=1): 6-term MFMA, 2-phase double-buffered LDS (planes 1,2
// via global_load_lds) + 3rd-plane fragments direct global->register.
// Per iter: ds_read frags(buf cur) -> issue 8 gloads(buf cur^1) -> direct
// a3/b3 loads -> 96 MFMA -> syncthreads (drain lands after MFMA).
// ---------------------------------------------------------------------------
__global__ __launch_bounds__(256, 2)
void conv_mfma6(const u16* __restrict__ xs, unsigned pstr_x,
                const u16* __restrict__ wt, unsigned pstr_w,
                const float* __restrict__ bias,
                u16* __restrict__ outp, unsigned pstr_o,
                int I, int O) {
    __shared__ u16 lds[32768];                 // 2 x 32KB buffers
    const int m0 = blockIdx.x << 7;
    const int n0 = blockIdx.y << 7;
    const int tid = threadIdx.x, lane = tid & 63, wv = tid >> 6;
    const int wr = ((wv >> 1) & 1) << 6, wc = (wv & 1) << 6;
    const int fr = lane & 15, fkg = lane >> 4;
    const int b = m0 >> 10, t0 = m0 & 1023;
    const int G = I >> 3;
    const int SL = 131200;                     // 16400*8, slice stride per g
    const int NIT = G;                         // K/32 iterations total
    const int npt = G >> 2;                    // iters per conv tap

    // staging: wave wv owns plane wv (0,1 = A planes 1,2; 2,3 = B planes 1,2)
    const u16* srcp[8];
    int dsto[8];
    int inc;
#pragma unroll
    for (int j = 0; j < 8; j++) {
        int kg = j >> 1, half = j & 1;
        int r = half * 64 + lane;
        if (wv < 2) {
            srcp[j] = xs + (size_t)wv * pstr_x + (size_t)kg * SL +
                      (size_t)(b * 2050 + t0 + r) * 8;
        } else {
            srcp[j] = wt + (size_t)(wv - 2) * pstr_w + (size_t)kg * (O * 8) +
                      (size_t)(n0 + r) * 8;
        }
        dsto[j] = wv * 4096 + j * 512;
    }
    inc = (wv < 2) ? 4 * SL : O * 32;

    // direct 3rd-plane pointers (per-lane)
    const u16* pa3 = xs + 2 * (size_t)pstr_x + (size_t)fkg * SL +
                     (size_t)(b * 2050 + t0 + wr + fr) * 8;
    const u16* pb3 = wt + 2 * (size_t)pstr_w + (size_t)fkg * (O * 8) +
                     (size_t)(n0 + wc + fr) * 8;

    f32x4 acc[4][4];
#pragma unroll
    for (int i = 0; i < 4; i++)
#pragma unroll
        for (int j = 0; j < 4; j++) acc[i][j] = (f32x4){0.f, 0.f, 0.f, 0.f};

    // prologue: stage iter 0 into buffer 0
#pragma unroll
    for (int j = 0; j < 8; j++) {
        gload_lds16(srcp[j], &lds[dsto[j]]);
        srcp[j] += inc;
    }
    __syncthreads();

    int scnt = npt - 1, skcv = 0;   // stage stream tap tracking (A waves)
    int dcnt = npt, dkcv = 0;       // direct-a3 stream tap tracking
    int cur = 0;

    for (int it = 0; it < NIT; ++it) {
        // 1. LDS -> regs (before any gload_lds this iter)
        const u16* lb = &lds[cur * 16384];
        bf16x8 a1[4], a2[4], b1[4], b2[4];
#pragma unroll
        for (int fm = 0; fm < 4; fm++) {
            int aidx = fkg * 1024 + (wr + fm * 16 + fr) * 8;
            a1[fm] = *reinterpret_cast<const bf16x8*>(lb + aidx);
            a2[fm] = *reinterpret_cast<const bf16x8*>(lb + 4096 + aidx);
        }
#pragma unroll
        for (int fn = 0; fn < 4; fn++) {
            int bidx = fkg * 1024 + (wc + fn * 16 + fr) * 8;
            b1[fn] = *reinterpret_cast<const bf16x8*>(lb + 8192 + bidx);
            b2[fn] = *reinterpret_cast<const bf16x8*>(lb + 12288 + bidx);
        }
        // 2. stage next iter into other buffer
        if (it + 1 < NIT) {
#pragma unroll
            for (int j = 0; j < 8; j++) {
                gload_lds16(srcp[j], &lds[(cur ^ 1) * 16384 + dsto[j]]);
                srcp[j] += inc;
            }
            if (wv < 2) {
                if (--scnt == 0) {
                    int d = ((skcv == 1) ? -8192 : 8200) - (int)pstr_x;
#pragma unroll
                    for (int j = 0; j < 8; j++) srcp[j] += d;
                    skcv++; scnt = npt;
                }
            }
        }
        // 3. direct 3rd-plane fragment loads for this iter
        bf16x8 da3[4], db3[4];
#pragma unroll
        for (int fm = 0; fm < 4; fm++)
            da3[fm] = *reinterpret_cast<const bf16x8*>(pa3 + fm * 128);
#pragma unroll
        for (int fn = 0; fn < 4; fn++)
            db3[fn] = *reinterpret_cast<const bf16x8*>(pb3 + fn * 128);
        pa3 += 4 * SL;
        pb3 += O * 32;
        if (--dcnt == 0) {
            pa3 += ((dkcv == 1) ? -8192 : 8200) - (int)pstr_x;
            dkcv++; dcnt = npt;
        }
        // 4. MFMA (96)
#pragma unroll
        for (int fm = 0; fm < 4; fm++)
#pragma unroll
            for (int fn = 0; fn < 4; fn++)
                mfma6(acc[fm][fn], a1[fm], a2[fm], da3[fm],
                      b1[fn], b2[fn], db3[fn]);
        // 5. sync (drains staging loads issued above; they overlapped MFMA)
        __syncthreads();
        cur ^= 1;
    }

    // ---- coalesced epilogue: per fm-slab, stage 3 planes in LDS, 16B stores
    u16 (*eld)[32][132] = (u16 (*)[32][132])lds;   // 25,344 B
    float bv[4];
#pragma unroll
    for (int fn = 0; fn < 4; fn++) bv[fn] = bias[n0 + wc + fn * 16 + fr];
    const int srb = (wr >> 6) * 16 + fkg * 4;      // slab row base
#pragma unroll
    for (int fm = 0; fm < 4; fm++) {
#pragma unroll
        for (int fn = 0; fn < 4; fn++) {
            int cl = wc + fn * 16 + fr;
#pragma unroll
            for (int j = 0; j < 4; j++) {
                float f = acc[fm][fn][j] + bv[fn];
                u16 h1, h2, h3; split3(f, h1, h2, h3);
                eld[0][srb + j][cl] = h1;
                eld[1][srb + j][cl] = h2;
                eld[2][srb + j][cl] = h3;
            }
        }
        __syncthreads();
#pragma unroll
        for (int q = 0; q < 6; q++) {
            int e = q * 256 + tid;
            int g = e / 96, rem = e - g * 96;
            int p = rem >> 5, sr = rem & 31;
            bf16x8 vv = *reinterpret_cast<const bf16x8*>(&eld[p][sr][g * 8]);
            int rowg = m0 + ((sr >> 4) << 6) + fm * 16 + (sr & 15);
            size_t addr = (size_t)p * pstr_o +
                          (size_t)((n0 >> 3) + g) * 65536 + (size_t)rowg * 8;
            *reinterpret_cast<bf16x8*>(&outp[addr]) = vv;
        }
        __syncthreads();
    }
}

// ---------------------------------------------------------------------------
// Projection: 6-term MFMA over 3 k8 segments; z_e f32 + coalesced zpl planes.
// ---------------------------------------------------------------------------
__global__ __launch_bounds__(256, 3)
void proj_mfma5(const u16* __restrict__ sA, const u16* __restrict__ sB,
                const u16* __restrict__ sM, const u16* __restrict__ wp,
                const float* __restrict__ bias, float* __restrict__ z_e,
                u16* __restrict__ zpl) {
    __shared__ u16 lds[24576];
    const int m0 = blockIdx.x << 7;
    const int n0 = blockIdx.y << 7;
    const int tid = threadIdx.x, lane = tid & 63, wv = tid >> 6;
    const int wr = ((wv >> 1) & 1) << 6, wc = (wv & 1) << 6;
    const int fr = lane & 15, fkg = lane >> 4;

    const u16* srcp[12];
    int dsto[12];
#pragma unroll
    for (int j = 0; j < 12; j++) {
        int ii = wv * 12 + j;
        int tile = ii >> 3, sub = ii & 7;
        int kg = sub >> 1, half = sub & 1;
        int r = half * 64 + lane;
        if (tile >= 3)
            srcp[j] = wp + (size_t)(tile - 3) * 851968 + (size_t)kg * 2048 +
                      (size_t)(n0 + r) * 8;
        else
            srcp[j] = nullptr;
        dsto[j] = tile * 4096 + sub * 512;
    }

    f32x4 acc[4][4];
#pragma unroll
    for (int i = 0; i < 4; i++)
#pragma unroll
        for (int j = 0; j < 4; j++) acc[i][j] = (f32x4){0.f, 0.f, 0.f, 0.f};

    const u16* segp[3] = {sA, sB, sM};
    const int segG[3] = {160, 128, 128};
    const unsigned segP[3] = {10485760u, 8388608u, 8388608u};

    for (int seg = 0; seg < 3; seg++) {
        const u16* sp = segp[seg];
        const unsigned sps = segP[seg];
#pragma unroll
        for (int j = 0; j < 12; j++) {
            int ii = wv * 12 + j;
            int tile = ii >> 3, sub = ii & 7;
            int kg = sub >> 1, half = sub & 1;
            int r = half * 64 + lane;
            if (tile < 3)
                srcp[j] = sp + (size_t)tile * sps + (size_t)kg * 65536 +
                          (size_t)(m0 + r) * 8;
        }
        const int niter = segG[seg] >> 2;
        for (int it = 0; it < niter; it++) {
#pragma unroll
            for (int j = 0; j < 12; j++) {
                gload_lds16(srcp[j], &lds[dsto[j]]);
                int ii = wv * 12 + j;
                srcp[j] += (ii >> 3) < 3 ? 262144 : 8192;
            }
            __syncthreads();
            bf16x8 bfr[3][4];
#pragma unroll
            for (int p = 0; p < 3; p++)
#pragma unroll
                for (int fn = 0; fn < 4; fn++)
                    bfr[p][fn] = *reinterpret_cast<const bf16x8*>(
                        &lds[(3 + p) * 4096 + fkg * 1024 + (wc + fn * 16 + fr) * 8]);
#pragma unroll
            for (int fm = 0; fm < 4; fm++) {
                int aidx = fkg * 1024 + (wr + fm * 16 + fr) * 8;
                bf16x8 a1 = *reinterpret_cast<const bf16x8*>(&lds[aidx]);
                bf16x8 a2 = *reinterpret_cast<const bf16x8*>(&lds[4096 + aidx]);
                bf16x8 a3 = *reinterpret_cast<const bf16x8*>(&lds[8192 + aidx]);
#pragma unroll
                for (int fn = 0; fn < 4; fn++)
                    mfma6(acc[fm][fn], a1, a2, a3, bfr[0][fn], bfr[1][fn], bfr[2][fn]);
            }
            __syncthreads();
        }
    }
    // ---- epilogue: z_e f32 direct + coalesced zpl planes via LDS
    u16 (*eld)[32][132] = (u16 (*)[32][132])lds;
    float bv[4];
#pragma unroll
    for (int fn = 0; fn < 4; fn++) bv[fn] = bias[n0 + wc + fn * 16 + fr];
    const int srb = (wr >> 6) * 16 + fkg * 4;
#pragma unroll
    for (int fm = 0; fm < 4; fm++) {
#pragma unroll
        for (int fn = 0; fn < 4; fn++) {
            int cl = wc + fn * 16 + fr;
            int col = n0 + cl;
#pragma unroll
            for (int j = 0; j < 4; j++) {
                float f = acc[fm][fn][j] + bv[fn];
                int rowg = m0 + wr + fm * 16 + fkg * 4 + j;
                z_e[(size_t)rowg * 256 + col] = f;
                u16 h1, h2, h3; split3(f, h1, h2, h3);
                eld[0][srb + j][cl] = h1;
                eld[1][srb + j][cl] = h2;
                eld[2][srb + j][cl] = h3;
            }
        }
        __syncthreads();
#pragma unroll
        for (int q = 0; q < 6; q++) {
            int e = q * 256 + tid;
            int g = e / 96, rem = e - g * 96;
            int p = rem >> 5, sr = rem & 31;
            bf16x8 vv = *reinterpret_cast<const bf16x8*>(&eld[p][sr][g * 8]);
            int rowg = m0 + ((sr >> 4) << 6) + fm * 16 + (sr & 15);
            size_t addr = (size_t)p * 2097152 +
                          (size_t)((n0 >> 3) + g) * 65536 + (size_t)rowg * 8;
            *reinterpret_cast<bf16x8*>(&zpl[addr]) = vv;
        }
        __syncthreads();
    }
}

// ---------------------------------------------------------------------------
// VQ: 6-term MFMA (K=256, k8 planes) + f64 compare + LDS argmin epilogue.
// ---------------------------------------------------------------------------
__global__ __launch_bounds__(256, 3)
void vq_mfma4(const u16* __restrict__ zpl, const u16* __restrict__ cbpl,
              const float* __restrict__ cn, double* __restrict__ pmin,
              int* __restrict__ pidx) {
    __shared__ __align__(16) char smem[49152];
    u16* lds = (u16*)smem;
    const int m0 = blockIdx.x << 7;
    const int n0 = blockIdx.y << 7;
    const int tid = threadIdx.x, lane = tid & 63, wv = tid >> 6;
    const int wr = ((wv >> 1) & 1) << 6, wc = (wv & 1) << 6;
    const int fr = lane & 15, fkg = lane >> 4;

    const u16* srcp[12];
    int dsto[12];
#pragma unroll
    for (int j = 0; j < 12; j++) {
        int ii = wv * 12 + j;
        int tile = ii >> 3, sub = ii & 7;
        int kg = sub >> 1, half = sub & 1;
        int r = half * 64 + lane;
        if (tile < 3)
            srcp[j] = zpl + (size_t)tile * 2097152 + (size_t)kg * 65536 +
                      (size_t)(m0 + r) * 8;
        else
            srcp[j] = cbpl + (size_t)(tile - 3) * 2097152 + (size_t)kg * 65536 +
                      (size_t)(n0 + r) * 8;
        dsto[j] = tile * 4096 + sub * 512;
    }

    f32x4 acc[4][4];
#pragma unroll
    for (int i = 0; i < 4; i++)
#pragma unroll
        for (int j = 0; j < 4; j++) acc[i][j] = (f32x4){0.f, 0.f, 0.f, 0.f};

    for (int kt = 0; kt < 256; kt += 32) {
#pragma unroll
        for (int j = 0; j < 12; j++) {
            gload_lds16(srcp[j], &lds[dsto[j]]);
            srcp[j] += 262144;
        }
        __syncthreads();
        bf16x8 bfr[3][4];
#pragma unroll
        for (int p = 0; p < 3; p++)
#pragma unroll
            for (int fn = 0; fn < 4; fn++)
                bfr[p][fn] = *reinterpret_cast<const bf16x8*>(
                    &lds[(3 + p) * 4096 + fkg * 1024 + (wc + fn * 16 + fr) * 8]);
#pragma unroll
        for (int fm = 0; fm < 4; fm++) {
            int aidx = fkg * 1024 + (wr + fm * 16 + fr) * 8;
            bf16x8 a1 = *reinterpret_cast<const bf16x8*>(&lds[aidx]);
            bf16x8 a2 = *reinterpret_cast<const bf16x8*>(&lds[4096 + aidx]);
            bf16x8 a3 = *reinterpret_cast<const bf16x8*>(&lds[8192 + aidx]);
#pragma unroll
            for (int fn = 0; fn < 4; fn++)
                mfma6(acc[fm][fn], a1, a2, a3, bfr[0][fn], bfr[1][fn], bfr[2][fn]);
        }
        __syncthreads();
    }
    double (*red_d)[32] = (double (*)[32])smem;
    int (*red_n)[32] = (int (*)[32])(smem + 32768);
#pragma unroll
    for (int fm = 0; fm < 4; fm++)
#pragma unroll
        for (int j = 0; j < 4; j++) {
            double best = 1e300; int bestn = 0x7fffffff;
#pragma unroll
            for (int fn = 0; fn < 4; fn++) {
                int gn = n0 + wc + fn * 16 + fr;
                double d = (double)cn[gn] - 2.0 * (double)acc[fm][fn][j];
                if (d < best || (d == best && gn < bestn)) { best = d; bestn = gn; }
            }
            int row = wr + fm * 16 + fkg * 4 + j;
            int cand = ((wv & 1) << 4) + fr;
            red_d[row][cand] = best; red_n[row][cand] = bestn;
        }
    __syncthreads();
    if (tid < 128) {
        double best = red_d[tid][0]; int bestn = red_n[tid][0];
#pragma unroll 4
        for (int k = 1; k < 32; k++) {
            double d = red_d[tid][k]; int n2 = red_n[tid][k];
            if (d < best || (d == best && n2 < bestn)) { best = d; bestn = n2; }
        }
        size_t idx = (size_t)(m0 + tid) * 64 + (n0 >> 7);
        pmin[idx] = best; pidx[idx] = bestn;
    }
}

// ---------------------------------------------------------------------------
__global__ void vq_finalize(const double* __restrict__ pmin, const int* __restrict__ pidx,
                            const float* __restrict__ z, const float* __restrict__ cb,
                            float* __restrict__ out, double* __restrict__ cpart) {
    int w = threadIdx.x >> 6, lane = threadIdx.x & 63;
    int m = blockIdx.x * 4 + w;
    double d = pmin[(size_t)m * 64 + lane];
    int n = pidx[(size_t)m * 64 + lane];
#pragma unroll
    for (int off = 32; off; off >>= 1) {
        double d2 = __shfl_xor(d, off);
        int n2 = __shfl_xor(n, off);
        if (d2 < d || (d2 == d && n2 < n)) { d = d2; n = n2; }
    }
    float4 cv = *reinterpret_cast<const float4*>(&cb[(size_t)n * 256 + lane * 4]);
    float4 zv = *reinterpret_cast<const float4*>(&z[(size_t)m * 256 + lane * 4]);
    *reinterpret_cast<float4*>(&out[(size_t)m * 256 + lane * 4]) = cv;
    float dx = zv.x - cv.x, dy = zv.y - cv.y, dz = zv.z - cv.z, dw = zv.w - cv.w;
    double s = (double)(dx * dx) + (double)(dy * dy) + (double)(dz * dz) + (double)(dw * dw);
#pragma unroll
    for (int off = 32; off; off >>= 1) s += __shfl_xor(s, off);
    if (lane == 0) {
        out[2097152 + m] = (float)n;
        cpart[m] = s;
    }
}

__global__ void vq_reduce(const double* __restrict__ cpart, float* __restrict__ out) {
    __shared__ double sm[256];
    double s = 0.0;
    for (int i = threadIdx.x; i < 8192; i += 256) s += cpart[i];
    sm[threadIdx.x] = s;
    __syncthreads();
    for (int off = 128; off; off >>= 1) {
        if ((int)threadIdx.x < off) sm[threadIdx.x] += sm[threadIdx.x + off];
        __syncthreads();
    }
    if (threadIdx.x == 0) out[2105344] = (float)(sm[0] / 2097152.0);
}

// ---------------------------------------------------------------------------
extern "C" void kernel_launch(void* const* d_in, const int* in_sizes, int n_in,
                              void* d_out, int out_size, void* d_ws, size_t ws_size,
                              hipStream_t stream) {
    (void)in_sizes; (void)n_in; (void)out_size; (void)ws_size;
    const float* whisper   = (const float*)d_in[0];
    const float* wavlm     = (const float*)d_in[1];
    const float* muq       = (const float*)d_in[2];
    const float* w_conv_w  = (const float*)d_in[3];
    const float* w_conv_b  = (const float*)d_in[4];
    const float* wl_conv_w = (const float*)d_in[5];
    const float* wl_conv_b = (const float*)d_in[6];
    const float* proj_w    = (const float*)d_in[7];
    const float* proj_b    = (const float*)d_in[8];
    const float* codebook  = (const float*)d_in[9];
    float* out = (float*)d_out;
    char* wsb = (char*)d_ws;

    // ---- workspace layout (bytes), same footprint as round 7 ----
    u16*   xsA   = (u16*)(wsb + 0);            // 3 planes, pstr 20,992,000 elems
    u16*   wtbA  = (u16*)(wsb + 125952000);    // 3 planes, pstr 6,553,600
    u16*   cApl  = (u16*)(wsb + 176259072);    // 3 planes, pstr 10,485,760
    u16*   xsB   = (u16*)(wsb + 0);            // pstr 16,793,600
    u16*   wtbB  = (u16*)(wsb + 100761600);    // pstr 4,194,304
    u16*   cBpl  = (u16*)(wsb + 125927424);    // pstr 8,388,608
    u16*   muqpl = (u16*)(wsb + 0);            // pstr 8,388,608
    u16*   wtpPl = (u16*)(wsb + 50331648);     // pstr 851,968
    float* z_e   = (float*)(wsb + 55443456);   // 8192*256 f32
    u16*   zpl   = (u16*)(wsb + 63832064);     // pstr 2,097,152
    u16*   cbpl  = (u16*)(wsb + 76414976);     // pstr 2,097,152
    float* cnorm = (float*)(wsb + 88997888);
    double* pmin = (double*)(wsb + 89030656);
    int*    pidx = (int*)(wsb + 93224960);
    double* cpart= (double*)(wsb + 95322112);

    // phase 1: whisper conv
    split_x8p<<<16400, 256, 0, stream>>>(whisper, xsA, 20992000, 1280);
    split_weightT8<<<1280, 256, 0, stream>>>(w_conv_w, wtbA, 6553600, 1280, 1280);
    conv_mfma6<<<dim3(64, 10), 256, 0, stream>>>(xsA, 20992000, wtbA, 6553600,
                                                 w_conv_b, cApl, 10485760, 1280, 1280);
    // phase 2: wavlm conv (reuses xsA/wtbA region)
    split_x8p<<<16400, 256, 0, stream>>>(wavlm, xsB, 16793600, 1024);
    split_weightT8<<<1024, 256, 0, stream>>>(wl_conv_w, wtbB, 4194304, 1024, 1024);
    conv_mfma6<<<dim3(64, 8), 256, 0, stream>>>(xsB, 16793600, wtbB, 4194304,
                                                wl_conv_b, cBpl, 8388608, 1024, 1024);
    // phase 3: projection
    split_rows8<<<8192, 256, 0, stream>>>(muq, muqpl, 8388608, 8192, 1024);
    split_rows8<<<256, 256, 0, stream>>>(proj_w, wtpPl, 851968, 256, 3328);
    proj_mfma5<<<dim3(64, 2), 256, 0, stream>>>(cApl, cBpl, muqpl, wtpPl, proj_b, z_e, zpl);
    // phase 4: VQ
    split_rows8<<<8192, 256, 0, stream>>>(codebook, cbpl, 2097152, 8192, 256);
    cnorm_kernel<<<2048, 256, 0, stream>>>(codebook, cnorm);
    vq_mfma4<<<dim3(64, 64), 256, 0, stream>>>(zpl, cbpl, cnorm, pmin, pidx);
    vq_finalize<<<2048, 256, 0, stream>>>(pmin, pidx, z_e, codebook, out, cpart);
    vq_reduce<<<1, 256, 0, stream>>>(cpart, out);
}

// Round 9
// 1371.800 us; speedup vs baseline: 2.4271x; 1.1815x over previous
//
#include <hip/hip_runtime.h>
#include <cstdint>
#include <cstddef>

typedef unsigned short u16;
typedef __attribute__((ext_vector_type(8))) short bf16x8;
typedef __attribute__((ext_vector_type(4))) float f32x4;
typedef unsigned int u32;
typedef __attribute__((address_space(1))) const u32 gu32;
typedef __attribute__((address_space(3))) u32 lu32;

__device__ __forceinline__ void gload_lds16(const void* g, void* l) {
    __builtin_amdgcn_global_load_lds((gu32*)g, (lu32*)l, 16, 0, 0);
}

__device__ __forceinline__ u16 f2bf(float v) {
    u32 u = __float_as_uint(v);
    return (u16)((u + 0x7fffu + ((u >> 16) & 1u)) >> 16);
}
__device__ __forceinline__ float bf2f(u16 h) { return __uint_as_float(((u32)h) << 16); }

__device__ __forceinline__ void split3(float f, u16& h1, u16& h2, u16& h3) {
    h1 = f2bf(f); float r = f - bf2f(h1);
    h2 = f2bf(r); r -= bf2f(h2);
    h3 = f2bf(r);
}

// 6-term emulated f32 product
__device__ __forceinline__ void mfma6(f32x4& c, bf16x8 a1, bf16x8 a2, bf16x8 a3,
                                      bf16x8 b1, bf16x8 b2, bf16x8 b3) {
    c = __builtin_amdgcn_mfma_f32_16x16x32_bf16(a1, b1, c, 0, 0, 0);
    c = __builtin_amdgcn_mfma_f32_16x16x32_bf16(a1, b2, c, 0, 0, 0);
    c = __builtin_amdgcn_mfma_f32_16x16x32_bf16(a2, b1, c, 0, 0, 0);
    c = __builtin_amdgcn_mfma_f32_16x16x32_bf16(a1, b3, c, 0, 0, 0);
    c = __builtin_amdgcn_mfma_f32_16x16x32_bf16(a3, b1, c, 0, 0, 0);
    c = __builtin_amdgcn_mfma_f32_16x16x32_bf16(a2, b2, c, 0, 0, 0);
}

// ---------------------------------------------------------------------------
// Activation prep (coalesced transpose): x (8,2048,I) f32 -> parity k8 planes
// [g][b][parity][1025][8].  Block: 64 opos x 64 channels tile via LDS.
// Grid: (8*33, I/64).  Output layout identical to round-8 split_x8p.
// ---------------------------------------------------------------------------
__global__ __launch_bounds__(256)
void split_x8t(const float* __restrict__ x, u16* __restrict__ p0,
               size_t pstr, int I) {
    __shared__ u16 tl[12288];                 // [3][8][64][8]
    const int b = blockIdx.x / 33, blk = blockIdx.x - b * 33;
    const int o0 = blk * 64;
    const int nval = (o0 + 64 <= 2050) ? 64 : (2050 - o0);
    const int c0 = blockIdx.y << 6;
    const int tid = threadIdx.x;
    const int r = tid >> 2, c4 = tid & 3;

    if (r < nval) {
        int local = o0 + r;
        int parity = local >= 1025 ? 1 : 0;
        int idx = local - parity * 1025;
        int prow = 2 * idx + parity;
        bool pad = (prow == 0) || (prow == 2049);
        int s = pad ? 0 : (prow - 1);
        const float* src = x + (size_t)(b * 2048 + s) * I + c0;
#pragma unroll
        for (int k = 0; k < 4; k++) {
            int cf4 = c4 + k * 4;
            float4 v = make_float4(0.f, 0.f, 0.f, 0.f);
            if (!pad) v = *reinterpret_cast<const float4*>(src + cf4 * 4);
            float vals[4] = {v.x, v.y, v.z, v.w};
            int base = ((cf4 >> 1) * 64 + r) * 8 + (cf4 & 1) * 4;
#pragma unroll
            for (int q = 0; q < 4; q++) {
                u16 h1, h2, h3; split3(vals[q], h1, h2, h3);
                tl[base + q]        = h1;
                tl[4096 + base + q] = h2;
                tl[8192 + base + q] = h3;
            }
        }
    }
    __syncthreads();
#pragma unroll
    for (int e = tid; e < 1536; e += 256) {
        int p = e >> 9, rem = e & 511;
        int gs = rem >> 6, rr = rem & 63;
        if (rr < nval) {
            size_t dst = (size_t)p * pstr +
                         (size_t)((c0 >> 3) + gs) * 131200 +
                         (size_t)(b * 2050 + o0 + rr) * 8;
            *reinterpret_cast<bf16x8*>(&p0[dst]) =
                *reinterpret_cast<const bf16x8*>(&tl[p * 4096 + (gs * 64 + rr) * 8]);
        }
    }
}

// ---------------------------------------------------------------------------
// Generic row split (coalesced transpose): in (R,C) f32 -> plane[g][r][8].
// Grid: (R/64, C/64).  Output layout identical to round-8 split_rows8.
// ---------------------------------------------------------------------------
__global__ __launch_bounds__(256)
void split_rows8t(const float* __restrict__ in, u16* __restrict__ p0,
                  size_t pstr, int R, int C) {
    __shared__ u16 tl[12288];
    const int r0 = blockIdx.x << 6;
    const int c0 = blockIdx.y << 6;
    const int tid = threadIdx.x;
    const int r = tid >> 2, c4 = tid & 3;
    const float* src = in + (size_t)(r0 + r) * C + c0;
#pragma unroll
    for (int k = 0; k < 4; k++) {
        int cf4 = c4 + k * 4;
        float4 v = *reinterpret_cast<const float4*>(src + cf4 * 4);
        float vals[4] = {v.x, v.y, v.z, v.w};
        int base = ((cf4 >> 1) * 64 + r) * 8 + (cf4 & 1) * 4;
#pragma unroll
        for (int q = 0; q < 4; q++) {
            u16 h1, h2, h3; split3(vals[q], h1, h2, h3);
            tl[base + q]        = h1;
            tl[4096 + base + q] = h2;
            tl[8192 + base + q] = h3;
        }
    }
    __syncthreads();
#pragma unroll
    for (int e = tid; e < 1536; e += 256) {
        int p = e >> 9, rem = e & 511;
        int gs = rem >> 6, rr = rem & 63;
        size_t dst = (size_t)p * pstr +
                     ((size_t)((c0 >> 3) + gs) * R + (r0 + rr)) * 8;
        *reinterpret_cast<bf16x8*>(&p0[dst]) =
            *reinterpret_cast<const bf16x8*>(&tl[p * 4096 + (gs * 64 + rr) * 8]);
    }
}

// ---------------------------------------------------------------------------
// Weight prep (coalesced transpose): w (O,I,4) f32 -> plane[kg][o][8],
// kg = kcv*(I/8) + i/8.  Grid: (O/64, I/64), kcv looped inside.
// Output layout identical to round-8 split_weightT8.
// ---------------------------------------------------------------------------
__global__ __launch_bounds__(256)
void split_weightT8t(const float* __restrict__ w, u16* __restrict__ p0,
                     size_t pstr, int I, int O) {
    __shared__ u16 tl[12288];
    const int o0 = blockIdx.x << 6;
    const int c0 = blockIdx.y << 6;
    const int G = I >> 3;
    const int tid = threadIdx.x;
    const int r = tid >> 2, c4 = tid & 3;
    for (int kcv = 0; kcv < 4; kcv++) {
#pragma unroll
        for (int k = 0; k < 4; k++) {
            int cf4 = c4 + k * 4;
#pragma unroll
            for (int q = 0; q < 4; q++) {
                int i = c0 + cf4 * 4 + q;
                float f = w[((size_t)(o0 + r) * I + i) * 4 + kcv];
                u16 h1, h2, h3; split3(f, h1, h2, h3);
                int base = ((cf4 >> 1) * 64 + r) * 8 + (cf4 & 1) * 4 + q;
                tl[base]        = h1;
                tl[4096 + base] = h2;
                tl[8192 + base] = h3;
            }
        }
        __syncthreads();
        for (int e = tid; e < 1536; e += 256) {
            int p = e >> 9, rem = e & 511;
            int gs = rem >> 6, rr = rem & 63;
            size_t dst = (size_t)p * pstr +
                         ((size_t)(kcv * G + (c0 >> 3) + gs) * O + (o0 + rr)) * 8;
            *reinterpret_cast<bf16x8*>(&p0[dst]) =
                *reinterpret_cast<const bf16x8*>(&tl[p * 4096 + (gs * 64 + rr) * 8]);
        }
        __syncthreads();
    }
}

__global__ void cnorm_kernel(const float* __restrict__ cb, float* __restrict__ cn) {
    int w = threadIdx.x >> 6, lane = threadIdx.x & 63;
    int row = blockIdx.x * 4 + w;
    float4 v = *reinterpret_cast<const float4*>(&cb[(size_t)row * 256 + lane * 4]);
    float s = v.x * v.x + v.y * v.y + v.z * v.z + v.w * v.w;
#pragma unroll
    for (int off = 32; off; off >>= 1) s += __shfl_xor(s, off);
    if (lane == 0) cn[row] = s;
}

// ---------------------------------------------------------------------------
// Conv1d(k=4,s=2,p=1): 6-term MFMA, 2-phase double-buffered LDS (planes 1,2
// via global_load_lds) + 3rd-plane fragments direct global->register.
// ---------------------------------------------------------------------------
__global__ __launch_bounds__(256, 2)
void conv_mfma6(const u16* __restrict__ xs, unsigned pstr_x,
                const u16* __restrict__ wt, unsigned pstr_w,
                const float* __restrict__ bias,
                u16* __restrict__ outp, unsigned pstr_o,
                int I, int O) {
    __shared__ u16 lds[32768];                 // 2 x 32KB buffers
    const int m0 = blockIdx.x << 7;
    const int n0 = blockIdx.y << 7;
    const int tid = threadIdx.x, lane = tid & 63, wv = tid >> 6;
    const int wr = ((wv >> 1) & 1) << 6, wc = (wv & 1) << 6;
    const int fr = lane & 15, fkg = lane >> 4;
    const int b = m0 >> 10, t0 = m0 & 1023;
    const int G = I >> 3;
    const int SL = 131200;
    const int NIT = G;
    const int npt = G >> 2;

    const u16* srcp[8];
    int dsto[8];
    int inc;
#pragma unroll
    for (int j = 0; j < 8; j++) {
        int kg = j >> 1, half = j & 1;
        int r = half * 64 + lane;
        if (wv < 2) {
            srcp[j] = xs + (size_t)wv * pstr_x + (size_t)kg * SL +
                      (size_t)(b * 2050 + t0 + r) * 8;
        } else {
            srcp[j] = wt + (size_t)(wv - 2) * pstr_w + (size_t)kg * (O * 8) +
                      (size_t)(n0 + r) * 8;
        }
        dsto[j] = wv * 4096 + j * 512;
    }
    inc = (wv < 2) ? 4 * SL : O * 32;

    const u16* pa3 = xs + 2 * (size_t)pstr_x + (size_t)fkg * SL +
                     (size_t)(b * 2050 + t0 + wr + fr) * 8;
    const u16* pb3 = wt + 2 * (size_t)pstr_w + (size_t)fkg * (O * 8) +
                     (size_t)(n0 + wc + fr) * 8;

    f32x4 acc[4][4];
#pragma unroll
    for (int i = 0; i < 4; i++)
#pragma unroll
        for (int j = 0; j < 4; j++) acc[i][j] = (f32x4){0.f, 0.f, 0.f, 0.f};

#pragma unroll
    for (int j = 0; j < 8; j++) {
        gload_lds16(srcp[j], &lds[dsto[j]]);
        srcp[j] += inc;
    }
    __syncthreads();

    int scnt = npt - 1, skcv = 0;
    int dcnt = npt, dkcv = 0;
    int cur = 0;

    for (int it = 0; it < NIT; ++it) {
        const u16* lb = &lds[cur * 16384];
        bf16x8 a1[4], a2[4], b1[4], b2[4];
#pragma unroll
        for (int fm = 0; fm < 4; fm++) {
            int aidx = fkg * 1024 + (wr + fm * 16 + fr) * 8;
            a1[fm] = *reinterpret_cast<const bf16x8*>(lb + aidx);
            a2[fm] = *reinterpret_cast<const bf16x8*>(lb + 4096 + aidx);
        }
#pragma unroll
        for (int fn = 0; fn < 4; fn++) {
            int bidx = fkg * 1024 + (wc + fn * 16 + fr) * 8;
            b1[fn] = *reinterpret_cast<const bf16x8*>(lb + 8192 + bidx);
            b2[fn] = *reinterpret_cast<const bf16x8*>(lb + 12288 + bidx);
        }
        if (it + 1 < NIT) {
#pragma unroll
            for (int j = 0; j < 8; j++) {
                gload_lds16(srcp[j], &lds[(cur ^ 1) * 16384 + dsto[j]]);
                srcp[j] += inc;
            }
            if (wv < 2) {
                if (--scnt == 0) {
                    int d = ((skcv == 1) ? -8192 : 8200) - (int)pstr_x;
#pragma unroll
                    for (int j = 0; j < 8; j++) srcp[j] += d;
                    skcv++; scnt = npt;
                }
            }
        }
        bf16x8 da3[4], db3[4];
#pragma unroll
        for (int fm = 0; fm < 4; fm++)
            da3[fm] = *reinterpret_cast<const bf16x8*>(pa3 + fm * 128);
#pragma unroll
        for (int fn = 0; fn < 4; fn++)
            db3[fn] = *reinterpret_cast<const bf16x8*>(pb3 + fn * 128);
        pa3 += 4 * SL;
        pb3 += O * 32;
        if (--dcnt == 0) {
            pa3 += ((dkcv == 1) ? -8192 : 8200) - (int)pstr_x;
            dkcv++; dcnt = npt;
        }
#pragma unroll
        for (int fm = 0; fm < 4; fm++)
#pragma unroll
            for (int fn = 0; fn < 4; fn++)
                mfma6(acc[fm][fn], a1[fm], a2[fm], da3[fm],
                      b1[fn], b2[fn], db3[fn]);
        __syncthreads();
        cur ^= 1;
    }

    u16 (*eld)[32][132] = (u16 (*)[32][132])lds;
    float bv[4];
#pragma unroll
    for (int fn = 0; fn < 4; fn++) bv[fn] = bias[n0 + wc + fn * 16 + fr];
    const int srb = (wr >> 6) * 16 + fkg * 4;
#pragma unroll
    for (int fm = 0; fm < 4; fm++) {
#pragma unroll
        for (int fn = 0; fn < 4; fn++) {
            int cl = wc + fn * 16 + fr;
#pragma unroll
            for (int j = 0; j < 4; j++) {
                float f = acc[fm][fn][j] + bv[fn];
                u16 h1, h2, h3; split3(f, h1, h2, h3);
                eld[0][srb + j][cl] = h1;
                eld[1][srb + j][cl] = h2;
                eld[2][srb + j][cl] = h3;
            }
        }
        __syncthreads();
#pragma unroll
        for (int q = 0; q < 6; q++) {
            int e = q * 256 + tid;
            int g = e / 96, rem = e - g * 96;
            int p = rem >> 5, sr = rem & 31;
            bf16x8 vv = *reinterpret_cast<const bf16x8*>(&eld[p][sr][g * 8]);
            int rowg = m0 + ((sr >> 4) << 6) + fm * 16 + (sr & 15);
            size_t addr = (size_t)p * pstr_o +
                          (size_t)((n0 >> 3) + g) * 65536 + (size_t)rowg * 8;
            *reinterpret_cast<bf16x8*>(&outp[addr]) = vv;
        }
        __syncthreads();
    }
}

// ---------------------------------------------------------------------------
// Projection: 6-term MFMA over 3 k8 segments; z_e f32 + coalesced zpl planes.
// ---------------------------------------------------------------------------
__global__ __launch_bounds__(256, 3)
void proj_mfma5(const u16* __restrict__ sA, const u16* __restrict__ sB,
                const u16* __restrict__ sM, const u16* __restrict__ wp,
                const float* __restrict__ bias, float* __restrict__ z_e,
                u16* __restrict__ zpl) {
    __shared__ u16 lds[24576];
    const int m0 = blockIdx.x << 7;
    const int n0 = blockIdx.y << 7;
    const int tid = threadIdx.x, lane = tid & 63, wv = tid >> 6;
    const int wr = ((wv >> 1) & 1) << 6, wc = (wv & 1) << 6;
    const int fr = lane & 15, fkg = lane >> 4;

    const u16* srcp[12];
    int dsto[12];
#pragma unroll
    for (int j = 0; j < 12; j++) {
        int ii = wv * 12 + j;
        int tile = ii >> 3, sub = ii & 7;
        int kg = sub >> 1, half = sub & 1;
        int r = half * 64 + lane;
        if (tile >= 3)
            srcp[j] = wp + (size_t)(tile - 3) * 851968 + (size_t)kg * 2048 +
                      (size_t)(n0 + r) * 8;
        else
            srcp[j] = nullptr;
        dsto[j] = tile * 4096 + sub * 512;
    }

    f32x4 acc[4][4];
#pragma unroll
    for (int i = 0; i < 4; i++)
#pragma unroll
        for (int j = 0; j < 4; j++) acc[i][j] = (f32x4){0.f, 0.f, 0.f, 0.f};

    const u16* segp[3] = {sA, sB, sM};
    const int segG[3] = {160, 128, 128};
    const unsigned segP[3] = {10485760u, 8388608u, 8388608u};

    for (int seg = 0; seg < 3; seg++) {
        const u16* sp = segp[seg];
        const unsigned sps = segP[seg];
#pragma unroll
        for (int j = 0; j < 12; j++) {
            int ii = wv * 12 + j;
            int tile = ii >> 3, sub = ii & 7;
            int kg = sub >> 1, half = sub & 1;
            int r = half * 64 + lane;
            if (tile < 3)
                srcp[j] = sp + (size_t)tile * sps + (size_t)kg * 65536 +
                          (size_t)(m0 + r) * 8;
        }
        const int niter = segG[seg] >> 2;
        for (int it = 0; it < niter; it++) {
#pragma unroll
            for (int j = 0; j < 12; j++) {
                gload_lds16(srcp[j], &lds[dsto[j]]);
                int ii = wv * 12 + j;
                srcp[j] += (ii >> 3) < 3 ? 262144 : 8192;
            }
            __syncthreads();
            bf16x8 bfr[3][4];
#pragma unroll
            for (int p = 0; p < 3; p++)
#pragma unroll
                for (int fn = 0; fn < 4; fn++)
                    bfr[p][fn] = *reinterpret_cast<const bf16x8*>(
                        &lds[(3 + p) * 4096 + fkg * 1024 + (wc + fn * 16 + fr) * 8]);
#pragma unroll
            for (int fm = 0; fm < 4; fm++) {
                int aidx = fkg * 1024 + (wr + fm * 16 + fr) * 8;
                bf16x8 a1 = *reinterpret_cast<const bf16x8*>(&lds[aidx]);
                bf16x8 a2 = *reinterpret_cast<const bf16x8*>(&lds[4096 + aidx]);
                bf16x8 a3 = *reinterpret_cast<const bf16x8*>(&lds[8192 + aidx]);
#pragma unroll
                for (int fn = 0; fn < 4; fn++)
                    mfma6(acc[fm][fn], a1, a2, a3, bfr[0][fn], bfr[1][fn], bfr[2][fn]);
            }
            __syncthreads();
        }
    }
    u16 (*eld)[32][132] = (u16 (*)[32][132])lds;
    float bv[4];
#pragma unroll
    for (int fn = 0; fn < 4; fn++) bv[fn] = bias[n0 + wc + fn * 16 + fr];
    const int srb = (wr >> 6) * 16 + fkg * 4;
#pragma unroll
    for (int fm = 0; fm < 4; fm++) {
#pragma unroll
        for (int fn = 0; fn < 4; fn++) {
            int cl = wc + fn * 16 + fr;
            int col = n0 + cl;
#pragma unroll
            for (int j = 0; j < 4; j++) {
                float f = acc[fm][fn][j] + bv[fn];
                int rowg = m0 + wr + fm * 16 + fkg * 4 + j;
                z_e[(size_t)rowg * 256 + col] = f;
                u16 h1, h2, h3; split3(f, h1, h2, h3);
                eld[0][srb + j][cl] = h1;
                eld[1][srb + j][cl] = h2;
                eld[2][srb + j][cl] = h3;
            }
        }
        __syncthreads();
#pragma unroll
        for (int q = 0; q < 6; q++) {
            int e = q * 256 + tid;
            int g = e / 96, rem = e - g * 96;
            int p = rem >> 5, sr = rem & 31;
            bf16x8 vv = *reinterpret_cast<const bf16x8*>(&eld[p][sr][g * 8]);
            int rowg = m0 + ((sr >> 4) << 6) + fm * 16 + (sr & 15);
            size_t addr = (size_t)p * 2097152 +
                          (size_t)((n0 >> 3) + g) * 65536 + (size_t)rowg * 8;
            *reinterpret_cast<bf16x8*>(&zpl[addr]) = vv;
        }
        __syncthreads();
    }
}

// ---------------------------------------------------------------------------
// VQ: 6-term MFMA (K=256, k8 planes) + f64 compare + LDS argmin epilogue.
// ---------------------------------------------------------------------------
__global__ __launch_bounds__(256, 3)
void vq_mfma4(const u16* __restrict__ zpl, const u16* __restrict__ cbpl,
              const float* __restrict__ cn, double* __restrict__ pmin,
              int* __restrict__ pidx) {
    __shared__ __align__(16) char smem[49152];
    u16* lds = (u16*)smem;
    const int m0 = blockIdx.x << 7;
    const int n0 = blockIdx.y << 7;
    const int tid = threadIdx.x, lane = tid & 63, wv = tid >> 6;
    const int wr = ((wv >> 1) & 1) << 6, wc = (wv & 1) << 6;
    const int fr = lane & 15, fkg = lane >> 4;

    const u16* srcp[12];
    int dsto[12];
#pragma unroll
    for (int j = 0; j < 12; j++) {
        int ii = wv * 12 + j;
        int tile = ii >> 3, sub = ii & 7;
        int kg = sub >> 1, half = sub & 1;
        int r = half * 64 + lane;
        if (tile < 3)
            srcp[j] = zpl + (size_t)tile * 2097152 + (size_t)kg * 65536 +
                      (size_t)(m0 + r) * 8;
        else
            srcp[j] = cbpl + (size_t)(tile - 3) * 2097152 + (size_t)kg * 65536 +
                      (size_t)(n0 + r) * 8;
        dsto[j] = tile * 4096 + sub * 512;
    }

    f32x4 acc[4][4];
#pragma unroll
    for (int i = 0; i < 4; i++)
#pragma unroll
        for (int j = 0; j < 4; j++) acc[i][j] = (f32x4){0.f, 0.f, 0.f, 0.f};

    for (int kt = 0; kt < 256; kt += 32) {
#pragma unroll
        for (int j = 0; j < 12; j++) {
            gload_lds16(srcp[j], &lds[dsto[j]]);
            srcp[j] += 262144;
        }
        __syncthreads();
        bf16x8 bfr[3][4];
#pragma unroll
        for (int p = 0; p < 3; p++)
#pragma unroll
            for (int fn = 0; fn < 4; fn++)
                bfr[p][fn] = *reinterpret_cast<const bf16x8*>(
                    &lds[(3 + p) * 4096 + fkg * 1024 + (wc + fn * 16 + fr) * 8]);
#pragma unroll
        for (int fm = 0; fm < 4; fm++) {
            int aidx = fkg * 1024 + (wr + fm * 16 + fr) * 8;
            bf16x8 a1 = *reinterpret_cast<const bf16x8*>(&lds[aidx]);
            bf16x8 a2 = *reinterpret_cast<const bf16x8*>(&lds[4096 + aidx]);
            bf16x8 a3 = *reinterpret_cast<const bf16x8*>(&lds[8192 + aidx]);
#pragma unroll
            for (int fn = 0; fn < 4; fn++)
                mfma6(acc[fm][fn], a1, a2, a3, bfr[0][fn], bfr[1][fn], bfr[2][fn]);
        }
        __syncthreads();
    }
    double (*red_d)[32] = (double (*)[32])smem;
    int (*red_n)[32] = (int (*)[32])(smem + 32768);
#pragma unroll
    for (int fm = 0; fm < 4; fm++)
#pragma unroll
        for (int j = 0; j < 4; j++) {
            double best = 1e300; int bestn = 0x7fffffff;
#pragma unroll
            for (int fn = 0; fn < 4; fn++) {
                int gn = n0 + wc + fn * 16 + fr;
                double d = (double)cn[gn] - 2.0 * (double)acc[fm][fn][j];
                if (d < best || (d == best && gn < bestn)) { best = d; bestn = gn; }
            }
            int row = wr + fm * 16 + fkg * 4 + j;
            int cand = ((wv & 1) << 4) + fr;
            red_d[row][cand] = best; red_n[row][cand] = bestn;
        }
    __syncthreads();
    if (tid < 128) {
        double best = red_d[tid][0]; int bestn = red_n[tid][0];
#pragma unroll 4
        for (int k = 1; k < 32; k++) {
            double d = red_d[tid][k]; int n2 = red_n[tid][k];
            if (d < best || (d == best && n2 < bestn)) { best = d; bestn = n2; }
        }
        size_t idx = (size_t)(m0 + tid) * 64 + (n0 >> 7);
        pmin[idx] = best; pidx[idx] = bestn;
    }
}

// ---------------------------------------------------------------------------
__global__ void vq_finalize(const double* __restrict__ pmin, const int* __restrict__ pidx,
                            const float* __restrict__ z, const float* __restrict__ cb,
                            float* __restrict__ out, double* __restrict__ cpart) {
    int w = threadIdx.x >> 6, lane = threadIdx.x & 63;
    int m = blockIdx.x * 4 + w;
    double d = pmin[(size_t)m * 64 + lane];
    int n = pidx[(size_t)m * 64 + lane];
#pragma unroll
    for (int off = 32; off; off >>= 1) {
        double d2 = __shfl_xor(d, off);
        int n2 = __shfl_xor(n, off);
        if (d2 < d || (d2 == d && n2 < n)) { d = d2; n = n2; }
    }
    float4 cv = *reinterpret_cast<const float4*>(&cb[(size_t)n * 256 + lane * 4]);
    float4 zv = *reinterpret_cast<const float4*>(&z[(size_t)m * 256 + lane * 4]);
    *reinterpret_cast<float4*>(&out[(size_t)m * 256 + lane * 4]) = cv;
    float dx = zv.x - cv.x, dy = zv.y - cv.y, dz = zv.z - cv.z, dw = zv.w - cv.w;
    double s = (double)(dx * dx) + (double)(dy * dy) + (double)(dz * dz) + (double)(dw * dw);
#pragma unroll
    for (int off = 32; off; off >>= 1) s += __shfl_xor(s, off);
    if (lane == 0) {
        out[2097152 + m] = (float)n;
        cpart[m] = s;
    }
}

__global__ void vq_reduce(const double* __restrict__ cpart, float* __restrict__ out) {
    __shared__ double sm[256];
    double s = 0.0;
    for (int i = threadIdx.x; i < 8192; i += 256) s += cpart[i];
    sm[threadIdx.x] = s;
    __syncthreads();
    for (int off = 128; off; off >>= 1) {
        if ((int)threadIdx.x < off) sm[threadIdx.x] += sm[threadIdx.x + off];
        __syncthreads();
    }
    if (threadIdx.x == 0) out[2105344] = (float)(sm[0] / 2097152.0);
}

// ---------------------------------------------------------------------------
extern "C" void kernel_launch(void* const* d_in, const int* in_sizes, int n_in,
                              void* d_out, int out_size, void* d_ws, size_t ws_size,
                              hipStream_t stream) {
    (void)in_sizes; (void)n_in; (void)out_size; (void)ws_size;
    const float* whisper   = (const float*)d_in[0];
    const float* wavlm     = (const float*)d_in[1];
    const float* muq       = (const float*)d_in[2];
    const float* w_conv_w  = (const float*)d_in[3];
    const float* w_conv_b  = (const float*)d_in[4];
    const float* wl_conv_w = (const float*)d_in[5];
    const float* wl_conv_b = (const float*)d_in[6];
    const float* proj_w    = (const float*)d_in[7];
    const float* proj_b    = (const float*)d_in[8];
    const float* codebook  = (const float*)d_in[9];
    float* out = (float*)d_out;
    char* wsb = (char*)d_ws;

    // ---- workspace layout (bytes), same footprint as round 8 ----
    u16*   xsA   = (u16*)(wsb + 0);            // 3 planes, pstr 20,992,000 elems
    u16*   wtbA  = (u16*)(wsb + 125952000);    // 3 planes, pstr 6,553,600
    u16*   cApl  = (u16*)(wsb + 176259072);    // 3 planes, pstr 10,485,760
    u16*   xsB   = (u16*)(wsb + 0);            // pstr 16,793,600
    u16*   wtbB  = (u16*)(wsb + 100761600);    // pstr 4,194,304
    u16*   cBpl  = (u16*)(wsb + 125927424);    // pstr 8,388,608
    u16*   muqpl = (u16*)(wsb + 0);            // pstr 8,388,608
    u16*   wtpPl = (u16*)(wsb + 50331648);     // pstr 851,968
    float* z_e   = (float*)(wsb + 55443456);   // 8192*256 f32
    u16*   zpl   = (u16*)(wsb + 63832064);     // pstr 2,097,152
    u16*   cbpl  = (u16*)(wsb + 76414976);     // pstr 2,097,152
    float* cnorm = (float*)(wsb + 88997888);
    double* pmin = (double*)(wsb + 89030656);
    int*    pidx = (int*)(wsb + 93224960);
    double* cpart= (double*)(wsb + 95322112);

    // phase 1: whisper conv
    split_x8t<<<dim3(264, 20), 256, 0, stream>>>(whisper, xsA, 20992000, 1280);
    split_weightT8t<<<dim3(20, 20), 256, 0, stream>>>(w_conv_w, wtbA, 6553600, 1280, 1280);
    conv_mfma6<<<dim3(64, 10), 256, 0, stream>>>(xsA, 20992000, wtbA, 6553600,
                                                 w_conv_b, cApl, 10485760, 1280, 1280);
    // phase 2: wavlm conv (reuses xsA/wtbA region)
    split_x8t<<<dim3(264, 16), 256, 0, stream>>>(wavlm, xsB, 16793600, 1024);
    split_weightT8t<<<dim3(16, 16), 256, 0, stream>>>(wl_conv_w, wtbB, 4194304, 1024, 1024);
    conv_mfma6<<<dim3(64, 8), 256, 0, stream>>>(xsB, 16793600, wtbB, 4194304,
                                                wl_conv_b, cBpl, 8388608, 1024, 1024);
    // phase 3: projection
    split_rows8t<<<dim3(128, 16), 256, 0, stream>>>(muq, muqpl, 8388608, 8192, 1024);
    split_rows8t<<<dim3(4, 52), 256, 0, stream>>>(proj_w, wtpPl, 851968, 256, 3328);
    proj_mfma5<<<dim3(64, 2), 256, 0, stream>>>(cApl, cBpl, muqpl, wtpPl, proj_b, z_e, zpl);
    // phase 4: VQ
    split_rows8t<<<dim3(128, 4), 256, 0, stream>>>(codebook, cbpl, 2097152, 8192, 256);
    cnorm_kernel<<<2048, 256, 0, stream>>>(codebook, cnorm);
    vq_mfma4<<<dim3(64, 64), 256, 0, stream>>>(zpl, cbpl, cnorm, pmin, pidx);
    vq_finalize<<<2048, 256, 0, stream>>>(pmin, pidx, z_e, codebook, out, cpart);
    vq_reduce<<<1, 256, 0, stream>>>(cpart, out);
}

// Round 10
// 1268.605 us; speedup vs baseline: 2.6246x; 1.0813x over previous
//
#include <hip/hip_runtime.h>
#include <cstdint>
#include <cstddef>

typedef unsigned short u16;
typedef __attribute__((ext_vector_type(8))) short bf16x8;
typedef __attribute__((ext_vector_type(4))) float f32x4;
typedef unsigned int u32;
typedef __attribute__((address_space(1))) const u32 gu32;
typedef __attribute__((address_space(3))) u32 lu32;

__device__ __forceinline__ void gload_lds16(const void* g, void* l) {
    __builtin_amdgcn_global_load_lds((gu32*)g, (lu32*)l, 16, 0, 0);
}

__device__ __forceinline__ u16 f2bf(float v) {
    u32 u = __float_as_uint(v);
    return (u16)((u + 0x7fffu + ((u >> 16) & 1u)) >> 16);
}
__device__ __forceinline__ float bf2f(u16 h) { return __uint_as_float(((u32)h) << 16); }

__device__ __forceinline__ void split3(float f, u16& h1, u16& h2, u16& h3) {
    h1 = f2bf(f); float r = f - bf2f(h1);
    h2 = f2bf(r); r -= bf2f(h2);
    h3 = f2bf(r);
}

// 6-term emulated f32 product
__device__ __forceinline__ void mfma6(f32x4& c, bf16x8 a1, bf16x8 a2, bf16x8 a3,
                                      bf16x8 b1, bf16x8 b2, bf16x8 b3) {
    c = __builtin_amdgcn_mfma_f32_16x16x32_bf16(a1, b1, c, 0, 0, 0);
    c = __builtin_amdgcn_mfma_f32_16x16x32_bf16(a1, b2, c, 0, 0, 0);
    c = __builtin_amdgcn_mfma_f32_16x16x32_bf16(a2, b1, c, 0, 0, 0);
    c = __builtin_amdgcn_mfma_f32_16x16x32_bf16(a1, b3, c, 0, 0, 0);
    c = __builtin_amdgcn_mfma_f32_16x16x32_bf16(a3, b1, c, 0, 0, 0);
    c = __builtin_amdgcn_mfma_f32_16x16x32_bf16(a2, b2, c, 0, 0, 0);
}

// ---------------------------------------------------------------------------
// Activation prep (coalesced transpose): x (8,2048,I) f32 -> parity k8 planes
// [g][b][parity][1025][8].
// ---------------------------------------------------------------------------
__global__ __launch_bounds__(256)
void split_x8t(const float* __restrict__ x, u16* __restrict__ p0,
               size_t pstr, int I) {
    __shared__ u16 tl[12288];                 // [3][8][64][8]
    const int b = blockIdx.x / 33, blk = blockIdx.x - b * 33;
    const int o0 = blk * 64;
    const int nval = (o0 + 64 <= 2050) ? 64 : (2050 - o0);
    const int c0 = blockIdx.y << 6;
    const int tid = threadIdx.x;
    const int r = tid >> 2, c4 = tid & 3;

    if (r < nval) {
        int local = o0 + r;
        int parity = local >= 1025 ? 1 : 0;
        int idx = local - parity * 1025;
        int prow = 2 * idx + parity;
        bool pad = (prow == 0) || (prow == 2049);
        int s = pad ? 0 : (prow - 1);
        const float* src = x + (size_t)(b * 2048 + s) * I + c0;
#pragma unroll
        for (int k = 0; k < 4; k++) {
            int cf4 = c4 + k * 4;
            float4 v = make_float4(0.f, 0.f, 0.f, 0.f);
            if (!pad) v = *reinterpret_cast<const float4*>(src + cf4 * 4);
            float vals[4] = {v.x, v.y, v.z, v.w};
            int base = ((cf4 >> 1) * 64 + r) * 8 + (cf4 & 1) * 4;
#pragma unroll
            for (int q = 0; q < 4; q++) {
                u16 h1, h2, h3; split3(vals[q], h1, h2, h3);
                tl[base + q]        = h1;
                tl[4096 + base + q] = h2;
                tl[8192 + base + q] = h3;
            }
        }
    }
    __syncthreads();
#pragma unroll
    for (int e = tid; e < 1536; e += 256) {
        int p = e >> 9, rem = e & 511;
        int gs = rem >> 6, rr = rem & 63;
        if (rr < nval) {
            size_t dst = (size_t)p * pstr +
                         (size_t)((c0 >> 3) + gs) * 131200 +
                         (size_t)(b * 2050 + o0 + rr) * 8;
            *reinterpret_cast<bf16x8*>(&p0[dst]) =
                *reinterpret_cast<const bf16x8*>(&tl[p * 4096 + (gs * 64 + rr) * 8]);
        }
    }
}

// ---------------------------------------------------------------------------
// Generic row split (coalesced transpose): in (R,C) f32 -> plane[g][r][8].
// ---------------------------------------------------------------------------
__global__ __launch_bounds__(256)
void split_rows8t(const float* __restrict__ in, u16* __restrict__ p0,
                  size_t pstr, int R, int C) {
    __shared__ u16 tl[12288];
    const int r0 = blockIdx.x << 6;
    const int c0 = blockIdx.y << 6;
    const int tid = threadIdx.x;
    const int r = tid >> 2, c4 = tid & 3;
    const float* src = in + (size_t)(r0 + r) * C + c0;
#pragma unroll
    for (int k = 0; k < 4; k++) {
        int cf4 = c4 + k * 4;
        float4 v = *reinterpret_cast<const float4*>(src + cf4 * 4);
        float vals[4] = {v.x, v.y, v.z, v.w};
        int base = ((cf4 >> 1) * 64 + r) * 8 + (cf4 & 1) * 4;
#pragma unroll
        for (int q = 0; q < 4; q++) {
            u16 h1, h2, h3; split3(vals[q], h1, h2, h3);
            tl[base + q]        = h1;
            tl[4096 + base + q] = h2;
            tl[8192 + base + q] = h3;
        }
    }
    __syncthreads();
#pragma unroll
    for (int e = tid; e < 1536; e += 256) {
        int p = e >> 9, rem = e & 511;
        int gs = rem >> 6, rr = rem & 63;
        size_t dst = (size_t)p * pstr +
                     ((size_t)((c0 >> 3) + gs) * R + (r0 + rr)) * 8;
        *reinterpret_cast<bf16x8*>(&p0[dst]) =
            *reinterpret_cast<const bf16x8*>(&tl[p * 4096 + (gs * 64 + rr) * 8]);
    }
}

// ---------------------------------------------------------------------------
// Weight prep (coalesced transpose, TILE-MAJOR): w (O,I,4) f32 ->
// plane[ng][kg][NT][8], kg = kcv*G + i/8, ng = o/NT.  Grid: (O/64, I/64).
// ---------------------------------------------------------------------------
__global__ __launch_bounds__(256)
void split_weightT8m(const float* __restrict__ w, u16* __restrict__ p0,
                     size_t pstr, int I, int O, int NT) {
    __shared__ u16 tl[12288];
    const int o0 = blockIdx.x << 6;
    const int c0 = blockIdx.y << 6;
    const int G = I >> 3;
    const size_t SLAB = (size_t)4 * G * NT * 8;
    const int tid = threadIdx.x;
    const int r = tid >> 2, c4 = tid & 3;
    for (int kcv = 0; kcv < 4; kcv++) {
#pragma unroll
        for (int k = 0; k < 4; k++) {
            int cf4 = c4 + k * 4;
#pragma unroll
            for (int q = 0; q < 4; q++) {
                int i = c0 + cf4 * 4 + q;
                float f = w[((size_t)(o0 + r) * I + i) * 4 + kcv];
                u16 h1, h2, h3; split3(f, h1, h2, h3);
                int base = ((cf4 >> 1) * 64 + r) * 8 + (cf4 & 1) * 4 + q;
                tl[base]        = h1;
                tl[4096 + base] = h2;
                tl[8192 + base] = h3;
            }
        }
        __syncthreads();
        for (int e = tid; e < 1536; e += 256) {
            int p = e >> 9, rem = e & 511;
            int gs = rem >> 6, rr = rem & 63;
            int o = o0 + rr;
            int ng = o / NT, orr = o - ng * NT;
            int kg = kcv * G + (c0 >> 3) + gs;
            size_t dst = (size_t)p * pstr + (size_t)ng * SLAB +
                         (size_t)kg * NT * 8 + (size_t)orr * 8;
            *reinterpret_cast<bf16x8*>(&p0[dst]) =
                *reinterpret_cast<const bf16x8*>(&tl[p * 4096 + (gs * 64 + rr) * 8]);
        }
        __syncthreads();
    }
}

__global__ void cnorm_kernel(const float* __restrict__ cb, float* __restrict__ cn) {
    int w = threadIdx.x >> 6, lane = threadIdx.x & 63;
    int row = blockIdx.x * 4 + w;
    float4 v = *reinterpret_cast<const float4*>(&cb[(size_t)row * 256 + lane * 4]);
    float s = v.x * v.x + v.y * v.y + v.z * v.z + v.w * v.w;
#pragma unroll
    for (int off = 32; off; off >>= 1) s += __shfl_xor(s, off);
    if (lane == 0) cn[row] = s;
}

// ---------------------------------------------------------------------------
// Conv1d(k=4,s=2,p=1): 6-term MFMA, dbuf LDS (planes 1,2) + plane-3 direct.
// Templated on TN (n-tile): 160 (whisper, grid 64x8) / 128 (wavlm, 64x8).
// B in tile-major layout: per-iter slab contiguous -> linear 1KB loads.
// ---------------------------------------------------------------------------
template<int TN>
__global__ __launch_bounds__(256, 2)
void conv_mfma7(const u16* __restrict__ xs, unsigned pstr_x,
                const u16* __restrict__ wt, unsigned pstr_w,
                const float* __restrict__ bias,
                u16* __restrict__ outp, unsigned pstr_o,
                int I, int O) {
    constexpr int FN = TN / 32;            // n-frags per wave (5 or 4)
    constexpr int NB = TN / 16;            // B loads per wave per iter (10 or 8)
    constexpr int BPLANE = 32 * TN;        // u16 per B plane per iter-slab
    constexpr int BUFE = 8192 + 2 * BPLANE;
    __shared__ u16 lds[2 * BUFE];
    const int m0 = blockIdx.x << 7;
    const int ny = blockIdx.y;
    const int n0 = ny * TN;
    const int tid = threadIdx.x, lane = tid & 63, wv = tid >> 6;
    const int wr = ((wv >> 1) & 1) << 6, wc = (wv & 1) * (TN / 2);
    const int fr = lane & 15, fkg = lane >> 4;
    const int b = m0 >> 10, t0 = m0 & 1023;
    const int G = I >> 3;
    const int SL = 131200;
    const int NIT = G, npt = G >> 2;
    const size_t SLAB = (size_t)4 * G * TN * 8;

    const u16* srcp[NB];
    int dsto[NB];
    const int nload = (wv < 2) ? 8 : NB;
    int inc;
    if (wv < 2) {
        inc = 4 * SL;
#pragma unroll
        for (int j = 0; j < NB; j++) {
            if (j < 8) {
                int kg = j >> 1, half = j & 1;
                int r = half * 64 + lane;
                srcp[j] = xs + (size_t)wv * pstr_x + (size_t)kg * SL +
                          (size_t)(b * 2050 + t0 + r) * 8;
                dsto[j] = wv * 4096 + j * 512;
            } else { srcp[j] = xs; dsto[j] = 0; }
        }
    } else {
        inc = BPLANE;
#pragma unroll
        for (int j = 0; j < NB; j++) {
            srcp[j] = wt + (size_t)(wv - 2) * pstr_w + (size_t)ny * SLAB +
                      j * 512 + lane * 8;
            dsto[j] = 8192 + (wv - 2) * BPLANE + j * 512;
        }
    }

    const u16* pa3 = xs + 2 * (size_t)pstr_x + (size_t)fkg * SL +
                     (size_t)(b * 2050 + t0 + wr + fr) * 8;
    const u16* pb3 = wt + 2 * (size_t)pstr_w + (size_t)ny * SLAB +
                     (size_t)fkg * (TN * 8) + (size_t)(wc + fr) * 8;

    f32x4 acc[4][FN];
#pragma unroll
    for (int i = 0; i < 4; i++)
#pragma unroll
        for (int j = 0; j < FN; j++) acc[i][j] = (f32x4){0.f, 0.f, 0.f, 0.f};

    // prologue: stage iter 0 into buffer 0
#pragma unroll
    for (int j = 0; j < NB; j++)
        if (j < nload) { gload_lds16(srcp[j], &lds[dsto[j]]); srcp[j] += inc; }
    __syncthreads();

    int scnt = npt - 1, skcv = 0;
    int dcnt = npt, dkcv = 0;
    int cur = 0;

    for (int it = 0; it < NIT; ++it) {
        const u16* lb = &lds[cur * BUFE];
        bf16x8 a1[4], a2[4], b1[FN], b2[FN];
#pragma unroll
        for (int fm = 0; fm < 4; fm++) {
            int aidx = fkg * 1024 + (wr + fm * 16 + fr) * 8;
            a1[fm] = *reinterpret_cast<const bf16x8*>(lb + aidx);
            a2[fm] = *reinterpret_cast<const bf16x8*>(lb + 4096 + aidx);
        }
#pragma unroll
        for (int fn = 0; fn < FN; fn++) {
            int bidx = 8192 + fkg * (TN * 8) + (wc + fn * 16 + fr) * 8;
            b1[fn] = *reinterpret_cast<const bf16x8*>(lb + bidx);
            b2[fn] = *reinterpret_cast<const bf16x8*>(lb + BPLANE + bidx);
        }
        if (it + 1 < NIT) {
#pragma unroll
            for (int j = 0; j < NB; j++)
                if (j < nload) {
                    gload_lds16(srcp[j], &lds[(cur ^ 1) * BUFE + dsto[j]]);
                    srcp[j] += inc;
                }
            if (wv < 2) {
                if (--scnt == 0) {
                    int d = ((skcv == 1) ? -8192 : 8200) - (int)pstr_x;
#pragma unroll
                    for (int j = 0; j < 8; j++) srcp[j] += d;
                    skcv++; scnt = npt;
                }
            }
        }
        bf16x8 da3[4], db3[FN];
#pragma unroll
        for (int fm = 0; fm < 4; fm++)
            da3[fm] = *reinterpret_cast<const bf16x8*>(pa3 + fm * 128);
#pragma unroll
        for (int fn = 0; fn < FN; fn++)
            db3[fn] = *reinterpret_cast<const bf16x8*>(pb3 + fn * 128);
        pa3 += 4 * SL;
        pb3 += BPLANE;
        if (--dcnt == 0) {
            pa3 += ((dkcv == 1) ? -8192 : 8200) - (int)pstr_x;
            dkcv++; dcnt = npt;
        }
#pragma unroll
        for (int fm = 0; fm < 4; fm++)
#pragma unroll
            for (int fn = 0; fn < FN; fn++)
                mfma6(acc[fm][fn], a1[fm], a2[fm], da3[fm],
                      b1[fn], b2[fn], db3[fn]);
        __syncthreads();
        cur ^= 1;
    }

    // ---- coalesced epilogue: per fm-slab, stage 3 planes in LDS, 16B stores
    u16 (*eld)[32][TN + 8] = (u16 (*)[32][TN + 8])lds;
    float bv[FN];
#pragma unroll
    for (int fn = 0; fn < FN; fn++) bv[fn] = bias[n0 + wc + fn * 16 + fr];
    const int srb = (wr >> 6) * 16 + fkg * 4;
#pragma unroll
    for (int fm = 0; fm < 4; fm++) {
#pragma unroll
        for (int fn = 0; fn < FN; fn++) {
            int cl = wc + fn * 16 + fr;
#pragma unroll
            for (int j = 0; j < 4; j++) {
                float f = acc[fm][fn][j] + bv[fn];
                u16 h1, h2, h3; split3(f, h1, h2, h3);
                eld[0][srb + j][cl] = h1;
                eld[1][srb + j][cl] = h2;
                eld[2][srb + j][cl] = h3;
            }
        }
        __syncthreads();
        for (int e = tid; e < 96 * (TN / 8); e += 256) {
            int g = e / 96, rem = e - g * 96;
            int p = rem >> 5, sr = rem & 31;
            bf16x8 vv = *reinterpret_cast<const bf16x8*>(&eld[p][sr][g * 8]);
            int rowg = m0 + ((sr >> 4) << 6) + fm * 16 + (sr & 15);
            size_t addr = (size_t)p * pstr_o +
                          (size_t)((n0 >> 3) + g) * 65536 + (size_t)rowg * 8;
            *reinterpret_cast<bf16x8*>(&outp[addr]) = vv;
        }
        __syncthreads();
    }
}

// ---------------------------------------------------------------------------
// Projection: 6-term MFMA over 3 k8 segments; z_e f32 + coalesced zpl planes.
// ---------------------------------------------------------------------------
__global__ __launch_bounds__(256, 3)
void proj_mfma5(const u16* __restrict__ sA, const u16* __restrict__ sB,
                const u16* __restrict__ sM, const u16* __restrict__ wp,
                const float* __restrict__ bias, float* __restrict__ z_e,
                u16* __restrict__ zpl) {
    __shared__ u16 lds[24576];
    const int m0 = blockIdx.x << 7;
    const int n0 = blockIdx.y << 7;
    const int tid = threadIdx.x, lane = tid & 63, wv = tid >> 6;
    const int wr = ((wv >> 1) & 1) << 6, wc = (wv & 1) << 6;
    const int fr = lane & 15, fkg = lane >> 4;

    const u16* srcp[12];
    int dsto[12];
#pragma unroll
    for (int j = 0; j < 12; j++) {
        int ii = wv * 12 + j;
        int tile = ii >> 3, sub = ii & 7;
        int kg = sub >> 1, half = sub & 1;
        int r = half * 64 + lane;
        if (tile >= 3)
            srcp[j] = wp + (size_t)(tile - 3) * 851968 + (size_t)kg * 2048 +
                      (size_t)(n0 + r) * 8;
        else
            srcp[j] = nullptr;
        dsto[j] = tile * 4096 + sub * 512;
    }

    f32x4 acc[4][4];
#pragma unroll
    for (int i = 0; i < 4; i++)
#pragma unroll
        for (int j = 0; j < 4; j++) acc[i][j] = (f32x4){0.f, 0.f, 0.f, 0.f};

    const u16* segp[3] = {sA, sB, sM};
    const int segG[3] = {160, 128, 128};
    const unsigned segP[3] = {10485760u, 8388608u, 8388608u};

    for (int seg = 0; seg < 3; seg++) {
        const u16* sp = segp[seg];
        const unsigned sps = segP[seg];
#pragma unroll
        for (int j = 0; j < 12; j++) {
            int ii = wv * 12 + j;
            int tile = ii >> 3, sub = ii & 7;
            int kg = sub >> 1, half = sub & 1;
            int r = half * 64 + lane;
            if (tile < 3)
                srcp[j] = sp + (size_t)tile * sps + (size_t)kg * 65536 +
                          (size_t)(m0 + r) * 8;
        }
        const int niter = segG[seg] >> 2;
        for (int it = 0; it < niter; it++) {
#pragma unroll
            for (int j = 0; j < 12; j++) {
                gload_lds16(srcp[j], &lds[dsto[j]]);
                int ii = wv * 12 + j;
                srcp[j] += (ii >> 3) < 3 ? 262144 : 8192;
            }
            __syncthreads();
            bf16x8 bfr[3][4];
#pragma unroll
            for (int p = 0; p < 3; p++)
#pragma unroll
                for (int fn = 0; fn < 4; fn++)
                    bfr[p][fn] = *reinterpret_cast<const bf16x8*>(
                        &lds[(3 + p) * 4096 + fkg * 1024 + (wc + fn * 16 + fr) * 8]);
#pragma unroll
            for (int fm = 0; fm < 4; fm++) {
                int aidx = fkg * 1024 + (wr + fm * 16 + fr) * 8;
                bf16x8 a1 = *reinterpret_cast<const bf16x8*>(&lds[aidx]);
                bf16x8 a2 = *reinterpret_cast<const bf16x8*>(&lds[4096 + aidx]);
                bf16x8 a3 = *reinterpret_cast<const bf16x8*>(&lds[8192 + aidx]);
#pragma unroll
                for (int fn = 0; fn < 4; fn++)
                    mfma6(acc[fm][fn], a1, a2, a3, bfr[0][fn], bfr[1][fn], bfr[2][fn]);
            }
            __syncthreads();
        }
    }
    u16 (*eld)[32][132] = (u16 (*)[32][132])lds;
    float bv[4];
#pragma unroll
    for (int fn = 0; fn < 4; fn++) bv[fn] = bias[n0 + wc + fn * 16 + fr];
    const int srb = (wr >> 6) * 16 + fkg * 4;
#pragma unroll
    for (int fm = 0; fm < 4; fm++) {
#pragma unroll
        for (int fn = 0; fn < 4; fn++) {
            int cl = wc + fn * 16 + fr;
            int col = n0 + cl;
#pragma unroll
            for (int j = 0; j < 4; j++) {
                float f = acc[fm][fn][j] + bv[fn];
                int rowg = m0 + wr + fm * 16 + fkg * 4 + j;
                z_e[(size_t)rowg * 256 + col] = f;
                u16 h1, h2, h3; split3(f, h1, h2, h3);
                eld[0][srb + j][cl] = h1;
                eld[1][srb + j][cl] = h2;
                eld[2][srb + j][cl] = h3;
            }
        }
        __syncthreads();
#pragma unroll
        for (int q = 0; q < 6; q++) {
            int e = q * 256 + tid;
            int g = e / 96, rem = e - g * 96;
            int p = rem >> 5, sr = rem & 31;
            bf16x8 vv = *reinterpret_cast<const bf16x8*>(&eld[p][sr][g * 8]);
            int rowg = m0 + ((sr >> 4) << 6) + fm * 16 + (sr & 15);
            size_t addr = (size_t)p * 2097152 +
                          (size_t)((n0 >> 3) + g) * 65536 + (size_t)rowg * 8;
            *reinterpret_cast<bf16x8*>(&zpl[addr]) = vv;
        }
        __syncthreads();
    }
}

// ---------------------------------------------------------------------------
// VQ: 6-term MFMA (K=256, k8 planes) + f64 compare + LDS argmin epilogue.
// ---------------------------------------------------------------------------
__global__ __launch_bounds__(256, 3)
void vq_mfma4(const u16* __restrict__ zpl, const u16* __restrict__ cbpl,
              const float* __restrict__ cn, double* __restrict__ pmin,
              int* __restrict__ pidx) {
    __shared__ __align__(16) char smem[49152];
    u16* lds = (u16*)smem;
    const int m0 = blockIdx.x << 7;
    const int n0 = blockIdx.y << 7;
    const int tid = threadIdx.x, lane = tid & 63, wv = tid >> 6;
    const int wr = ((wv >> 1) & 1) << 6, wc = (wv & 1) << 6;
    const int fr = lane & 15, fkg = lane >> 4;

    const u16* srcp[12];
    int dsto[12];
#pragma unroll
    for (int j = 0; j < 12; j++) {
        int ii = wv * 12 + j;
        int tile = ii >> 3, sub = ii & 7;
        int kg = sub >> 1, half = sub & 1;
        int r = half * 64 + lane;
        if (tile < 3)
            srcp[j] = zpl + (size_t)tile * 2097152 + (size_t)kg * 65536 +
                      (size_t)(m0 + r) * 8;
        else
            srcp[j] = cbpl + (size_t)(tile - 3) * 2097152 + (size_t)kg * 65536 +
                      (size_t)(n0 + r) * 8;
        dsto[j] = tile * 4096 + sub * 512;
    }

    f32x4 acc[4][4];
#pragma unroll
    for (int i = 0; i < 4; i++)
#pragma unroll
        for (int j = 0; j < 4; j++) acc[i][j] = (f32x4){0.f, 0.f, 0.f, 0.f};

    for (int kt = 0; kt < 256; kt += 32) {
#pragma unroll
        for (int j = 0; j < 12; j++) {
            gload_lds16(srcp[j], &lds[dsto[j]]);
            srcp[j] += 262144;
        }
        __syncthreads();
        bf16x8 bfr[3][4];
#pragma unroll
        for (int p = 0; p < 3; p++)
#pragma unroll
            for (int fn = 0; fn < 4; fn++)
                bfr[p][fn] = *reinterpret_cast<const bf16x8*>(
                    &lds[(3 + p) * 4096 + fkg * 1024 + (wc + fn * 16 + fr) * 8]);
#pragma unroll
        for (int fm = 0; fm < 4; fm++) {
            int aidx = fkg * 1024 + (wr + fm * 16 + fr) * 8;
            bf16x8 a1 = *reinterpret_cast<const bf16x8*>(&lds[aidx]);
            bf16x8 a2 = *reinterpret_cast<const bf16x8*>(&lds[4096 + aidx]);
            bf16x8 a3 = *reinterpret_cast<const bf16x8*>(&lds[8192 + aidx]);
#pragma unroll
            for (int fn = 0; fn < 4; fn++)
                mfma6(acc[fm][fn], a1, a2, a3, bfr[0][fn], bfr[1][fn], bfr[2][fn]);
        }
        __syncthreads();
    }
    double (*red_d)[32] = (double (*)[32])smem;
    int (*red_n)[32] = (int (*)[32])(smem + 32768);
#pragma unroll
    for (int fm = 0; fm < 4; fm++)
#pragma unroll
        for (int j = 0; j < 4; j++) {
            double best = 1e300; int bestn = 0x7fffffff;
#pragma unroll
            for (int fn = 0; fn < 4; fn++) {
                int gn = n0 + wc + fn * 16 + fr;
                double d = (double)cn[gn] - 2.0 * (double)acc[fm][fn][j];
                if (d < best || (d == best && gn < bestn)) { best = d; bestn = gn; }
            }
            int row = wr + fm * 16 + fkg * 4 + j;
            int cand = ((wv & 1) << 4) + fr;
            red_d[row][cand] = best; red_n[row][cand] = bestn;
        }
    __syncthreads();
    if (tid < 128) {
        double best = red_d[tid][0]; int bestn = red_n[tid][0];
#pragma unroll 4
        for (int k = 1; k < 32; k++) {
            double d = red_d[tid][k]; int n2 = red_n[tid][k];
            if (d < best || (d == best && n2 < bestn)) { best = d; bestn = n2; }
        }
        size_t idx = (size_t)(m0 + tid) * 64 + (n0 >> 7);
        pmin[idx] = best; pidx[idx] = bestn;
    }
}

// ---------------------------------------------------------------------------
__global__ void vq_finalize(const double* __restrict__ pmin, const int* __restrict__ pidx,
                            const float* __restrict__ z, const float* __restrict__ cb,
                            float* __restrict__ out, double* __restrict__ cpart) {
    int w = threadIdx.x >> 6, lane = threadIdx.x & 63;
    int m = blockIdx.x * 4 + w;
    double d = pmin[(size_t)m * 64 + lane];
    int n = pidx[(size_t)m * 64 + lane];
#pragma unroll
    for (int off = 32; off; off >>= 1) {
        double d2 = __shfl_xor(d, off);
        int n2 = __shfl_xor(n, off);
        if (d2 < d || (d2 == d && n2 < n)) { d = d2; n = n2; }
    }
    float4 cv = *reinterpret_cast<const float4*>(&cb[(size_t)n * 256 + lane * 4]);
    float4 zv = *reinterpret_cast<const float4*>(&z[(size_t)m * 256 + lane * 4]);
    *reinterpret_cast<float4*>(&out[(size_t)m * 256 + lane * 4]) = cv;
    float dx = zv.x - cv.x, dy = zv.y - cv.y, dz = zv.z - cv.z, dw = zv.w - cv.w;
    double s = (double)(dx * dx) + (double)(dy * dy) + (double)(dz * dz) + (double)(dw * dw);
#pragma unroll
    for (int off = 32; off; off >>= 1) s += __shfl_xor(s, off);
    if (lane == 0) {
        out[2097152 + m] = (float)n;
        cpart[m] = s;
    }
}

__global__ void vq_reduce(const double* __restrict__ cpart, float* __restrict__ out) {
    __shared__ double sm[256];
    double s = 0.0;
    for (int i = threadIdx.x; i < 8192; i += 256) s += cpart[i];
    sm[threadIdx.x] = s;
    __syncthreads();
    for (int off = 128; off; off >>= 1) {
        if ((int)threadIdx.x < off) sm[threadIdx.x] += sm[threadIdx.x + off];
        __syncthreads();
    }
    if (threadIdx.x == 0) out[2105344] = (float)(sm[0] / 2097152.0);
}

// ---------------------------------------------------------------------------
extern "C" void kernel_launch(void* const* d_in, const int* in_sizes, int n_in,
                              void* d_out, int out_size, void* d_ws, size_t ws_size,
                              hipStream_t stream) {
    (void)in_sizes; (void)n_in; (void)out_size; (void)ws_size;
    const float* whisper   = (const float*)d_in[0];
    const float* wavlm     = (const float*)d_in[1];
    const float* muq       = (const float*)d_in[2];
    const float* w_conv_w  = (const float*)d_in[3];
    const float* w_conv_b  = (const float*)d_in[4];
    const float* wl_conv_w = (const float*)d_in[5];
    const float* wl_conv_b = (const float*)d_in[6];
    const float* proj_w    = (const float*)d_in[7];
    const float* proj_b    = (const float*)d_in[8];
    const float* codebook  = (const float*)d_in[9];
    float* out = (float*)d_out;
    char* wsb = (char*)d_ws;

    // ---- workspace layout (bytes), same footprint as round 9 ----
    u16*   xsA   = (u16*)(wsb + 0);            // 3 planes, pstr 20,992,000 elems
    u16*   wtbA  = (u16*)(wsb + 125952000);    // 3 planes, pstr 6,553,600
    u16*   cApl  = (u16*)(wsb + 176259072);    // 3 planes, pstr 10,485,760
    u16*   xsB   = (u16*)(wsb + 0);            // pstr 16,793,600
    u16*   wtbB  = (u16*)(wsb + 100761600);    // pstr 4,194,304
    u16*   cBpl  = (u16*)(wsb + 125927424);    // pstr 8,388,608
    u16*   muqpl = (u16*)(wsb + 0);            // pstr 8,388,608
    u16*   wtpPl = (u16*)(wsb + 50331648);     // pstr 851,968
    float* z_e   = (float*)(wsb + 55443456);   // 8192*256 f32
    u16*   zpl   = (u16*)(wsb + 63832064);     // pstr 2,097,152
    u16*   cbpl  = (u16*)(wsb + 76414976);     // pstr 2,097,152
    float* cnorm = (float*)(wsb + 88997888);
    double* pmin = (double*)(wsb + 89030656);
    int*    pidx = (int*)(wsb + 93224960);
    double* cpart= (double*)(wsb + 95322112);

    // phase 1: whisper conv (TN=160 -> grid 64x8 = 512 blocks, perfect fill)
    split_x8t<<<dim3(264, 20), 256, 0, stream>>>(whisper, xsA, 20992000, 1280);
    split_weightT8m<<<dim3(20, 20), 256, 0, stream>>>(w_conv_w, wtbA, 6553600,
                                                      1280, 1280, 160);
    conv_mfma7<160><<<dim3(64, 8), 256, 0, stream>>>(xsA, 20992000, wtbA, 6553600,
                                                     w_conv_b, cApl, 10485760,
                                                     1280, 1280);
    // phase 2: wavlm conv (TN=128 -> grid 64x8 = 512 blocks)
    split_x8t<<<dim3(264, 16), 256, 0, stream>>>(wavlm, xsB, 16793600, 1024);
    split_weightT8m<<<dim3(16, 16), 256, 0, stream>>>(wl_conv_w, wtbB, 4194304,
                                                      1024, 1024, 128);
    conv_mfma7<128><<<dim3(64, 8), 256, 0, stream>>>(xsB, 16793600, wtbB, 4194304,
                                                     wl_conv_b, cBpl, 8388608,
                                                     1024, 1024);
    // phase 3: projection
    split_rows8t<<<dim3(128, 16), 256, 0, stream>>>(muq, muqpl, 8388608, 8192, 1024);
    split_rows8t<<<dim3(4, 52), 256, 0, stream>>>(proj_w, wtpPl, 851968, 256, 3328);
    proj_mfma5<<<dim3(64, 2), 256, 0, stream>>>(cApl, cBpl, muqpl, wtpPl, proj_b, z_e, zpl);
    // phase 4: VQ
    split_rows8t<<<dim3(128, 4), 256, 0, stream>>>(codebook, cbpl, 2097152, 8192, 256);
    cnorm_kernel<<<2048, 256, 0, stream>>>(codebook, cnorm);
    vq_mfma4<<<dim3(64, 64), 256, 0, stream>>>(zpl, cbpl, cnorm, pmin, pidx);
    vq_finalize<<<2048, 256, 0, stream>>>(pmin, pidx, z_e, codebook, out, cpart);
    vq_reduce<<<1, 256, 0, stream>>>(cpart, out);
}

// Round 11
// 1242.668 us; speedup vs baseline: 2.6793x; 1.0209x over previous
//
#include <hip/hip_runtime.h>
#include <cstdint>
#include <cstddef>

typedef unsigned short u16;
typedef __attribute__((ext_vector_type(8))) short bf16x8;
typedef __attribute__((ext_vector_type(4))) float f32x4;
typedef unsigned int u32;
typedef __attribute__((address_space(1))) const u32 gu32;
typedef __attribute__((address_space(3))) u32 lu32;

__device__ __forceinline__ void gload_lds16(const void* g, void* l) {
    __builtin_amdgcn_global_load_lds((gu32*)g, (lu32*)l, 16, 0, 0);
}

__device__ __forceinline__ u16 f2bf(float v) {
    u32 u = __float_as_uint(v);
    return (u16)((u + 0x7fffu + ((u >> 16) & 1u)) >> 16);
}
__device__ __forceinline__ float bf2f(u16 h) { return __uint_as_float(((u32)h) << 16); }

__device__ __forceinline__ void split3(float f, u16& h1, u16& h2, u16& h3) {
    h1 = f2bf(f); float r = f - bf2f(h1);
    h2 = f2bf(r); r -= bf2f(h2);
    h3 = f2bf(r);
}

// 6-term emulated f32 product
__device__ __forceinline__ void mfma6(f32x4& c, bf16x8 a1, bf16x8 a2, bf16x8 a3,
                                      bf16x8 b1, bf16x8 b2, bf16x8 b3) {
    c = __builtin_amdgcn_mfma_f32_16x16x32_bf16(a1, b1, c, 0, 0, 0);
    c = __builtin_amdgcn_mfma_f32_16x16x32_bf16(a1, b2, c, 0, 0, 0);
    c = __builtin_amdgcn_mfma_f32_16x16x32_bf16(a2, b1, c, 0, 0, 0);
    c = __builtin_amdgcn_mfma_f32_16x16x32_bf16(a1, b3, c, 0, 0, 0);
    c = __builtin_amdgcn_mfma_f32_16x16x32_bf16(a3, b1, c, 0, 0, 0);
    c = __builtin_amdgcn_mfma_f32_16x16x32_bf16(a2, b2, c, 0, 0, 0);
}

// ---------------------------------------------------------------------------
// Activation prep (coalesced transpose): x (8,2048,I) f32 -> parity k8 planes
// [g][b][parity][1025][8].
// ---------------------------------------------------------------------------
__global__ __launch_bounds__(256)
void split_x8t(const float* __restrict__ x, u16* __restrict__ p0,
               size_t pstr, int I) {
    __shared__ u16 tl[12288];                 // [3][8][64][8]
    const int b = blockIdx.x / 33, blk = blockIdx.x - b * 33;
    const int o0 = blk * 64;
    const int nval = (o0 + 64 <= 2050) ? 64 : (2050 - o0);
    const int c0 = blockIdx.y << 6;
    const int tid = threadIdx.x;
    const int r = tid >> 2, c4 = tid & 3;

    if (r < nval) {
        int local = o0 + r;
        int parity = local >= 1025 ? 1 : 0;
        int idx = local - parity * 1025;
        int prow = 2 * idx + parity;
        bool pad = (prow == 0) || (prow == 2049);
        int s = pad ? 0 : (prow - 1);
        const float* src = x + (size_t)(b * 2048 + s) * I + c0;
#pragma unroll
        for (int k = 0; k < 4; k++) {
            int cf4 = c4 + k * 4;
            float4 v = make_float4(0.f, 0.f, 0.f, 0.f);
            if (!pad) v = *reinterpret_cast<const float4*>(src + cf4 * 4);
            float vals[4] = {v.x, v.y, v.z, v.w};
            int base = ((cf4 >> 1) * 64 + r) * 8 + (cf4 & 1) * 4;
#pragma unroll
            for (int q = 0; q < 4; q++) {
                u16 h1, h2, h3; split3(vals[q], h1, h2, h3);
                tl[base + q]        = h1;
                tl[4096 + base + q] = h2;
                tl[8192 + base + q] = h3;
            }
        }
    }
    __syncthreads();
#pragma unroll
    for (int e = tid; e < 1536; e += 256) {
        int p = e >> 9, rem = e & 511;
        int gs = rem >> 6, rr = rem & 63;
        if (rr < nval) {
            size_t dst = (size_t)p * pstr +
                         (size_t)((c0 >> 3) + gs) * 131200 +
                         (size_t)(b * 2050 + o0 + rr) * 8;
            *reinterpret_cast<bf16x8*>(&p0[dst]) =
                *reinterpret_cast<const bf16x8*>(&tl[p * 4096 + (gs * 64 + rr) * 8]);
        }
    }
}

// ---------------------------------------------------------------------------
// Generic row split (coalesced transpose): in (R,C) f32 -> plane[g][r][8].
// ---------------------------------------------------------------------------
__global__ __launch_bounds__(256)
void split_rows8t(const float* __restrict__ in, u16* __restrict__ p0,
                  size_t pstr, int R, int C) {
    __shared__ u16 tl[12288];
    const int r0 = blockIdx.x << 6;
    const int c0 = blockIdx.y << 6;
    const int tid = threadIdx.x;
    const int r = tid >> 2, c4 = tid & 3;
    const float* src = in + (size_t)(r0 + r) * C + c0;
#pragma unroll
    for (int k = 0; k < 4; k++) {
        int cf4 = c4 + k * 4;
        float4 v = *reinterpret_cast<const float4*>(src + cf4 * 4);
        float vals[4] = {v.x, v.y, v.z, v.w};
        int base = ((cf4 >> 1) * 64 + r) * 8 + (cf4 & 1) * 4;
#pragma unroll
        for (int q = 0; q < 4; q++) {
            u16 h1, h2, h3; split3(vals[q], h1, h2, h3);
            tl[base + q]        = h1;
            tl[4096 + base + q] = h2;
            tl[8192 + base + q] = h3;
        }
    }
    __syncthreads();
#pragma unroll
    for (int e = tid; e < 1536; e += 256) {
        int p = e >> 9, rem = e & 511;
        int gs = rem >> 6, rr = rem & 63;
        size_t dst = (size_t)p * pstr +
                     ((size_t)((c0 >> 3) + gs) * R + (r0 + rr)) * 8;
        *reinterpret_cast<bf16x8*>(&p0[dst]) =
            *reinterpret_cast<const bf16x8*>(&tl[p * 4096 + (gs * 64 + rr) * 8]);
    }
}

// ---------------------------------------------------------------------------
// Weight prep (coalesced transpose, TILE-MAJOR): w (O,I,4) f32 ->
// plane[ng][kg][NT][8], kg = kcv*G + i/8, ng = o/NT.  Grid: (O/64, I/64).
// ---------------------------------------------------------------------------
__global__ __launch_bounds__(256)
void split_weightT8m(const float* __restrict__ w, u16* __restrict__ p0,
                     size_t pstr, int I, int O, int NT) {
    __shared__ u16 tl[12288];
    const int o0 = blockIdx.x << 6;
    const int c0 = blockIdx.y << 6;
    const int G = I >> 3;
    const size_t SLAB = (size_t)4 * G * NT * 8;
    const int tid = threadIdx.x;
    const int r = tid >> 2, c4 = tid & 3;
    for (int kcv = 0; kcv < 4; kcv++) {
#pragma unroll
        for (int k = 0; k < 4; k++) {
            int cf4 = c4 + k * 4;
#pragma unroll
            for (int q = 0; q < 4; q++) {
                int i = c0 + cf4 * 4 + q;
                float f = w[((size_t)(o0 + r) * I + i) * 4 + kcv];
                u16 h1, h2, h3; split3(f, h1, h2, h3);
                int base = ((cf4 >> 1) * 64 + r) * 8 + (cf4 & 1) * 4 + q;
                tl[base]        = h1;
                tl[4096 + base] = h2;
                tl[8192 + base] = h3;
            }
        }
        __syncthreads();
        for (int e = tid; e < 1536; e += 256) {
            int p = e >> 9, rem = e & 511;
            int gs = rem >> 6, rr = rem & 63;
            int o = o0 + rr;
            int ng = o / NT, orr = o - ng * NT;
            int kg = kcv * G + (c0 >> 3) + gs;
            size_t dst = (size_t)p * pstr + (size_t)ng * SLAB +
                         (size_t)kg * NT * 8 + (size_t)orr * 8;
            *reinterpret_cast<bf16x8*>(&p0[dst]) =
                *reinterpret_cast<const bf16x8*>(&tl[p * 4096 + (gs * 64 + rr) * 8]);
        }
        __syncthreads();
    }
}

__global__ void cnorm_kernel(const float* __restrict__ cb, float* __restrict__ cn) {
    int w = threadIdx.x >> 6, lane = threadIdx.x & 63;
    int row = blockIdx.x * 4 + w;
    float4 v = *reinterpret_cast<const float4*>(&cb[(size_t)row * 256 + lane * 4]);
    float s = v.x * v.x + v.y * v.y + v.z * v.z + v.w * v.w;
#pragma unroll
    for (int off = 32; off; off >>= 1) s += __shfl_xor(s, off);
    if (lane == 0) cn[row] = s;
}

// ---------------------------------------------------------------------------
// Conv1d(k=4,s=2,p=1): 6-term MFMA, dbuf LDS (planes 1,2) + plane-3 direct.
// Templated on TN: 160 (whisper) / 128 (wavlm); grid 64x8 = 512 both.
// ---------------------------------------------------------------------------
template<int TN>
__global__ __launch_bounds__(256, 2)
void conv_mfma7(const u16* __restrict__ xs, unsigned pstr_x,
                const u16* __restrict__ wt, unsigned pstr_w,
                const float* __restrict__ bias,
                u16* __restrict__ outp, unsigned pstr_o,
                int I, int O) {
    constexpr int FN = TN / 32;            // n-frags per wave (5 or 4)
    constexpr int NB = TN / 16;            // B loads per wave per iter (10 or 8)
    constexpr int BPLANE = 32 * TN;        // u16 per B plane per iter-slab
    constexpr int BUFE = 8192 + 2 * BPLANE;
    __shared__ u16 lds[2 * BUFE];
    const int m0 = blockIdx.x << 7;
    const int ny = blockIdx.y;
    const int n0 = ny * TN;
    const int tid = threadIdx.x, lane = tid & 63, wv = tid >> 6;
    const int wr = ((wv >> 1) & 1) << 6, wc = (wv & 1) * (TN / 2);
    const int fr = lane & 15, fkg = lane >> 4;
    const int b = m0 >> 10, t0 = m0 & 1023;
    const int G = I >> 3;
    const int SL = 131200;
    const int NIT = G, npt = G >> 2;
    const size_t SLAB = (size_t)4 * G * TN * 8;

    const u16* srcp[NB];
    int dsto[NB];
    const int nload = (wv < 2) ? 8 : NB;
    int inc;
    if (wv < 2) {
        inc = 4 * SL;
#pragma unroll
        for (int j = 0; j < NB; j++) {
            if (j < 8) {
                int kg = j >> 1, half = j & 1;
                int r = half * 64 + lane;
                srcp[j] = xs + (size_t)wv * pstr_x + (size_t)kg * SL +
                          (size_t)(b * 2050 + t0 + r) * 8;
                dsto[j] = wv * 4096 + j * 512;
            } else { srcp[j] = xs; dsto[j] = 0; }
        }
    } else {
        inc = BPLANE;
#pragma unroll
        for (int j = 0; j < NB; j++) {
            srcp[j] = wt + (size_t)(wv - 2) * pstr_w + (size_t)ny * SLAB +
                      j * 512 + lane * 8;
            dsto[j] = 8192 + (wv - 2) * BPLANE + j * 512;
        }
    }

    const u16* pa3 = xs + 2 * (size_t)pstr_x + (size_t)fkg * SL +
                     (size_t)(b * 2050 + t0 + wr + fr) * 8;
    const u16* pb3 = wt + 2 * (size_t)pstr_w + (size_t)ny * SLAB +
                     (size_t)fkg * (TN * 8) + (size_t)(wc + fr) * 8;

    f32x4 acc[4][FN];
#pragma unroll
    for (int i = 0; i < 4; i++)
#pragma unroll
        for (int j = 0; j < FN; j++) acc[i][j] = (f32x4){0.f, 0.f, 0.f, 0.f};

    // prologue: stage iter 0 into buffer 0
#pragma unroll
    for (int j = 0; j < NB; j++)
        if (j < nload) { gload_lds16(srcp[j], &lds[dsto[j]]); srcp[j] += inc; }
    __syncthreads();

    int scnt = npt - 1, skcv = 0;
    int dcnt = npt, dkcv = 0;
    int cur = 0;

    for (int it = 0; it < NIT; ++it) {
        const u16* lb = &lds[cur * BUFE];
        bf16x8 a1[4], a2[4], b1[FN], b2[FN];
#pragma unroll
        for (int fm = 0; fm < 4; fm++) {
            int aidx = fkg * 1024 + (wr + fm * 16 + fr) * 8;
            a1[fm] = *reinterpret_cast<const bf16x8*>(lb + aidx);
            a2[fm] = *reinterpret_cast<const bf16x8*>(lb + 4096 + aidx);
        }
#pragma unroll
        for (int fn = 0; fn < FN; fn++) {
            int bidx = 8192 + fkg * (TN * 8) + (wc + fn * 16 + fr) * 8;
            b1[fn] = *reinterpret_cast<const bf16x8*>(lb + bidx);
            b2[fn] = *reinterpret_cast<const bf16x8*>(lb + BPLANE + bidx);
        }
        if (it + 1 < NIT) {
#pragma unroll
            for (int j = 0; j < NB; j++)
                if (j < nload) {
                    gload_lds16(srcp[j], &lds[(cur ^ 1) * BUFE + dsto[j]]);
                    srcp[j] += inc;
                }
            if (wv < 2) {
                if (--scnt == 0) {
                    int d = ((skcv == 1) ? -8192 : 8200) - (int)pstr_x;
#pragma unroll
                    for (int j = 0; j < 8; j++) srcp[j] += d;
                    skcv++; scnt = npt;
                }
            }
        }
        bf16x8 da3[4], db3[FN];
#pragma unroll
        for (int fm = 0; fm < 4; fm++)
            da3[fm] = *reinterpret_cast<const bf16x8*>(pa3 + fm * 128);
#pragma unroll
        for (int fn = 0; fn < FN; fn++)
            db3[fn] = *reinterpret_cast<const bf16x8*>(pb3 + fn * 128);
        pa3 += 4 * SL;
        pb3 += BPLANE;
        if (--dcnt == 0) {
            pa3 += ((dkcv == 1) ? -8192 : 8200) - (int)pstr_x;
            dkcv++; dcnt = npt;
        }
        __builtin_amdgcn_s_setprio(1);
#pragma unroll
        for (int fm = 0; fm < 4; fm++)
#pragma unroll
            for (int fn = 0; fn < FN; fn++)
                mfma6(acc[fm][fn], a1[fm], a2[fm], da3[fm],
                      b1[fn], b2[fn], db3[fn]);
        __builtin_amdgcn_s_setprio(0);
        __syncthreads();
        cur ^= 1;
    }

    // ---- coalesced epilogue: per fm-slab, stage 3 planes in LDS, 16B stores
    u16 (*eld)[32][TN + 8] = (u16 (*)[32][TN + 8])lds;
    float bv[FN];
#pragma unroll
    for (int fn = 0; fn < FN; fn++) bv[fn] = bias[n0 + wc + fn * 16 + fr];
    const int srb = (wr >> 6) * 16 + fkg * 4;
#pragma unroll
    for (int fm = 0; fm < 4; fm++) {
#pragma unroll
        for (int fn = 0; fn < FN; fn++) {
            int cl = wc + fn * 16 + fr;
#pragma unroll
            for (int j = 0; j < 4; j++) {
                float f = acc[fm][fn][j] + bv[fn];
                u16 h1, h2, h3; split3(f, h1, h2, h3);
                eld[0][srb + j][cl] = h1;
                eld[1][srb + j][cl] = h2;
                eld[2][srb + j][cl] = h3;
            }
        }
        __syncthreads();
        for (int e = tid; e < 96 * (TN / 8); e += 256) {
            int g = e / 96, rem = e - g * 96;
            int p = rem >> 5, sr = rem & 31;
            bf16x8 vv = *reinterpret_cast<const bf16x8*>(&eld[p][sr][g * 8]);
            int rowg = m0 + ((sr >> 4) << 6) + fm * 16 + (sr & 15);
            size_t addr = (size_t)p * pstr_o +
                          (size_t)((n0 >> 3) + g) * 65536 + (size_t)rowg * 8;
            *reinterpret_cast<bf16x8*>(&outp[addr]) = vv;
        }
        __syncthreads();
    }
}

// ---------------------------------------------------------------------------
// Projection: 6-term MFMA over 3 k8 segments; z_e f32 + coalesced zpl planes.
// ---------------------------------------------------------------------------
__global__ __launch_bounds__(256, 3)
void proj_mfma5(const u16* __restrict__ sA, const u16* __restrict__ sB,
                const u16* __restrict__ sM, const u16* __restrict__ wp,
                const float* __restrict__ bias, float* __restrict__ z_e,
                u16* __restrict__ zpl) {
    __shared__ u16 lds[24576];
    const int m0 = blockIdx.x << 7;
    const int n0 = blockIdx.y << 7;
    const int tid = threadIdx.x, lane = tid & 63, wv = tid >> 6;
    const int wr = ((wv >> 1) & 1) << 6, wc = (wv & 1) << 6;
    const int fr = lane & 15, fkg = lane >> 4;

    const u16* srcp[12];
    int dsto[12];
#pragma unroll
    for (int j = 0; j < 12; j++) {
        int ii = wv * 12 + j;
        int tile = ii >> 3, sub = ii & 7;
        int kg = sub >> 1, half = sub & 1;
        int r = half * 64 + lane;
        if (tile >= 3)
            srcp[j] = wp + (size_t)(tile - 3) * 851968 + (size_t)kg * 2048 +
                      (size_t)(n0 + r) * 8;
        else
            srcp[j] = nullptr;
        dsto[j] = tile * 4096 + sub * 512;
    }

    f32x4 acc[4][4];
#pragma unroll
    for (int i = 0; i < 4; i++)
#pragma unroll
        for (int j = 0; j < 4; j++) acc[i][j] = (f32x4){0.f, 0.f, 0.f, 0.f};

    const u16* segp[3] = {sA, sB, sM};
    const int segG[3] = {160, 128, 128};
    const unsigned segP[3] = {10485760u, 8388608u, 8388608u};

    for (int seg = 0; seg < 3; seg++) {
        const u16* sp = segp[seg];
        const unsigned sps = segP[seg];
#pragma unroll
        for (int j = 0; j < 12; j++) {
            int ii = wv * 12 + j;
            int tile = ii >> 3, sub = ii & 7;
            int kg = sub >> 1, half = sub & 1;
            int r = half * 64 + lane;
            if (tile < 3)
                srcp[j] = sp + (size_t)tile * sps + (size_t)kg * 65536 +
                          (size_t)(m0 + r) * 8;
        }
        const int niter = segG[seg] >> 2;
        for (int it = 0; it < niter; it++) {
#pragma unroll
            for (int j = 0; j < 12; j++) {
                gload_lds16(srcp[j], &lds[dsto[j]]);
                int ii = wv * 12 + j;
                srcp[j] += (ii >> 3) < 3 ? 262144 : 8192;
            }
            __syncthreads();
            bf16x8 bfr[3][4];
#pragma unroll
            for (int p = 0; p < 3; p++)
#pragma unroll
                for (int fn = 0; fn < 4; fn++)
                    bfr[p][fn] = *reinterpret_cast<const bf16x8*>(
                        &lds[(3 + p) * 4096 + fkg * 1024 + (wc + fn * 16 + fr) * 8]);
            __builtin_amdgcn_s_setprio(1);
#pragma unroll
            for (int fm = 0; fm < 4; fm++) {
                int aidx = fkg * 1024 + (wr + fm * 16 + fr) * 8;
                bf16x8 a1 = *reinterpret_cast<const bf16x8*>(&lds[aidx]);
                bf16x8 a2 = *reinterpret_cast<const bf16x8*>(&lds[4096 + aidx]);
                bf16x8 a3 = *reinterpret_cast<const bf16x8*>(&lds[8192 + aidx]);
#pragma unroll
                for (int fn = 0; fn < 4; fn++)
                    mfma6(acc[fm][fn], a1, a2, a3, bfr[0][fn], bfr[1][fn], bfr[2][fn]);
            }
            __builtin_amdgcn_s_setprio(0);
            __syncthreads();
        }
    }
    u16 (*eld)[32][132] = (u16 (*)[32][132])lds;
    float bv[4];
#pragma unroll
    for (int fn = 0; fn < 4; fn++) bv[fn] = bias[n0 + wc + fn * 16 + fr];
    const int srb = (wr >> 6) * 16 + fkg * 4;
#pragma unroll
    for (int fm = 0; fm < 4; fm++) {
#pragma unroll
        for (int fn = 0; fn < 4; fn++) {
            int cl = wc + fn * 16 + fr;
            int col = n0 + cl;
#pragma unroll
            for (int j = 0; j < 4; j++) {
                float f = acc[fm][fn][j] + bv[fn];
                int rowg = m0 + wr + fm * 16 + fkg * 4 + j;
                z_e[(size_t)rowg * 256 + col] = f;
                u16 h1, h2, h3; split3(f, h1, h2, h3);
                eld[0][srb + j][cl] = h1;
                eld[1][srb + j][cl] = h2;
                eld[2][srb + j][cl] = h3;
            }
        }
        __syncthreads();
#pragma unroll
        for (int q = 0; q < 6; q++) {
            int e = q * 256 + tid;
            int g = e / 96, rem = e - g * 96;
            int p = rem >> 5, sr = rem & 31;
            bf16x8 vv = *reinterpret_cast<const bf16x8*>(&eld[p][sr][g * 8]);
            int rowg = m0 + ((sr >> 4) << 6) + fm * 16 + (sr & 15);
            size_t addr = (size_t)p * 2097152 +
                          (size_t)((n0 >> 3) + g) * 65536 + (size_t)rowg * 8;
            *reinterpret_cast<bf16x8*>(&zpl[addr]) = vv;
        }
        __syncthreads();
    }
}

// ---------------------------------------------------------------------------
// VQ: 6-term MFMA (K=256), dbuf LDS (planes 1,2) + plane-3 direct,
// f64 compare + LDS argmin epilogue.  Grid (64,64).
// Bit-identical accumulation to round-10 vq_mfma4 (same values, same order).
// ---------------------------------------------------------------------------
__global__ __launch_bounds__(256, 2)
void vq_mfma5(const u16* __restrict__ zpl, const u16* __restrict__ cbpl,
              const float* __restrict__ cn, double* __restrict__ pmin,
              int* __restrict__ pidx) {
    __shared__ __align__(16) char smem[65536];   // 2 x 32KB dbuf; epilogue 48KB
    u16* lds = (u16*)smem;
    const int m0 = blockIdx.x << 7;
    const int n0 = blockIdx.y << 7;
    const int tid = threadIdx.x, lane = tid & 63, wv = tid >> 6;
    const int wr = ((wv >> 1) & 1) << 6, wc = (wv & 1) << 6;
    const int fr = lane & 15, fkg = lane >> 4;

    // staging: wv0 -> A p1, wv1 -> A p2, wv2 -> B p1, wv3 -> B p2 (8 x 1KB each)
    const u16* srcp[8];
    int dsto[8];
    {
        const u16* bse = (wv < 2) ? (zpl + (size_t)wv * 2097152)
                                  : (cbpl + (size_t)(wv - 2) * 2097152);
        int r0 = (wv < 2) ? m0 : n0;
#pragma unroll
        for (int j = 0; j < 8; j++) {
            int kg = j >> 1, half = j & 1;
            srcp[j] = bse + (size_t)kg * 65536 + (size_t)(r0 + half * 64 + lane) * 8;
            dsto[j] = wv * 4096 + j * 512;
        }
    }
    const u16* pa3 = zpl + (size_t)2 * 2097152 + (size_t)fkg * 65536 +
                     (size_t)(m0 + wr + fr) * 8;
    const u16* pb3 = cbpl + (size_t)2 * 2097152 + (size_t)fkg * 65536 +
                     (size_t)(n0 + wc + fr) * 8;

    f32x4 acc[4][4];
#pragma unroll
    for (int i = 0; i < 4; i++)
#pragma unroll
        for (int j = 0; j < 4; j++) acc[i][j] = (f32x4){0.f, 0.f, 0.f, 0.f};

    // prologue
#pragma unroll
    for (int j = 0; j < 8; j++) {
        gload_lds16(srcp[j], &lds[dsto[j]]);
        srcp[j] += 262144;
    }
    __syncthreads();

    int cur = 0;
    for (int it = 0; it < 8; ++it) {
        const u16* lb = &lds[cur * 16384];
        bf16x8 a1[4], a2[4], b1[4], b2[4];
#pragma unroll
        for (int fm = 0; fm < 4; fm++) {
            int aidx = fkg * 1024 + (wr + fm * 16 + fr) * 8;
            a1[fm] = *reinterpret_cast<const bf16x8*>(lb + aidx);
            a2[fm] = *reinterpret_cast<const bf16x8*>(lb + 4096 + aidx);
        }
#pragma unroll
        for (int fn = 0; fn < 4; fn++) {
            int bidx = fkg * 1024 + (wc + fn * 16 + fr) * 8;
            b1[fn] = *reinterpret_cast<const bf16x8*>(lb + 8192 + bidx);
            b2[fn] = *reinterpret_cast<const bf16x8*>(lb + 12288 + bidx);
        }
        if (it + 1 < 8) {
#pragma unroll
            for (int j = 0; j < 8; j++) {
                gload_lds16(srcp[j], &lds[(cur ^ 1) * 16384 + dsto[j]]);
                srcp[j] += 262144;
            }
        }
        bf16x8 da3[4], db3[4];
#pragma unroll
        for (int fm = 0; fm < 4; fm++)
            da3[fm] = *reinterpret_cast<const bf16x8*>(pa3 + fm * 128);
#pragma unroll
        for (int fn = 0; fn < 4; fn++)
            db3[fn] = *reinterpret_cast<const bf16x8*>(pb3 + fn * 128);
        pa3 += 262144;
        pb3 += 262144;
        __builtin_amdgcn_s_setprio(1);
#pragma unroll
        for (int fm = 0; fm < 4; fm++)
#pragma unroll
            for (int fn = 0; fn < 4; fn++)
                mfma6(acc[fm][fn], a1[fm], a2[fm], da3[fm],
                      b1[fn], b2[fn], db3[fn]);
        __builtin_amdgcn_s_setprio(0);
        __syncthreads();
        cur ^= 1;
    }

    // ---- epilogue: per-row argmin, d = |c|^2 - 2 dot in f64 (LDS reused)
    double (*red_d)[32] = (double (*)[32])smem;
    int (*red_n)[32] = (int (*)[32])(smem + 32768);
#pragma unroll
    for (int fm = 0; fm < 4; fm++)
#pragma unroll
        for (int j = 0; j < 4; j++) {
            double best = 1e300; int bestn = 0x7fffffff;
#pragma unroll
            for (int fn = 0; fn < 4; fn++) {
                int gn = n0 + wc + fn * 16 + fr;
                double d = (double)cn[gn] - 2.0 * (double)acc[fm][fn][j];
                if (d < best || (d == best && gn < bestn)) { best = d; bestn = gn; }
            }
            int row = wr + fm * 16 + fkg * 4 + j;
            int cand = ((wv & 1) << 4) + fr;
            red_d[row][cand] = best; red_n[row][cand] = bestn;
        }
    __syncthreads();
    if (tid < 128) {
        double best = red_d[tid][0]; int bestn = red_n[tid][0];
#pragma unroll 4
        for (int k = 1; k < 32; k++) {
            double d = red_d[tid][k]; int n2 = red_n[tid][k];
            if (d < best || (d == best && n2 < bestn)) { best = d; bestn = n2; }
        }
        size_t idx = (size_t)(m0 + tid) * 64 + (n0 >> 7);
        pmin[idx] = best; pidx[idx] = bestn;
    }
}

// ---------------------------------------------------------------------------
__global__ void vq_finalize(const double* __restrict__ pmin, const int* __restrict__ pidx,
                            const float* __restrict__ z, const float* __restrict__ cb,
                            float* __restrict__ out, double* __restrict__ cpart) {
    int w = threadIdx.x >> 6, lane = threadIdx.x & 63;
    int m = blockIdx.x * 4 + w;
    double d = pmin[(size_t)m * 64 + lane];
    int n = pidx[(size_t)m * 64 + lane];
#pragma unroll
    for (int off = 32; off; off >>= 1) {
        double d2 = __shfl_xor(d, off);
        int n2 = __shfl_xor(n, off);
        if (d2 < d || (d2 == d && n2 < n)) { d = d2; n = n2; }
    }
    float4 cv = *reinterpret_cast<const float4*>(&cb[(size_t)n * 256 + lane * 4]);
    float4 zv = *reinterpret_cast<const float4*>(&z[(size_t)m * 256 + lane * 4]);
    *reinterpret_cast<float4*>(&out[(size_t)m * 256 + lane * 4]) = cv;
    float dx = zv.x - cv.x, dy = zv.y - cv.y, dz = zv.z - cv.z, dw = zv.w - cv.w;
    double s = (double)(dx * dx) + (double)(dy * dy) + (double)(dz * dz) + (double)(dw * dw);
#pragma unroll
    for (int off = 32; off; off >>= 1) s += __shfl_xor(s, off);
    if (lane == 0) {
        out[2097152 + m] = (float)n;
        cpart[m] = s;
    }
}

__global__ void vq_reduce(const double* __restrict__ cpart, float* __restrict__ out) {
    __shared__ double sm[256];
    double s = 0.0;
    for (int i = threadIdx.x; i < 8192; i += 256) s += cpart[i];
    sm[threadIdx.x] = s;
    __syncthreads();
    for (int off = 128; off; off >>= 1) {
        if ((int)threadIdx.x < off) sm[threadIdx.x] += sm[threadIdx.x + off];
        __syncthreads();
    }
    if (threadIdx.x == 0) out[2105344] = (float)(sm[0] / 2097152.0);
}

// ---------------------------------------------------------------------------
extern "C" void kernel_launch(void* const* d_in, const int* in_sizes, int n_in,
                              void* d_out, int out_size, void* d_ws, size_t ws_size,
                              hipStream_t stream) {
    (void)in_sizes; (void)n_in; (void)out_size; (void)ws_size;
    const float* whisper   = (const float*)d_in[0];
    const float* wavlm     = (const float*)d_in[1];
    const float* muq       = (const float*)d_in[2];
    const float* w_conv_w  = (const float*)d_in[3];
    const float* w_conv_b  = (const float*)d_in[4];
    const float* wl_conv_w = (const float*)d_in[5];
    const float* wl_conv_b = (const float*)d_in[6];
    const float* proj_w    = (const float*)d_in[7];
    const float* proj_b    = (const float*)d_in[8];
    const float* codebook  = (const float*)d_in[9];
    float* out = (float*)d_out;
    char* wsb = (char*)d_ws;

    // ---- workspace layout (bytes), same footprint as round 10 ----
    u16*   xsA   = (u16*)(wsb + 0);            // 3 planes, pstr 20,992,000 elems
    u16*   wtbA  = (u16*)(wsb + 125952000);    // 3 planes, pstr 6,553,600
    u16*   cApl  = (u16*)(wsb + 176259072);    // 3 planes, pstr 10,485,760
    u16*   xsB   = (u16*)(wsb + 0);            // pstr 16,793,600
    u16*   wtbB  = (u16*)(wsb + 100761600);    // pstr 4,194,304
    u16*   cBpl  = (u16*)(wsb + 125927424);    // pstr 8,388,608
    u16*   muqpl = (u16*)(wsb + 0);            // pstr 8,388,608
    u16*   wtpPl = (u16*)(wsb + 50331648);     // pstr 851,968
    float* z_e   = (float*)(wsb + 55443456);   // 8192*256 f32
    u16*   zpl   = (u16*)(wsb + 63832064);     // pstr 2,097,152
    u16*   cbpl  = (u16*)(wsb + 76414976);     // pstr 2,097,152
    float* cnorm = (float*)(wsb + 88997888);
    double* pmin = (double*)(wsb + 89030656);
    int*    pidx = (int*)(wsb + 93224960);
    double* cpart= (double*)(wsb + 95322112);

    // phase 1: whisper conv (TN=160 -> grid 64x8 = 512 blocks, perfect fill)
    split_x8t<<<dim3(264, 20), 256, 0, stream>>>(whisper, xsA, 20992000, 1280);
    split_weightT8m<<<dim3(20, 20), 256, 0, stream>>>(w_conv_w, wtbA, 6553600,
                                                      1280, 1280, 160);
    conv_mfma7<160><<<dim3(64, 8), 256, 0, stream>>>(xsA, 20992000, wtbA, 6553600,
                                                     w_conv_b, cApl, 10485760,
                                                     1280, 1280);
    // phase 2: wavlm conv (TN=128 -> grid 64x8 = 512 blocks)
    split_x8t<<<dim3(264, 16), 256, 0, stream>>>(wavlm, xsB, 16793600, 1024);
    split_weightT8m<<<dim3(16, 16), 256, 0, stream>>>(wl_conv_w, wtbB, 4194304,
                                                      1024, 1024, 128);
    conv_mfma7<128><<<dim3(64, 8), 256, 0, stream>>>(xsB, 16793600, wtbB, 4194304,
                                                     wl_conv_b, cBpl, 8388608,
                                                     1024, 1024);
    // phase 3: projection
    split_rows8t<<<dim3(128, 16), 256, 0, stream>>>(muq, muqpl, 8388608, 8192, 1024);
    split_rows8t<<<dim3(4, 52), 256, 0, stream>>>(proj_w, wtpPl, 851968, 256, 3328);
    proj_mfma5<<<dim3(64, 2), 256, 0, stream>>>(cApl, cBpl, muqpl, wtpPl, proj_b, z_e, zpl);
    // phase 4: VQ
    split_rows8t<<<dim3(128, 4), 256, 0, stream>>>(codebook, cbpl, 2097152, 8192, 256);
    cnorm_kernel<<<2048, 256, 0, stream>>>(codebook, cnorm);
    vq_mfma5<<<dim3(64, 64), 256, 0, stream>>>(zpl, cbpl, cnorm, pmin, pidx);
    vq_finalize<<<2048, 256, 0, stream>>>(pmin, pidx, z_e, codebook, out, cpart);
    vq_reduce<<<1, 256, 0, stream>>>(cpart, out);
}